// Round 14
// baseline (267.297 us; speedup 1.0000x reference)
//
#include <hip/hip_runtime.h>
#include <hip/hip_bf16.h>

typedef __attribute__((ext_vector_type(8))) short short8;
typedef __attribute__((ext_vector_type(4))) short bhalf4;
typedef __attribute__((ext_vector_type(4))) float floatx4;

constexpr int N_ = 4096;
constexpr float SQRT_E = 16.0f;
// q scale folded with log2(e): softmax computed in exp2 domain
constexpr float QSCALE = 0.17677669529663687f * 1.4426950408889634f;

__device__ __forceinline__ ushort f2bf(float x) {
  __hip_bfloat16 h = __float2bfloat16(x);
  return *reinterpret_cast<ushort*>(&h);
}
__device__ __forceinline__ float bf2f(ushort b) {
  unsigned int u = ((unsigned int)b) << 16;
  return __uint_as_float(u);
}

// ---------------- transpose helper (device side of mega-prep) ----------------
__device__ __forceinline__ void do_transpose(
    const float* __restrict__ src, ushort* __restrict__ dsth,
    ushort* __restrict__ dstl, int R, int C, int lb, int cb_shift,
    float* smem, int hasLo)
{
  float (*tile)[33] = (float(*)[33])smem;
  const int r0 = (lb >> cb_shift) * 32;
  const int c0 = (lb & ((1 << cb_shift) - 1)) * 32;
  const int tx = threadIdx.x & 31, ty = threadIdx.x >> 5;
  #pragma unroll
  for (int p = 0; p < 4; ++p) {
    const int lr = p*8 + ty;
    tile[lr][tx] = (r0+lr < R && c0+tx < C) ? src[(size_t)(r0+lr)*C + c0 + tx] : 0.f;
  }
  __syncthreads();
  #pragma unroll
  for (int p = 0; p < 4; ++p) {
    const int dc = p*8 + ty;
    if (c0+dc < C && r0+tx < R) {
      const float v = tile[tx][dc];
      const ushort hi = f2bf(v);
      dsth[(size_t)(c0+dc)*R + r0 + tx] = hi;
      if (hasLo) dstl[(size_t)(c0+dc)*R + r0 + tx] = f2bf(v - bf2f(hi));
    }
  }
}

// ---------------- mega-prep: all transposes + hsplit + k1 in ONE launch --------
__global__ __launch_bounds__(256) void k_prep(
    const float* __restrict__ equ, const float* __restrict__ h,
    const float* __restrict__ W_equ, const float* __restrict__ W_gproj,
    const float* __restrict__ W_g1, const float* __restrict__ W_g2,
    const float* __restrict__ W_q, const float* __restrict__ W_k,
    const float* __restrict__ W_v, const float* __restrict__ W_vg,
    const float* __restrict__ W_ng, const float* __restrict__ W_gout,
    const float* __restrict__ W_hdec, const float* __restrict__ W_gdec,
    ushort* __restrict__ Wg1t, ushort* __restrict__ Wg2t,
    ushort* __restrict__ Wth, ushort* __restrict__ Wtl,
    ushort* __restrict__ Wvgt, ushort* __restrict__ Wngt,
    ushort* __restrict__ Wgoutt, ushort* __restrict__ Whdect,
    ushort* __restrict__ Wgdect,
    ushort* __restrict__ h2h, ushort* __restrict__ h2l,
    ushort* __restrict__ g_src_b, ushort* __restrict__ gram_b,
    float* __restrict__ pre0)
{
  __shared__ __align__(16) float smem[1120];
  const int b = blockIdx.x;
  const int t = threadIdx.x;

  if (b < 512) {            // W_g1 [1024,512] -> Wg1t
    do_transpose(W_g1, Wg1t, nullptr, 1024, 512, b, 4, smem, 0);
  } else if (b < 640) {     // W_g2 [512,256]
    do_transpose(W_g2, Wg2t, nullptr, 512, 256, b-512, 3, smem, 0);
  } else if (b < 768) {     // W_q hi/lo
    do_transpose(W_q, Wth, Wtl, 512, 256, b-640, 3, smem, 1);
  } else if (b < 896) {     // W_k hi/lo
    do_transpose(W_k, Wth + 256*512, Wtl + 256*512, 512, 256, b-768, 3, smem, 1);
  } else if (b < 1024) {    // W_v hi/lo
    do_transpose(W_v, Wth + 512*512, Wtl + 512*512, 512, 256, b-896, 3, smem, 1);
  } else if (b < 1088) {    // W_vg
    do_transpose(W_vg, Wvgt, nullptr, 256, 256, b-1024, 3, smem, 0);
  } else if (b < 1152) {    // W_ng
    do_transpose(W_ng, Wngt, nullptr, 256, 256, b-1088, 3, smem, 0);
  } else if (b < 1216) {    // W_gout
    do_transpose(W_gout, Wgoutt, nullptr, 256, 256, b-1152, 3, smem, 0);
  } else if (b < 1280) {    // W_hdec
    do_transpose(W_hdec, Whdect, nullptr, 256, 256, b-1216, 3, smem, 0);
  } else if (b < 1288) {    // W_gdec [256,16]
    do_transpose(W_gdec, Wgdect, nullptr, 256, 16, b-1280, 0, smem, 0);
  } else if (b < 5384) {    // hsplit: h_src half of h2 (hi/lo)
    const int i = b - 1288;
    const float v = h[(size_t)i*256 + t] * SQRT_E;
    const ushort hi = f2bf(v);
    h2h[(size_t)i*512 + 256 + t] = hi;
    h2l[(size_t)i*512 + 256 + t] = f2bf(v - bf2f(hi));
  } else {                  // k1: g_src_b + gram_b + pre0
    float* eq   = smem;        // 48
    float* gs   = smem + 48;   // 768
    float* g2p  = smem + 816;  // 96
    float* part = smem + 912;  // 192
    const int i = b - 5384;
    if (t < 48) eq[t] = equ[(size_t)i*48 + t];
    __syncthreads();
    #pragma unroll
    for (int j = 0; j < 3; ++j) {
      float s = 0.f;
      #pragma unroll
      for (int m = 0; m < 16; ++m) s += eq[j*16+m] * W_equ[m*256 + t];
      s *= SQRT_E;
      gs[j*256 + t] = s;
      g_src_b[((size_t)i*3 + j)*256 + t] = f2bf(s);
    }
    __syncthreads();
    if (t < 192) {            // 2-way K-split of the gproj GEMV
      const int o = t % 96, half = t / 96;
      const int j = o >> 5, a = o & 31;
      const int e0 = half * 128;
      float s = 0.f;
      for (int e = 0; e < 128; ++e)
        s += gs[j*256 + e0 + e] * W_gproj[(size_t)(e0+e)*32 + a];
      part[t] = s;
    }
    __syncthreads();
    if (t < 96) g2p[t] = part[t] + part[96 + t];
    __syncthreads();
    #pragma unroll
    for (int r = 0; r < 4; ++r) {
      const int idx = r*256 + t;
      const int a = idx >> 5, bb = idx & 31;
      const float s = g2p[a]*g2p[bb] + g2p[32+a]*g2p[32+bb] + g2p[64+a]*g2p[64+bb];
      gram_b[(size_t)i*1024 + idx] = f2bf(s);
    }
    // pre0 = g_src(f32) @ W_gdec, 4-way K-split. t = j*64 + ks*16 + mc
    if (t < 192) {
      const int j = t >> 6, ks = (t >> 4) & 3, mc = t & 15;
      const int e0 = ks * 64;
      float s = 0.f;
      for (int e = 0; e < 64; ++e)
        s += gs[j*256 + e0 + e] * W_gdec[(size_t)(e0 + e)*16 + mc];
      part[t] = s;
    }
    __syncthreads();
    if (t < 48) {
      const int j = t >> 4, mc = t & 15;
      pre0[((size_t)i*3 + j)*16 + mc] =
          part[j*64 + mc] + part[j*64 + 16 + mc] +
          part[j*64 + 32 + mc] + part[j*64 + 48 + mc];
    }
  }
}

// ---------------- GEMM cores: BK=64, double-pumped, register prefetch -----------
template<int KTOT>
__device__ __forceinline__ void gemm_core(
    const ushort* __restrict__ A, const ushort* __restrict__ Bt,
    int bM, int bN, floatx4 acc[4], ushort* As, ushort* Bs)
{
  const int t = threadIdx.x;
  const int wave = t >> 6, lane = t & 63, quad = lane >> 4, m = lane & 15;
  #pragma unroll
  for (int ct = 0; ct < 4; ++ct) acc[ct] = {0.f, 0.f, 0.f, 0.f};
  const int ca = t*2, cb = t*2 + 1;
  const int ra = ca >> 3, pa = ca & 7;
  const int rb = cb >> 3, pb = cb & 7;
  const ushort* pA0 = A  + (size_t)(bM+ra)*KTOT + pa*8;
  const ushort* pA1 = A  + (size_t)(bM+rb)*KTOT + pb*8;
  const ushort* pB0 = Bt + (size_t)(bN+ra)*KTOT + pa*8;
  const ushort* pB1 = Bt + (size_t)(bN+rb)*KTOT + pb*8;
  short8 rA0 = *(const short8*)pA0, rA1 = *(const short8*)pA1;
  short8 rB0 = *(const short8*)pB0, rB1 = *(const short8*)pB1;
  for (int k0 = 0; k0 < KTOT; k0 += 64) {
    __syncthreads();
    *(short8*)&As[ra*72 + pa*8] = rA0;
    *(short8*)&As[rb*72 + pb*8] = rA1;
    *(short8*)&Bs[ra*72 + pa*8] = rB0;
    *(short8*)&Bs[rb*72 + pb*8] = rB1;
    if (k0 + 64 < KTOT) {
      pA0 += 64; pA1 += 64; pB0 += 64; pB1 += 64;
      rA0 = *(const short8*)pA0; rA1 = *(const short8*)pA1;
      rB0 = *(const short8*)pB0; rB1 = *(const short8*)pB1;
    }
    __syncthreads();
    #pragma unroll
    for (int ks = 0; ks < 2; ++ks) {
      const short8 af = *(const short8*)&As[(wave*16 + m)*72 + ks*32 + quad*8];
      #pragma unroll
      for (int ct = 0; ct < 4; ++ct) {
        const short8 bf = *(const short8*)&Bs[(ct*16 + m)*72 + ks*32 + quad*8];
        acc[ct] = __builtin_amdgcn_mfma_f32_16x16x32_bf16(af, bf, acc[ct], 0, 0, 0);
      }
    }
  }
}

template<int KTOT>
__device__ __forceinline__ void gemm_core3(
    const ushort* __restrict__ Ah, const ushort* __restrict__ Al,
    const ushort* __restrict__ Bth, const ushort* __restrict__ Btl,
    int bM, int bN, floatx4 acc[4],
    ushort* Ash, ushort* Asl, ushort* Bsh, ushort* Bsl)
{
  const int t = threadIdx.x;
  const int wave = t >> 6, lane = t & 63, quad = lane >> 4, m = lane & 15;
  #pragma unroll
  for (int ct = 0; ct < 4; ++ct) acc[ct] = {0.f, 0.f, 0.f, 0.f};
  const int ca = t*2, cb = t*2 + 1;
  const int ra = ca >> 3, pa = ca & 7;
  const int rb = cb >> 3, pb = cb & 7;
  const ushort* pAh0 = Ah  + (size_t)(bM+ra)*KTOT + pa*8;
  const ushort* pAh1 = Ah  + (size_t)(bM+rb)*KTOT + pb*8;
  const ushort* pAl0 = Al  + (size_t)(bM+ra)*KTOT + pa*8;
  const ushort* pAl1 = Al  + (size_t)(bM+rb)*KTOT + pb*8;
  const ushort* pBh0 = Bth + (size_t)(bN+ra)*KTOT + pa*8;
  const ushort* pBh1 = Bth + (size_t)(bN+rb)*KTOT + pb*8;
  const ushort* pBl0 = Btl + (size_t)(bN+ra)*KTOT + pa*8;
  const ushort* pBl1 = Btl + (size_t)(bN+rb)*KTOT + pb*8;
  short8 rAh0 = *(const short8*)pAh0, rAh1 = *(const short8*)pAh1;
  short8 rAl0 = *(const short8*)pAl0, rAl1 = *(const short8*)pAl1;
  short8 rBh0 = *(const short8*)pBh0, rBh1 = *(const short8*)pBh1;
  short8 rBl0 = *(const short8*)pBl0, rBl1 = *(const short8*)pBl1;
  for (int k0 = 0; k0 < KTOT; k0 += 64) {
    __syncthreads();
    *(short8*)&Ash[ra*72 + pa*8] = rAh0;
    *(short8*)&Ash[rb*72 + pb*8] = rAh1;
    *(short8*)&Asl[ra*72 + pa*8] = rAl0;
    *(short8*)&Asl[rb*72 + pb*8] = rAl1;
    *(short8*)&Bsh[ra*72 + pa*8] = rBh0;
    *(short8*)&Bsh[rb*72 + pb*8] = rBh1;
    *(short8*)&Bsl[ra*72 + pa*8] = rBl0;
    *(short8*)&Bsl[rb*72 + pb*8] = rBl1;
    if (k0 + 64 < KTOT) {
      pAh0 += 64; pAh1 += 64; pAl0 += 64; pAl1 += 64;
      pBh0 += 64; pBh1 += 64; pBl0 += 64; pBl1 += 64;
      rAh0 = *(const short8*)pAh0; rAh1 = *(const short8*)pAh1;
      rAl0 = *(const short8*)pAl0; rAl1 = *(const short8*)pAl1;
      rBh0 = *(const short8*)pBh0; rBh1 = *(const short8*)pBh1;
      rBl0 = *(const short8*)pBl0; rBl1 = *(const short8*)pBl1;
    }
    __syncthreads();
    #pragma unroll
    for (int ks = 0; ks < 2; ++ks) {
      const short8 ah = *(const short8*)&Ash[(wave*16 + m)*72 + ks*32 + quad*8];
      const short8 al = *(const short8*)&Asl[(wave*16 + m)*72 + ks*32 + quad*8];
      #pragma unroll
      for (int ct = 0; ct < 4; ++ct) {
        const short8 bh = *(const short8*)&Bsh[(ct*16 + m)*72 + ks*32 + quad*8];
        const short8 bl = *(const short8*)&Bsl[(ct*16 + m)*72 + ks*32 + quad*8];
        acc[ct] = __builtin_amdgcn_mfma_f32_16x16x32_bf16(ah, bl, acc[ct], 0, 0, 0);
        acc[ct] = __builtin_amdgcn_mfma_f32_16x16x32_bf16(al, bh, acc[ct], 0, 0, 0);
        acc[ct] = __builtin_amdgcn_mfma_f32_16x16x32_bf16(ah, bh, acc[ct], 0, 0, 0);
      }
    }
  }
}

// G1: hidden = relu(gram @ W_g1 + b_g1)
__global__ __launch_bounds__(256) void k_g1(
    const ushort* __restrict__ gram_b, const ushort* __restrict__ Wg1t,
    const float* __restrict__ b_g1, ushort* __restrict__ hidden)
{
  __shared__ __align__(16) ushort As[64*72], Bs[64*72];
  floatx4 acc[4];
  const int bM = blockIdx.x*64, bN = blockIdx.y*64;
  gemm_core<1024>(gram_b, Wg1t, bM, bN, acc, As, Bs);
  const int lane = threadIdx.x & 63, wave = threadIdx.x >> 6;
  const int quad = lane >> 4, m = lane & 15;
  #pragma unroll
  for (int ct = 0; ct < 4; ++ct) {
    const int c = bN + ct*16 + m;
    #pragma unroll
    for (int r = 0; r < 4; ++r) {
      const int i = bM + wave*16 + quad*4 + r;
      hidden[(size_t)i*512 + c] = f2bf(fmaxf(acc[ct][r] + b_g1[c], 0.f));
    }
  }
}

// G2: g2 = hidden @ W_g2 + b_g2 -> hi/lo into h2 cols 0..255
__global__ __launch_bounds__(256) void k_g2(
    const ushort* __restrict__ hidden, const ushort* __restrict__ Wg2t,
    const float* __restrict__ b_g2, ushort* __restrict__ h2h, ushort* __restrict__ h2l)
{
  __shared__ __align__(16) ushort As[64*72], Bs[64*72];
  floatx4 acc[4];
  const int bM = blockIdx.x*64, bN = blockIdx.y*64;
  gemm_core<512>(hidden, Wg2t, bM, bN, acc, As, Bs);
  const int lane = threadIdx.x & 63, wave = threadIdx.x >> 6;
  const int quad = lane >> 4, m = lane & 15;
  #pragma unroll
  for (int ct = 0; ct < 4; ++ct) {
    const int c = bN + ct*16 + m;
    #pragma unroll
    for (int r = 0; r < 4; ++r) {
      const int i = bM + wave*16 + quad*4 + r;
      const float s = acc[ct][r] + b_g2[c];
      const ushort hi = f2bf(s);
      h2h[(size_t)i*512 + c] = hi;
      h2l[(size_t)i*512 + c] = f2bf(s - bf2f(hi));
    }
  }
}

// G3: q/k hi/lo 3-term GEMM (4 LDS buffers, 37 KB -> 4 blk/CU, 512 blocks).
// Split from the old k_g34: its 4-buffer LDS footprint was charged to ALL
// 1536 blocks (v/vg only need 2 buffers), halving their occupancy.
__global__ __launch_bounds__(256) void k_g3(
    const ushort* __restrict__ h2h, const ushort* __restrict__ h2l,
    const ushort* __restrict__ Wth, const ushort* __restrict__ Wtl,
    const float* __restrict__ b_q, const float* __restrict__ b_k,
    float* __restrict__ q_ws, ushort* __restrict__ kh)
{
  __shared__ __align__(16) ushort S0[64*72], S1[64*72], S2[64*72], S3[64*72];
  const int lane = threadIdx.x & 63, wave = threadIdx.x >> 6;
  const int quad = lane >> 4, m = lane & 15;
  floatx4 acc[4];
  const int bM = blockIdx.x*64, bN = blockIdx.y*64;   // grid (64,8): bN < 512
  gemm_core3<512>(h2h, h2l, Wth, Wtl, bM, bN, acc, S0, S1, S2, S3);
  #pragma unroll
  for (int ct = 0; ct < 4; ++ct) {
    const int c = bN + ct*16 + m;
    #pragma unroll
    for (int r = 0; r < 4; ++r) {
      const int i = bM + wave*16 + quad*4 + r;
      if (c < 256) {
        const float s = acc[ct][r] + b_q[c];
        q_ws[((size_t)(c >> 5)*N_ + i)*32 + (c & 31)] = s * QSCALE;
      } else {
        const int cc = c - 256;
        const float s = acc[ct][r] + b_k[cc];
        kh[((size_t)(cc >> 5)*N_ + i)*32 + (cc & 31)] = f2bf(s);
      }
    }
  }
}

// G4: v (1-term, 256 blocks) + vg (1-term, 768 blocks). 2 LDS buffers
// (18.5 KB) -> 8 blk/CU; 1024 blocks = half a round at 2048 capacity.
__global__ __launch_bounds__(256) void k_g4(
    const ushort* __restrict__ h2h, const ushort* __restrict__ Wth,
    const float* __restrict__ b_v,
    const ushort* __restrict__ g_src_b, const ushort* __restrict__ Wvgt,
    ushort* __restrict__ vt)
{
  __shared__ __align__(16) ushort S0[64*72], S1[64*72];
  const int id = blockIdx.x;                           // grid (1024)
  const int lane = threadIdx.x & 63, wave = threadIdx.x >> 6;
  const int quad = lane >> 4, m = lane & 15;
  floatx4 acc[4];
  if (id < 256) {
    // v path: bN in {512..704} of the [q|k|v] 768-col output
    const int bM = (id & 63)*64, bN = 512 + (id >> 6)*64;
    gemm_core<512>(h2h, Wth, bM, bN, acc, S0, S1);
    #pragma unroll
    for (int ct = 0; ct < 4; ++ct) {
      const int cc = bN + ct*16 + m - 512;
      #pragma unroll
      for (int r = 0; r < 4; ++r) {
        const int i = bM + wave*16 + quad*4 + r;
        const float s = acc[ct][r] + b_v[cc];
        vt[((size_t)(cc >> 5)*128 + (cc & 31))*N_ + i] = f2bf(s);
      }
    }
  } else {
    const int lb2 = id - 256;                          // 0..767
    const int bM = (lb2 >> 2)*64, bN = (lb2 & 3)*64;
    gemm_core<256>(g_src_b, Wvgt, bM, bN, acc, S0, S1);
    #pragma unroll
    for (int ct = 0; ct < 4; ++ct) {
      const int c = bN + ct*16 + m;
      const int hh = c >> 5, d = c & 31;
      #pragma unroll
      for (int r = 0; r < 4; ++r) {
        const int i3 = bM + wave*16 + quad*4 + r;
        const int i = i3 / 3, j = i3 - 3*i;
        vt[((size_t)hh*128 + 32 + j*32 + d)*N_ + i] = f2bf(acc[ct][r]);
      }
    }
  }
}

// ---------------- K3: swapped-operand flash attention, P fully in-register -----
// mfma(K,Q) gives S^T with q = lane&15 -> softmax is lane-local. V columns are
// stored bit-permuted in LDS (slot{5..0} = {k5,k3,k2,k4,k1,k0}) so each lane's
// own 16 P values form its PV B-fragment directly: no P LDS buffer, no cross-
// lane exchange. PV swapped too (O^T = V^T P^T). Denominator = ones-row MFMA.
// 8-wave blocks (512 thr, 128 q-rows). Grid (32,8,4)=1024 = 4 blk/CU resident.
// __launch_bounds__(512,4): proven 56-VGPR codegen (75 us, rounds 9/11/13).
// LESSONS: (r10) doubling accumulator state spills (~64 live VGPR budget);
// (r12) fixed-base exp2 softmax NaNs — the online max is load-bearing.
__global__ __launch_bounds__(512, 4) void k3_attn(
    const float* __restrict__ q_ws, const ushort* __restrict__ kh,
    const ushort* __restrict__ vt,
    ushort* __restrict__ Po0, ushort* __restrict__ Po1,
    ushort* __restrict__ Po2, ushort* __restrict__ Po3,
    float* __restrict__ Pml)
{
  __shared__ __align__(16) ushort Khs[64*40];              // 5 KiB
  __shared__ __align__(16) ushort Vs[128*64];              // 16 KiB, permuted+swizzled
  __shared__ float li_s[128];

  const int t    = threadIdx.x;          // 0..511
  const int wave = t >> 6;               // 0..7
  const int lane = t & 63;
  const int quad = lane >> 4;
  const int m    = lane & 15;
  const int h    = blockIdx.y;
  const int s    = blockIdx.z;
  const int n0q  = blockIdx.x * 128;

  const int ktb = s * 16;
  const int kte = ktb + 16;

  // Q fragment (B-operand; rows n0q + wave*16 + m, wave in [0,8))
  union { short8 v; ushort u[8]; } Aqh, Aql;
  {
    const float* qp = q_ws + ((size_t)h*N_ + n0q + wave*16 + m)*32 + quad*8;
    #pragma unroll
    for (int jj = 0; jj < 8; ++jj) {
      const float x = qp[jj];
      const ushort hi = f2bf(x);
      Aqh.u[jj] = hi;
      Aql.u[jj] = f2bf(x - bf2f(hi));
    }
  }

  // ones A-fragment: A row 0 = ones -> denominator row of O^T
  union { short8 v; ushort u[8]; } onesf;
  {
    const ushort ov = (m == 0) ? (ushort)0x3F80 : (ushort)0;
    #pragma unroll
    for (int jj = 0; jj < 8; ++jj) onesf.u[jj] = ov;
  }

  // Of[nt][r] = O^T[d = nt*16 + quad*4 + r][q = wave*16 + m]; Of8 row0 = denom
  floatx4 Of[8];
  #pragma unroll
  for (int nt = 0; nt < 8; ++nt) Of[nt] = {0.f, 0.f, 0.f, 0.f};
  floatx4 Of8 = {0.f, 0.f, 0.f, 0.f};
  float mi = -3.0e38f;

  // K staging: 256 chunks handled by threads t < 256
  const int krow = t >> 2, kch = (t & 3) * 8;
  const ushort* pKh = kh + ((size_t)h*N_ + ktb*64 + (krow & 63))*32 + kch;

  // V staging: 1024 (row,g) chunks over 512 threads (2 each); each 8-k run
  // splits into two permuted b64s.
  // slot = 32*(g>>2) + 16*(g&1) + 8*(e>>2) + 4*((g>>1)&1) + (e&3)
  const ushort* pV[2];
  int wv0[2], wv1[2];
  #pragma unroll
  for (int p = 0; p < 2; ++p) {
    const int idx = p*512 + t, row = idx >> 3, g = idx & 7;
    pV[p] = vt + ((size_t)h*128 + row)*N_ + ktb*64 + g*8;
    const int sb0  = 32*(g>>2) + 16*(g&1) + 4*((g>>1)&1);
    const int blk0 = sb0 >> 3, off = sb0 & 4, r7 = row & 7;
    wv0[p] = row*64 + ((blk0       ^ r7) * 8) + off;
    wv1[p] = row*64 + (((blk0 + 1) ^ r7) * 8) + off;
  }

  short8 rK0 = {0,0,0,0,0,0,0,0};
  if (t < 256) rK0 = *(const short8*)pKh;
  short8 rV[2];
  #pragma unroll
  for (int p = 0; p < 2; ++p) rV[p] = *(const short8*)pV[p];

  const int x7 = m & 7;   // read-side swizzle key (row = nt*16 + m)

  for (int kt = ktb; kt < kte; ++kt) {
    __syncthreads();
    if (t < 256) *(short8*)&Khs[krow*40 + kch] = rK0;
    #pragma unroll
    for (int p = 0; p < 2; ++p) {
      union { short8 v; bhalf4 h2[2]; } tmp;
      tmp.v = rV[p];
      *(bhalf4*)&Vs[wv0[p]] = tmp.h2[0];
      *(bhalf4*)&Vs[wv1[p]] = tmp.h2[1];
    }
    if (kt + 1 < kte) {
      if (t < 256) { pKh += 2048; rK0 = *(const short8*)pKh; }
      #pragma unroll
      for (int p = 0; p < 2; ++p) { pV[p] += 64; rV[p] = *(const short8*)pV[p]; }
    }
    __syncthreads();

    // S^T = K Q^T (swapped operands): sf[kb][r] = S[k=kb*16+quad*4+r][q=m-col]
    floatx4 sf[4];
    #pragma unroll
    for (int kb = 0; kb < 4; ++kb) {
      const short8 bkh = *(const short8*)&Khs[(kb*16 + m)*40 + quad*8];
      floatx4 sv = {0.f, 0.f, 0.f, 0.f};
      sv = __builtin_amdgcn_mfma_f32_16x16x32_bf16(bkh, Aql.v, sv, 0, 0, 0);
      sv = __builtin_amdgcn_mfma_f32_16x16x32_bf16(bkh, Aqh.v, sv, 0, 0, 0);
      sf[kb] = sv;
    }

    // row max: 15 fmax local + 2 shuffle across quads (lanes m, m^16, m^32, m^48)
    float nm = fmaxf(fmaxf(sf[0][0], sf[0][1]), fmaxf(sf[0][2], sf[0][3]));
    nm = fmaxf(nm, fmaxf(fmaxf(sf[1][0], sf[1][1]), fmaxf(sf[1][2], sf[1][3])));
    nm = fmaxf(nm, fmaxf(fmaxf(sf[2][0], sf[2][1]), fmaxf(sf[2][2], sf[2][3])));
    nm = fmaxf(nm, fmaxf(fmaxf(sf[3][0], sf[3][1]), fmaxf(sf[3][2], sf[3][3])));
    nm = fmaxf(nm, __shfl_xor(nm, 16));
    nm = fmaxf(nm, __shfl_xor(nm, 32));

    if (__any(nm > mi + 20.f)) {
      const float mn = fmaxf(mi, nm);
      const float al = exp2f(mi - mn);
      mi = mn;
      #pragma unroll
      for (int nt = 0; nt < 8; ++nt) {
        Of[nt][0] *= al; Of[nt][1] *= al; Of[nt][2] *= al; Of[nt][3] *= al;
      }
      Of8[0] *= al; Of8[1] *= al; Of8[2] *= al; Of8[3] *= al;
    }

    // P = exp2(S - mi), Schraudolph bits, packed in-register into B-fragments:
    // pk[ks].u[p] = {P(kb=2ks+(p>>1), r=2(p&1)) lo16, r=2(p&1)+1 hi16}
    const float base = 1064866805.0f - mi*8388608.0f;
    union { short8 v; unsigned int u[4]; } pk[2];
    #pragma unroll
    for (int kb = 0; kb < 4; ++kb) {
      int p0 = (int)(sf[kb][0]*8388608.0f + base); p0 = p0 < 0 ? 0 : p0;
      int p1 = (int)(sf[kb][1]*8388608.0f + base); p1 = p1 < 0 ? 0 : p1;
      int p2 = (int)(sf[kb][2]*8388608.0f + base); p2 = p2 < 0 ? 0 : p2;
      int p3 = (int)(sf[kb][3]*8388608.0f + base); p3 = p3 < 0 ? 0 : p3;
      pk[kb >> 1].u[(kb & 1)*2 + 0] = ((unsigned)p0 >> 16) | ((unsigned)p1 & 0xffff0000u);
      pk[kb >> 1].u[(kb & 1)*2 + 1] = ((unsigned)p2 >> 16) | ((unsigned)p3 & 0xffff0000u);
    }

    // O^T += V^T P^T : A = V^T fragment from permuted LDS, B = pk (in-register)
    #pragma unroll
    for (int ks = 0; ks < 2; ++ks) {
      #pragma unroll
      for (int nt = 0; nt < 8; ++nt) {
        const short8 av = *(const short8*)&Vs[(nt*16 + m)*64 + (((ks*4 + quad) ^ x7) * 8)];
        Of[nt] = __builtin_amdgcn_mfma_f32_16x16x32_bf16(av, pk[ks].v, Of[nt], 0, 0, 0);
      }
      Of8 = __builtin_amdgcn_mfma_f32_16x16x32_bf16(onesf.v, pk[ks].v, Of8, 0, 0, 0);
    }
  }

  // denom lives at quad==0 lanes (C row 0), broadcast via LDS
  if (quad == 0) li_s[wave*16 + m] = Of8[0];
  __syncthreads();
  const float linv = 1.0f / li_s[wave*16 + m];

  ushort* Po = (s == 0) ? Po0 : ((s == 1) ? Po1 : ((s == 2) ? Po2 : Po3));
  const int n = n0q + wave*16 + m;
  #pragma unroll
  for (int nt = 0; nt < 8; ++nt) {
    unsigned int lo = (unsigned)f2bf(Of[nt][0] * linv) | ((unsigned)f2bf(Of[nt][1] * linv) << 16);
    unsigned int hi = (unsigned)f2bf(Of[nt][2] * linv) | ((unsigned)f2bf(Of[nt][3] * linv) << 16);
    uint2 pkd; pkd.x = lo; pkd.y = hi;
    *(uint2*)&Po[((size_t)h*N_ + n)*128 + nt*16 + quad*4] = pkd;
  }
  if (quad == 0) {
    Pml[(((size_t)s*8 + h)*N_ + n)*2 + 0] = mi;
    Pml[(((size_t)s*8 + h)*N_ + n)*2 + 1] = Of8[0];
  }
}

// ---------------- merge: combine 4 split-K partials (8 elems/thread) ------------
__global__ __launch_bounds__(256) void k_merge(
    const ushort* __restrict__ Po0, const ushort* __restrict__ Po1,
    const ushort* __restrict__ Po2, const ushort* __restrict__ Po3,
    const float* __restrict__ Pml,
    ushort* __restrict__ out_v_b, ushort* __restrict__ out_g_b)
{
  const int idx = blockIdx.x*256 + threadIdx.x;
  const int c0 = (idx & 15) * 8;
  const int n  = (idx >> 4) & 4095;
  const int h  = idx >> 16;
  float mm[4], ll[4];
  #pragma unroll
  for (int s = 0; s < 4; ++s) {
    mm[s] = Pml[(((size_t)s*8 + h)*N_ + n)*2 + 0];
    ll[s] = Pml[(((size_t)s*8 + h)*N_ + n)*2 + 1];
  }
  const float M = fmaxf(fmaxf(mm[0], mm[1]), fmaxf(mm[2], mm[3]));
  float w[4], tot = 0.f;
  #pragma unroll
  for (int s = 0; s < 4; ++s) { w[s] = exp2f(mm[s] - M) * ll[s]; tot += w[s]; }
  const float inv = 1.0f / tot;
  union { short8 v; ushort u[8]; } a, b, c, d, res;
  a.v = *(const short8*)&Po0[((size_t)h*N_ + n)*128 + c0];
  b.v = *(const short8*)&Po1[((size_t)h*N_ + n)*128 + c0];
  c.v = *(const short8*)&Po2[((size_t)h*N_ + n)*128 + c0];
  d.v = *(const short8*)&Po3[((size_t)h*N_ + n)*128 + c0];
  #pragma unroll
  for (int j = 0; j < 8; ++j)
    res.u[j] = f2bf((w[0]*bf2f(a.u[j]) + w[1]*bf2f(b.u[j]) +
                     w[2]*bf2f(c.u[j]) + w[3]*bf2f(d.u[j])) * inv);
  if (c0 < 32) {
    *(short8*)&out_v_b[(size_t)n*256 + h*32 + c0] = res.v;
  } else {
    const int j = (c0 - 32) >> 5, cc = (c0 - 32) & 31;
    *(short8*)&out_g_b[((size_t)n*3 + j)*256 + h*32 + cc] = res.v;
  }
}

// ---------------- k5a+k5b fused ----------------
__global__ __launch_bounds__(256) void k56ab(
    const ushort* __restrict__ out_v_b, const ushort* __restrict__ Wngt,
    const float* __restrict__ b_ng, const float* __restrict__ h,
    ushort* __restrict__ tmp_b,
    const ushort* __restrict__ out_g_b, const ushort* __restrict__ Wgoutt,
    ushort* __restrict__ gsum_b)
{
  __shared__ __align__(16) ushort As[64*72], Bs[64*72];
  floatx4 acc[4];
  const int lane = threadIdx.x & 63, wave = threadIdx.x >> 6;
  const int quad = lane >> 4, m = lane & 15;
  const int bN = blockIdx.y*64;
  if (blockIdx.x < 64) {
    const int bM = blockIdx.x*64;
    gemm_core<256>(out_v_b, Wngt, bM, bN, acc, As, Bs);
    #pragma unroll
    for (int ct = 0; ct < 4; ++ct) {
      const int c = bN + ct*16 + m;
      #pragma unroll
      for (int r = 0; r < 4; ++r) {
        const int i = bM + wave*16 + quad*4 + r;
        tmp_b[(size_t)i*256 + c] =
            f2bf(acc[ct][r] + b_ng[c] + h[(size_t)i*256 + c] * SQRT_E);
      }
    }
  } else {
    const int bM = (blockIdx.x - 64)*64;
    gemm_core<256>(out_g_b, Wgoutt, bM, bN, acc, As, Bs);
    #pragma unroll
    for (int ct = 0; ct < 4; ++ct) {
      const int c = bN + ct*16 + m;
      #pragma unroll
      for (int r = 0; r < 4; ++r) {
        const int i = bM + wave*16 + quad*4 + r;
        gsum_b[(size_t)i*256 + c] = f2bf(acc[ct][r]);
      }
    }
  }
}

// ---------------- k5c+k5d fused ----------------
__global__ __launch_bounds__(256) void k56cd(
    const ushort* __restrict__ tmp_b, const ushort* __restrict__ Whdect,
    const float* __restrict__ b_hdec,
    const ushort* __restrict__ gsum_b, const ushort* __restrict__ Wgdect,
    const float* __restrict__ pre0,
    float* __restrict__ out)
{
  __shared__ __align__(16) ushort As[64*72], Bs[64*72];
  const int t = threadIdx.x;
  const int lane = t & 63, wave = t >> 6;
  const int quad = lane >> 4, m = lane & 15;
  if (blockIdx.x < 64) {
    floatx4 acc[4];
    const int bM = blockIdx.x*64, bN = blockIdx.y*64;
    gemm_core<256>(tmp_b, Whdect, bM, bN, acc, As, Bs);
    #pragma unroll
    for (int ct = 0; ct < 4; ++ct) {
      const int c = bN + ct*16 + m;
      #pragma unroll
      for (int r = 0; r < 4; ++r) {
        const int i = bM + wave*16 + quad*4 + r;
        out[196608 + (size_t)i*256 + c] = acc[ct][r] + b_hdec[c];
      }
    }
  } else if (blockIdx.y == 0) {
    const int bM = (blockIdx.x - 64)*64;
    floatx4 acc = {0.f, 0.f, 0.f, 0.f};
    const int row = t >> 2, kq = (t & 3) * 8;
    for (int k0 = 0; k0 < 256; k0 += 32) {
      __syncthreads();
      *(short8*)&As[row*40 + kq] = *(const short8*)&gsum_b[(size_t)(bM+row)*256 + k0 + kq];
      if (t < 64)
        *(short8*)&Bs[(t>>2)*40 + kq] = *(const short8*)&Wgdect[(size_t)(t>>2)*256 + k0 + kq];
      __syncthreads();
      const short8 af = *(const short8*)&As[(wave*16 + m)*40 + quad*8];
      const short8 bf = *(const short8*)&Bs[m*40 + quad*8];
      acc = __builtin_amdgcn_mfma_f32_16x16x32_bf16(af, bf, acc, 0, 0, 0);
    }
    #pragma unroll
    for (int r = 0; r < 4; ++r) {
      const int i3 = bM + wave*16 + quad*4 + r;
      out[(size_t)i3*16 + m] = acc[r] + pre0[(size_t)i3*16 + m];
    }
  }
}

extern "C" void kernel_launch(void* const* d_in, const int* in_sizes, int n_in,
                              void* d_out, int out_size, void* d_ws, size_t ws_size,
                              hipStream_t stream) {
  const float* equ    = (const float*)d_in[0];
  const float* h      = (const float*)d_in[1];
  const float* W_equ  = (const float*)d_in[4];
  const float* W_gproj= (const float*)d_in[5];
  const float* W_vg   = (const float*)d_in[6];
  const float* W_g1   = (const float*)d_in[7];
  const float* b_g1   = (const float*)d_in[8];
  const float* W_g2   = (const float*)d_in[9];
  const float* b_g2   = (const float*)d_in[10];
  const float* W_q    = (const float*)d_in[11];
  const float* b_q    = (const float*)d_in[12];
  const float* W_k    = (const float*)d_in[13];
  const float* b_k    = (const float*)d_in[14];
  const float* W_v    = (const float*)d_in[15];
  const float* b_v    = (const float*)d_in[16];
  const float* W_ng   = (const float*)d_in[17];
  const float* b_ng   = (const float*)d_in[18];
  const float* W_gout = (const float*)d_in[19];
  const float* W_gdec = (const float*)d_in[20];
  const float* W_hdec = (const float*)d_in[21];
  const float* b_hdec = (const float*)d_in[22];
  float* out = (float*)d_out;

  // ---- workspace layout (lifetimes annotated), peak 50.4 MiB (52 proven) ----
  // Stages: P=prep G1 G2 G3/G4 A=attn M=merge B=k56ab C=k56cd
  char* wsb = (char*)d_ws;
  constexpr size_t MiB = 1048576;
  float*  q_ws    = (float*) (wsb +  0*MiB);            // 4 MiB   [G3 -> A]
  ushort* kh      = (ushort*)(wsb +  4*MiB);            // 2 MiB   [G3 -> A]
  float*  Pml     = (float*) (wsb +  6*MiB);            // 1 MiB   [A -> M] (4 splits)
  float*  pre0    = (float*) (wsb +  7*MiB);            // 0.75 MiB[P -> C]
  ushort* vt      = (ushort*)(wsb +  8*MiB);            // 8 MiB   [G4 -> A]
  ushort* h2h     = (ushort*)(wsb + 17*MiB);            // 4 MiB   [P/G2 -> G3/G4]
  ushort* h2l     = (ushort*)(wsb + 21*MiB);            // 4 MiB
  ushort* g_src_b = (ushort*)(wsb + 25*MiB);            // 6 MiB   [P -> G4]
  ushort* wbase   = (ushort*)(wsb + 31*MiB);            // 2.875 MiB [P -> G3/G4]
  ushort* Wg1t = wbase;                                 // 512x1024
  ushort* Wg2t = wbase + 524288;                        // 256x512
  ushort* Wth  = wbase + 655360;                        // 768x512 hi
  ushort* Wtl  = wbase + 1048576;                       // 768x512 lo
  ushort* Wvgt = wbase + 1441792;                       // 256x256
  ushort* gram_b  = (ushort*)(wsb + 34*MiB);            // 8 MiB   [P -> G1]
  ushort* hidden  = (ushort*)(wsb + 42*MiB);            // 4 MiB   [G1 -> G2]
  // split-K x4 attention partials (all alias dead regions):
  ushort* Po0     = (ushort*)(wsb + 17*MiB);            // 8 MiB [A -> M] alias h2h/h2l
  ushort* Po1     = (ushort*)(wsb + 25*MiB);            // 8 MiB [A -> M] alias g_src_b+wbase
  ushort* Po2     = (ushort*)(wsb + 34*MiB);            // 8 MiB [A -> M] alias gram_b
  ushort* Po3     = (ushort*)(wsb + 42*MiB);            // 8 MiB [A -> M] alias hidden+
  ushort* wbase2  = (ushort*)(wsb + 50*MiB);            // 0.4 MiB [P -> B/C]
  ushort* Wngt   = wbase2;                              // 256x256
  ushort* Wgoutt = wbase2 + 65536;                      // 256x256
  ushort* Whdect = wbase2 + 131072;                     // 256x256
  ushort* Wgdect = wbase2 + 196608;                     // 16x256
  ushort* out_v_b = (ushort*)(wsb +  4*MiB);            // 2 MiB [M -> B] alias kh
  ushort* out_g_b = (ushort*)(wsb +  8*MiB);            // 6 MiB [M -> B] alias vt
  ushort* tmp_b   = (ushort*)(wsb + 17*MiB);            // 2 MiB [B -> C] alias Po0
  ushort* gsum_b  = (ushort*)(wsb + 25*MiB);            // 6 MiB [B -> C] alias Po1

  // ---- 1 mega-prep launch (10 transposes + hsplit + k1 + pre0) ----
  k_prep<<<9480, 256, 0, stream>>>(
      equ, h, W_equ, W_gproj, W_g1, W_g2, W_q, W_k, W_v,
      W_vg, W_ng, W_gout, W_hdec, W_gdec,
      Wg1t, Wg2t, Wth, Wtl, Wvgt, Wngt, Wgoutt, Whdect, Wgdect,
      h2h, h2l, g_src_b, gram_b, pre0);

  // ---- GEMM chain (BK=64 double-pumped cores) ----
  k_g1<<<dim3(64, 8), 256, 0, stream>>>(gram_b, Wg1t, b_g1, hidden);
  k_g2<<<dim3(64, 4), 256, 0, stream>>>(hidden, Wg2t, b_g2, h2h, h2l);
  k_g3<<<dim3(64, 8), 256, 0, stream>>>(h2h, h2l, Wth, Wtl, b_q, b_k, q_ws, kh);
  k_g4<<<1024, 256, 0, stream>>>(h2h, Wth, b_v, g_src_b, Wvgt, vt);

  // ---- attention (8-wave blocks, swapped-operand, in-reg P, split-K x4) ----
  dim3 g3(32, 8, 4);
  k3_attn<<<g3, 512, 0, stream>>>(q_ws, kh, vt, Po0, Po1, Po2, Po3, Pml);
  k_merge<<<2048, 256, 0, stream>>>(Po0, Po1, Po2, Po3, Pml, out_v_b, out_g_b);

  // ---- epilogue GEMMs (fused pairs) ----
  k56ab<<<dim3(256, 4), 256, 0, stream>>>(out_v_b, Wngt, b_ng, h, tmp_b,
                                          out_g_b, Wgoutt, gsum_b);
  k56cd<<<dim3(256, 4), 256, 0, stream>>>(tmp_b, Whdect, b_hdec,
                                          gsum_b, Wgdect, pre0, out);
}

// Round 15
// 262.871 us; speedup vs baseline: 1.0168x; 1.0168x over previous
//
#include <hip/hip_runtime.h>
#include <hip/hip_bf16.h>

typedef __attribute__((ext_vector_type(8))) short short8;
typedef __attribute__((ext_vector_type(4))) short bhalf4;
typedef __attribute__((ext_vector_type(4))) float floatx4;

constexpr int N_ = 4096;
constexpr float SQRT_E = 16.0f;
// q scale folded with log2(e): softmax computed in exp2 domain
constexpr float QSCALE = 0.17677669529663687f * 1.4426950408889634f;

__device__ __forceinline__ ushort f2bf(float x) {
  __hip_bfloat16 h = __float2bfloat16(x);
  return *reinterpret_cast<ushort*>(&h);
}
__device__ __forceinline__ float bf2f(ushort b) {
  unsigned int u = ((unsigned int)b) << 16;
  return __uint_as_float(u);
}

// ---------------- transpose helper (device side of mega-prep) ----------------
__device__ __forceinline__ void do_transpose(
    const float* __restrict__ src, ushort* __restrict__ dsth,
    ushort* __restrict__ dstl, int R, int C, int lb, int cb_shift,
    float* smem, int hasLo)
{
  float (*tile)[33] = (float(*)[33])smem;
  const int r0 = (lb >> cb_shift) * 32;
  const int c0 = (lb & ((1 << cb_shift) - 1)) * 32;
  const int tx = threadIdx.x & 31, ty = threadIdx.x >> 5;
  #pragma unroll
  for (int p = 0; p < 4; ++p) {
    const int lr = p*8 + ty;
    tile[lr][tx] = (r0+lr < R && c0+tx < C) ? src[(size_t)(r0+lr)*C + c0 + tx] : 0.f;
  }
  __syncthreads();
  #pragma unroll
  for (int p = 0; p < 4; ++p) {
    const int dc = p*8 + ty;
    if (c0+dc < C && r0+tx < R) {
      const float v = tile[tx][dc];
      const ushort hi = f2bf(v);
      dsth[(size_t)(c0+dc)*R + r0 + tx] = hi;
      if (hasLo) dstl[(size_t)(c0+dc)*R + r0 + tx] = f2bf(v - bf2f(hi));
    }
  }
}

// ---------------- mega-prep: all transposes + hsplit + k1 in ONE launch --------
__global__ __launch_bounds__(256) void k_prep(
    const float* __restrict__ equ, const float* __restrict__ h,
    const float* __restrict__ W_equ, const float* __restrict__ W_gproj,
    const float* __restrict__ W_g1, const float* __restrict__ W_g2,
    const float* __restrict__ W_q, const float* __restrict__ W_k,
    const float* __restrict__ W_v, const float* __restrict__ W_vg,
    const float* __restrict__ W_ng, const float* __restrict__ W_gout,
    const float* __restrict__ W_hdec, const float* __restrict__ W_gdec,
    ushort* __restrict__ Wg1t, ushort* __restrict__ Wg2t,
    ushort* __restrict__ Wth, ushort* __restrict__ Wtl,
    ushort* __restrict__ Wvgt, ushort* __restrict__ Wngt,
    ushort* __restrict__ Wgoutt, ushort* __restrict__ Whdect,
    ushort* __restrict__ Wgdect,
    ushort* __restrict__ h2h, ushort* __restrict__ h2l,
    ushort* __restrict__ g_src_b, ushort* __restrict__ gram_b,
    float* __restrict__ pre0)
{
  __shared__ __align__(16) float smem[1120];
  const int b = blockIdx.x;
  const int t = threadIdx.x;

  if (b < 512) {            // W_g1 [1024,512] -> Wg1t
    do_transpose(W_g1, Wg1t, nullptr, 1024, 512, b, 4, smem, 0);
  } else if (b < 640) {     // W_g2 [512,256]
    do_transpose(W_g2, Wg2t, nullptr, 512, 256, b-512, 3, smem, 0);
  } else if (b < 768) {     // W_q hi/lo
    do_transpose(W_q, Wth, Wtl, 512, 256, b-640, 3, smem, 1);
  } else if (b < 896) {     // W_k hi/lo
    do_transpose(W_k, Wth + 256*512, Wtl + 256*512, 512, 256, b-768, 3, smem, 1);
  } else if (b < 1024) {    // W_v hi/lo
    do_transpose(W_v, Wth + 512*512, Wtl + 512*512, 512, 256, b-896, 3, smem, 1);
  } else if (b < 1088) {    // W_vg
    do_transpose(W_vg, Wvgt, nullptr, 256, 256, b-1024, 3, smem, 0);
  } else if (b < 1152) {    // W_ng
    do_transpose(W_ng, Wngt, nullptr, 256, 256, b-1088, 3, smem, 0);
  } else if (b < 1216) {    // W_gout
    do_transpose(W_gout, Wgoutt, nullptr, 256, 256, b-1152, 3, smem, 0);
  } else if (b < 1280) {    // W_hdec
    do_transpose(W_hdec, Whdect, nullptr, 256, 256, b-1216, 3, smem, 0);
  } else if (b < 1288) {    // W_gdec [256,16]
    do_transpose(W_gdec, Wgdect, nullptr, 256, 16, b-1280, 0, smem, 0);
  } else if (b < 5384) {    // hsplit: h_src half of h2 (hi/lo)
    const int i = b - 1288;
    const float v = h[(size_t)i*256 + t] * SQRT_E;
    const ushort hi = f2bf(v);
    h2h[(size_t)i*512 + 256 + t] = hi;
    h2l[(size_t)i*512 + 256 + t] = f2bf(v - bf2f(hi));
  } else {                  // k1: g_src_b + gram_b + pre0
    float* eq   = smem;        // 48
    float* gs   = smem + 48;   // 768
    float* g2p  = smem + 816;  // 96
    float* part = smem + 912;  // 192
    const int i = b - 5384;
    if (t < 48) eq[t] = equ[(size_t)i*48 + t];
    __syncthreads();
    #pragma unroll
    for (int j = 0; j < 3; ++j) {
      float s = 0.f;
      #pragma unroll
      for (int m = 0; m < 16; ++m) s += eq[j*16+m] * W_equ[m*256 + t];
      s *= SQRT_E;
      gs[j*256 + t] = s;
      g_src_b[((size_t)i*3 + j)*256 + t] = f2bf(s);
    }
    __syncthreads();
    if (t < 192) {            // 2-way K-split of the gproj GEMV
      const int o = t % 96, half = t / 96;
      const int j = o >> 5, a = o & 31;
      const int e0 = half * 128;
      float s = 0.f;
      for (int e = 0; e < 128; ++e)
        s += gs[j*256 + e0 + e] * W_gproj[(size_t)(e0+e)*32 + a];
      part[t] = s;
    }
    __syncthreads();
    if (t < 96) g2p[t] = part[t] + part[96 + t];
    __syncthreads();
    #pragma unroll
    for (int r = 0; r < 4; ++r) {
      const int idx = r*256 + t;
      const int a = idx >> 5, bb = idx & 31;
      const float s = g2p[a]*g2p[bb] + g2p[32+a]*g2p[32+bb] + g2p[64+a]*g2p[64+bb];
      gram_b[(size_t)i*1024 + idx] = f2bf(s);
    }
    // pre0 = g_src(f32) @ W_gdec, 4-way K-split. t = j*64 + ks*16 + mc
    if (t < 192) {
      const int j = t >> 6, ks = (t >> 4) & 3, mc = t & 15;
      const int e0 = ks * 64;
      float s = 0.f;
      for (int e = 0; e < 64; ++e)
        s += gs[j*256 + e0 + e] * W_gdec[(size_t)(e0 + e)*16 + mc];
      part[t] = s;
    }
    __syncthreads();
    if (t < 48) {
      const int j = t >> 4, mc = t & 15;
      pre0[((size_t)i*3 + j)*16 + mc] =
          part[j*64 + mc] + part[j*64 + 16 + mc] +
          part[j*64 + 32 + mc] + part[j*64 + 48 + mc];
    }
  }
}

// ---------------- GEMM cores: BK=64, double-pumped, register prefetch -----------
template<int KTOT>
__device__ __forceinline__ void gemm_core(
    const ushort* __restrict__ A, const ushort* __restrict__ Bt,
    int bM, int bN, floatx4 acc[4], ushort* As, ushort* Bs)
{
  const int t = threadIdx.x;
  const int wave = t >> 6, lane = t & 63, quad = lane >> 4, m = lane & 15;
  #pragma unroll
  for (int ct = 0; ct < 4; ++ct) acc[ct] = {0.f, 0.f, 0.f, 0.f};
  const int ca = t*2, cb = t*2 + 1;
  const int ra = ca >> 3, pa = ca & 7;
  const int rb = cb >> 3, pb = cb & 7;
  const ushort* pA0 = A  + (size_t)(bM+ra)*KTOT + pa*8;
  const ushort* pA1 = A  + (size_t)(bM+rb)*KTOT + pb*8;
  const ushort* pB0 = Bt + (size_t)(bN+ra)*KTOT + pa*8;
  const ushort* pB1 = Bt + (size_t)(bN+rb)*KTOT + pb*8;
  short8 rA0 = *(const short8*)pA0, rA1 = *(const short8*)pA1;
  short8 rB0 = *(const short8*)pB0, rB1 = *(const short8*)pB1;
  for (int k0 = 0; k0 < KTOT; k0 += 64) {
    __syncthreads();
    *(short8*)&As[ra*72 + pa*8] = rA0;
    *(short8*)&As[rb*72 + pb*8] = rA1;
    *(short8*)&Bs[ra*72 + pa*8] = rB0;
    *(short8*)&Bs[rb*72 + pb*8] = rB1;
    if (k0 + 64 < KTOT) {
      pA0 += 64; pA1 += 64; pB0 += 64; pB1 += 64;
      rA0 = *(const short8*)pA0; rA1 = *(const short8*)pA1;
      rB0 = *(const short8*)pB0; rB1 = *(const short8*)pB1;
    }
    __syncthreads();
    #pragma unroll
    for (int ks = 0; ks < 2; ++ks) {
      const short8 af = *(const short8*)&As[(wave*16 + m)*72 + ks*32 + quad*8];
      #pragma unroll
      for (int ct = 0; ct < 4; ++ct) {
        const short8 bf = *(const short8*)&Bs[(ct*16 + m)*72 + ks*32 + quad*8];
        acc[ct] = __builtin_amdgcn_mfma_f32_16x16x32_bf16(af, bf, acc[ct], 0, 0, 0);
      }
    }
  }
}

template<int KTOT>
__device__ __forceinline__ void gemm_core3(
    const ushort* __restrict__ Ah, const ushort* __restrict__ Al,
    const ushort* __restrict__ Bth, const ushort* __restrict__ Btl,
    int bM, int bN, floatx4 acc[4],
    ushort* Ash, ushort* Asl, ushort* Bsh, ushort* Bsl)
{
  const int t = threadIdx.x;
  const int wave = t >> 6, lane = t & 63, quad = lane >> 4, m = lane & 15;
  #pragma unroll
  for (int ct = 0; ct < 4; ++ct) acc[ct] = {0.f, 0.f, 0.f, 0.f};
  const int ca = t*2, cb = t*2 + 1;
  const int ra = ca >> 3, pa = ca & 7;
  const int rb = cb >> 3, pb = cb & 7;
  const ushort* pAh0 = Ah  + (size_t)(bM+ra)*KTOT + pa*8;
  const ushort* pAh1 = Ah  + (size_t)(bM+rb)*KTOT + pb*8;
  const ushort* pAl0 = Al  + (size_t)(bM+ra)*KTOT + pa*8;
  const ushort* pAl1 = Al  + (size_t)(bM+rb)*KTOT + pb*8;
  const ushort* pBh0 = Bth + (size_t)(bN+ra)*KTOT + pa*8;
  const ushort* pBh1 = Bth + (size_t)(bN+rb)*KTOT + pb*8;
  const ushort* pBl0 = Btl + (size_t)(bN+ra)*KTOT + pa*8;
  const ushort* pBl1 = Btl + (size_t)(bN+rb)*KTOT + pb*8;
  short8 rAh0 = *(const short8*)pAh0, rAh1 = *(const short8*)pAh1;
  short8 rAl0 = *(const short8*)pAl0, rAl1 = *(const short8*)pAl1;
  short8 rBh0 = *(const short8*)pBh0, rBh1 = *(const short8*)pBh1;
  short8 rBl0 = *(const short8*)pBl0, rBl1 = *(const short8*)pBl1;
  for (int k0 = 0; k0 < KTOT; k0 += 64) {
    __syncthreads();
    *(short8*)&Ash[ra*72 + pa*8] = rAh0;
    *(short8*)&Ash[rb*72 + pb*8] = rAh1;
    *(short8*)&Asl[ra*72 + pa*8] = rAl0;
    *(short8*)&Asl[rb*72 + pb*8] = rAl1;
    *(short8*)&Bsh[ra*72 + pa*8] = rBh0;
    *(short8*)&Bsh[rb*72 + pb*8] = rBh1;
    *(short8*)&Bsl[ra*72 + pa*8] = rBl0;
    *(short8*)&Bsl[rb*72 + pb*8] = rBl1;
    if (k0 + 64 < KTOT) {
      pAh0 += 64; pAh1 += 64; pAl0 += 64; pAl1 += 64;
      pBh0 += 64; pBh1 += 64; pBl0 += 64; pBl1 += 64;
      rAh0 = *(const short8*)pAh0; rAh1 = *(const short8*)pAh1;
      rAl0 = *(const short8*)pAl0; rAl1 = *(const short8*)pAl1;
      rBh0 = *(const short8*)pBh0; rBh1 = *(const short8*)pBh1;
      rBl0 = *(const short8*)pBl0; rBl1 = *(const short8*)pBl1;
    }
    __syncthreads();
    #pragma unroll
    for (int ks = 0; ks < 2; ++ks) {
      const short8 ah = *(const short8*)&Ash[(wave*16 + m)*72 + ks*32 + quad*8];
      const short8 al = *(const short8*)&Asl[(wave*16 + m)*72 + ks*32 + quad*8];
      #pragma unroll
      for (int ct = 0; ct < 4; ++ct) {
        const short8 bh = *(const short8*)&Bsh[(ct*16 + m)*72 + ks*32 + quad*8];
        const short8 bl = *(const short8*)&Bsl[(ct*16 + m)*72 + ks*32 + quad*8];
        acc[ct] = __builtin_amdgcn_mfma_f32_16x16x32_bf16(ah, bl, acc[ct], 0, 0, 0);
        acc[ct] = __builtin_amdgcn_mfma_f32_16x16x32_bf16(al, bh, acc[ct], 0, 0, 0);
        acc[ct] = __builtin_amdgcn_mfma_f32_16x16x32_bf16(ah, bh, acc[ct], 0, 0, 0);
      }
    }
  }
}

// G1: hidden = relu(gram @ W_g1 + b_g1)
__global__ __launch_bounds__(256) void k_g1(
    const ushort* __restrict__ gram_b, const ushort* __restrict__ Wg1t,
    const float* __restrict__ b_g1, ushort* __restrict__ hidden)
{
  __shared__ __align__(16) ushort As[64*72], Bs[64*72];
  floatx4 acc[4];
  const int bM = blockIdx.x*64, bN = blockIdx.y*64;
  gemm_core<1024>(gram_b, Wg1t, bM, bN, acc, As, Bs);
  const int lane = threadIdx.x & 63, wave = threadIdx.x >> 6;
  const int quad = lane >> 4, m = lane & 15;
  #pragma unroll
  for (int ct = 0; ct < 4; ++ct) {
    const int c = bN + ct*16 + m;
    #pragma unroll
    for (int r = 0; r < 4; ++r) {
      const int i = bM + wave*16 + quad*4 + r;
      hidden[(size_t)i*512 + c] = f2bf(fmaxf(acc[ct][r] + b_g1[c], 0.f));
    }
  }
}

// G2: g2 = hidden @ W_g2 + b_g2 -> hi/lo into h2 cols 0..255
__global__ __launch_bounds__(256) void k_g2(
    const ushort* __restrict__ hidden, const ushort* __restrict__ Wg2t,
    const float* __restrict__ b_g2, ushort* __restrict__ h2h, ushort* __restrict__ h2l)
{
  __shared__ __align__(16) ushort As[64*72], Bs[64*72];
  floatx4 acc[4];
  const int bM = blockIdx.x*64, bN = blockIdx.y*64;
  gemm_core<512>(hidden, Wg2t, bM, bN, acc, As, Bs);
  const int lane = threadIdx.x & 63, wave = threadIdx.x >> 6;
  const int quad = lane >> 4, m = lane & 15;
  #pragma unroll
  for (int ct = 0; ct < 4; ++ct) {
    const int c = bN + ct*16 + m;
    #pragma unroll
    for (int r = 0; r < 4; ++r) {
      const int i = bM + wave*16 + quad*4 + r;
      const float s = acc[ct][r] + b_g2[c];
      const ushort hi = f2bf(s);
      h2h[(size_t)i*512 + c] = hi;
      h2l[(size_t)i*512 + c] = f2bf(s - bf2f(hi));
    }
  }
}

// G3+G4 fused: q/k hi/lo 3-term; v 1-term; vg 1-term. vt = [head][d 0..127][n].
// NOTE (r14): splitting this into separate g3/g4 kernels REGRESSED +6 us —
// the mixed heavy/light 1536-block grid load-balances better than two
// dispatches with separate tails. Keep monolithic.
__global__ __launch_bounds__(256) void k_g34(
    const ushort* __restrict__ h2h, const ushort* __restrict__ h2l,
    const ushort* __restrict__ Wth, const ushort* __restrict__ Wtl,
    const float* __restrict__ b_q, const float* __restrict__ b_k,
    const float* __restrict__ b_v,
    const ushort* __restrict__ g_src_b, const ushort* __restrict__ Wvgt,
    float* __restrict__ q_ws, ushort* __restrict__ kh,
    ushort* __restrict__ vt)
{
  __shared__ __align__(16) ushort S0[64*72], S1[64*72], S2[64*72], S3[64*72];
  const int lb = blockIdx.y*192 + blockIdx.x;     // grid (192,8) = 1536
  const int lane = threadIdx.x & 63, wave = threadIdx.x >> 6;
  const int quad = lane >> 4, m = lane & 15;
  floatx4 acc[4];
  if (lb < 768) {
    const int bM = (lb & 63)*64, bN = (lb >> 6)*64;
    if (bN < 512) {
      gemm_core3<512>(h2h, h2l, Wth, Wtl, bM, bN, acc, S0, S1, S2, S3);
      #pragma unroll
      for (int ct = 0; ct < 4; ++ct) {
        const int c = bN + ct*16 + m;
        #pragma unroll
        for (int r = 0; r < 4; ++r) {
          const int i = bM + wave*16 + quad*4 + r;
          if (c < 256) {
            const float s = acc[ct][r] + b_q[c];
            q_ws[((size_t)(c >> 5)*N_ + i)*32 + (c & 31)] = s * QSCALE;
          } else {
            const int cc = c - 256;
            const float s = acc[ct][r] + b_k[cc];
            kh[((size_t)(cc >> 5)*N_ + i)*32 + (cc & 31)] = f2bf(s);
          }
        }
      }
    } else {
      gemm_core<512>(h2h, Wth, bM, bN, acc, S0, S1);
      #pragma unroll
      for (int ct = 0; ct < 4; ++ct) {
        const int cc = bN + ct*16 + m - 512;
        #pragma unroll
        for (int r = 0; r < 4; ++r) {
          const int i = bM + wave*16 + quad*4 + r;
          const float s = acc[ct][r] + b_v[cc];
          vt[((size_t)(cc >> 5)*128 + (cc & 31))*N_ + i] = f2bf(s);
        }
      }
    }
  } else {
    const int lb2 = lb - 768;
    const int bM = (lb2 >> 2)*64, bN = (lb2 & 3)*64;
    gemm_core<256>(g_src_b, Wvgt, bM, bN, acc, S0, S1);
    #pragma unroll
    for (int ct = 0; ct < 4; ++ct) {
      const int c = bN + ct*16 + m;
      const int hh = c >> 5, d = c & 31;
      #pragma unroll
      for (int r = 0; r < 4; ++r) {
        const int i3 = bM + wave*16 + quad*4 + r;
        const int i = i3 / 3, j = i3 - 3*i;
        vt[((size_t)hh*128 + 32 + j*32 + d)*N_ + i] = f2bf(acc[ct][r]);
      }
    }
  }
}

// ---------------- K3: swapped-operand flash attention, P fully in-register -----
// mfma(K,Q) gives S^T with q = lane&15 -> softmax is lane-local. V columns are
// stored bit-permuted in LDS (slot{5..0} = {k5,k3,k2,k4,k1,k0}) so each lane's
// own 16 P values form its PV B-fragment directly: no P LDS buffer, no cross-
// lane exchange. PV swapped too (O^T = V^T P^T). Denominator = ones-row MFMA.
// 8-wave blocks (512 thr, 128 q-rows). Grid (32,8,4)=1024 = 4 blk/CU resident.
// __launch_bounds__(512,4): proven 56-VGPR codegen (75 us, rounds 9/11/13).
// LESSONS: (r10) doubling accumulator state spills (~64 live VGPR budget);
// (r12) fixed-base exp2 softmax NaNs — the online max is load-bearing;
// (r14) splitting k_g34 regressed (mixed-grid load balance beats LDS-union).
__global__ __launch_bounds__(512, 4) void k3_attn(
    const float* __restrict__ q_ws, const ushort* __restrict__ kh,
    const ushort* __restrict__ vt,
    ushort* __restrict__ Po0, ushort* __restrict__ Po1,
    ushort* __restrict__ Po2, ushort* __restrict__ Po3,
    float* __restrict__ Pml)
{
  __shared__ __align__(16) ushort Khs[64*40];              // 5 KiB
  __shared__ __align__(16) ushort Vs[128*64];              // 16 KiB, permuted+swizzled
  __shared__ float li_s[128];

  const int t    = threadIdx.x;          // 0..511
  const int wave = t >> 6;               // 0..7
  const int lane = t & 63;
  const int quad = lane >> 4;
  const int m    = lane & 15;
  const int h    = blockIdx.y;
  const int s    = blockIdx.z;
  const int n0q  = blockIdx.x * 128;

  const int ktb = s * 16;
  const int kte = ktb + 16;

  // Q fragment (B-operand; rows n0q + wave*16 + m, wave in [0,8))
  union { short8 v; ushort u[8]; } Aqh, Aql;
  {
    const float* qp = q_ws + ((size_t)h*N_ + n0q + wave*16 + m)*32 + quad*8;
    #pragma unroll
    for (int jj = 0; jj < 8; ++jj) {
      const float x = qp[jj];
      const ushort hi = f2bf(x);
      Aqh.u[jj] = hi;
      Aql.u[jj] = f2bf(x - bf2f(hi));
    }
  }

  // ones A-fragment: A row 0 = ones -> denominator row of O^T
  union { short8 v; ushort u[8]; } onesf;
  {
    const ushort ov = (m == 0) ? (ushort)0x3F80 : (ushort)0;
    #pragma unroll
    for (int jj = 0; jj < 8; ++jj) onesf.u[jj] = ov;
  }

  // Of[nt][r] = O^T[d = nt*16 + quad*4 + r][q = wave*16 + m]; Of8 row0 = denom
  floatx4 Of[8];
  #pragma unroll
  for (int nt = 0; nt < 8; ++nt) Of[nt] = {0.f, 0.f, 0.f, 0.f};
  floatx4 Of8 = {0.f, 0.f, 0.f, 0.f};
  float mi = -3.0e38f;

  // K staging: 256 chunks handled by threads t < 256
  const int krow = t >> 2, kch = (t & 3) * 8;
  const ushort* pKh = kh + ((size_t)h*N_ + ktb*64 + (krow & 63))*32 + kch;

  // V staging: 1024 (row,g) chunks over 512 threads (2 each); each 8-k run
  // splits into two permuted b64s.
  // slot = 32*(g>>2) + 16*(g&1) + 8*(e>>2) + 4*((g>>1)&1) + (e&3)
  const ushort* pV[2];
  int wv0[2], wv1[2];
  #pragma unroll
  for (int p = 0; p < 2; ++p) {
    const int idx = p*512 + t, row = idx >> 3, g = idx & 7;
    pV[p] = vt + ((size_t)h*128 + row)*N_ + ktb*64 + g*8;
    const int sb0  = 32*(g>>2) + 16*(g&1) + 4*((g>>1)&1);
    const int blk0 = sb0 >> 3, off = sb0 & 4, r7 = row & 7;
    wv0[p] = row*64 + ((blk0       ^ r7) * 8) + off;
    wv1[p] = row*64 + (((blk0 + 1) ^ r7) * 8) + off;
  }

  short8 rK0 = {0,0,0,0,0,0,0,0};
  if (t < 256) rK0 = *(const short8*)pKh;
  short8 rV[2];
  #pragma unroll
  for (int p = 0; p < 2; ++p) rV[p] = *(const short8*)pV[p];

  const int x7 = m & 7;   // read-side swizzle key (row = nt*16 + m)

  for (int kt = ktb; kt < kte; ++kt) {
    __syncthreads();
    if (t < 256) *(short8*)&Khs[krow*40 + kch] = rK0;
    #pragma unroll
    for (int p = 0; p < 2; ++p) {
      union { short8 v; bhalf4 h2[2]; } tmp;
      tmp.v = rV[p];
      *(bhalf4*)&Vs[wv0[p]] = tmp.h2[0];
      *(bhalf4*)&Vs[wv1[p]] = tmp.h2[1];
    }
    if (kt + 1 < kte) {
      if (t < 256) { pKh += 2048; rK0 = *(const short8*)pKh; }
      #pragma unroll
      for (int p = 0; p < 2; ++p) { pV[p] += 64; rV[p] = *(const short8*)pV[p]; }
    }
    __syncthreads();

    // S^T = K Q^T (swapped operands): sf[kb][r] = S[k=kb*16+quad*4+r][q=m-col]
    floatx4 sf[4];
    #pragma unroll
    for (int kb = 0; kb < 4; ++kb) {
      const short8 bkh = *(const short8*)&Khs[(kb*16 + m)*40 + quad*8];
      floatx4 sv = {0.f, 0.f, 0.f, 0.f};
      sv = __builtin_amdgcn_mfma_f32_16x16x32_bf16(bkh, Aql.v, sv, 0, 0, 0);
      sv = __builtin_amdgcn_mfma_f32_16x16x32_bf16(bkh, Aqh.v, sv, 0, 0, 0);
      sf[kb] = sv;
    }

    // row max: 15 fmax local + 2 shuffle across quads (lanes m, m^16, m^32, m^48)
    float nm = fmaxf(fmaxf(sf[0][0], sf[0][1]), fmaxf(sf[0][2], sf[0][3]));
    nm = fmaxf(nm, fmaxf(fmaxf(sf[1][0], sf[1][1]), fmaxf(sf[1][2], sf[1][3])));
    nm = fmaxf(nm, fmaxf(fmaxf(sf[2][0], sf[2][1]), fmaxf(sf[2][2], sf[2][3])));
    nm = fmaxf(nm, fmaxf(fmaxf(sf[3][0], sf[3][1]), fmaxf(sf[3][2], sf[3][3])));
    nm = fmaxf(nm, __shfl_xor(nm, 16));
    nm = fmaxf(nm, __shfl_xor(nm, 32));

    if (__any(nm > mi + 20.f)) {
      const float mn = fmaxf(mi, nm);
      const float al = exp2f(mi - mn);
      mi = mn;
      #pragma unroll
      for (int nt = 0; nt < 8; ++nt) {
        Of[nt][0] *= al; Of[nt][1] *= al; Of[nt][2] *= al; Of[nt][3] *= al;
      }
      Of8[0] *= al; Of8[1] *= al; Of8[2] *= al; Of8[3] *= al;
    }

    // P = exp2(S - mi), Schraudolph bits, packed in-register into B-fragments:
    // pk[ks].u[p] = {P(kb=2ks+(p>>1), r=2(p&1)) lo16, r=2(p&1)+1 hi16}
    const float base = 1064866805.0f - mi*8388608.0f;
    union { short8 v; unsigned int u[4]; } pk[2];
    #pragma unroll
    for (int kb = 0; kb < 4; ++kb) {
      int p0 = (int)(sf[kb][0]*8388608.0f + base); p0 = p0 < 0 ? 0 : p0;
      int p1 = (int)(sf[kb][1]*8388608.0f + base); p1 = p1 < 0 ? 0 : p1;
      int p2 = (int)(sf[kb][2]*8388608.0f + base); p2 = p2 < 0 ? 0 : p2;
      int p3 = (int)(sf[kb][3]*8388608.0f + base); p3 = p3 < 0 ? 0 : p3;
      pk[kb >> 1].u[(kb & 1)*2 + 0] = ((unsigned)p0 >> 16) | ((unsigned)p1 & 0xffff0000u);
      pk[kb >> 1].u[(kb & 1)*2 + 1] = ((unsigned)p2 >> 16) | ((unsigned)p3 & 0xffff0000u);
    }

    // O^T += V^T P^T : A = V^T fragment from permuted LDS, B = pk (in-register)
    #pragma unroll
    for (int ks = 0; ks < 2; ++ks) {
      #pragma unroll
      for (int nt = 0; nt < 8; ++nt) {
        const short8 av = *(const short8*)&Vs[(nt*16 + m)*64 + (((ks*4 + quad) ^ x7) * 8)];
        Of[nt] = __builtin_amdgcn_mfma_f32_16x16x32_bf16(av, pk[ks].v, Of[nt], 0, 0, 0);
      }
      Of8 = __builtin_amdgcn_mfma_f32_16x16x32_bf16(onesf.v, pk[ks].v, Of8, 0, 0, 0);
    }
  }

  // denom lives at quad==0 lanes (C row 0), broadcast via LDS
  if (quad == 0) li_s[wave*16 + m] = Of8[0];
  __syncthreads();
  const float linv = 1.0f / li_s[wave*16 + m];

  ushort* Po = (s == 0) ? Po0 : ((s == 1) ? Po1 : ((s == 2) ? Po2 : Po3));
  const int n = n0q + wave*16 + m;
  #pragma unroll
  for (int nt = 0; nt < 8; ++nt) {
    unsigned int lo = (unsigned)f2bf(Of[nt][0] * linv) | ((unsigned)f2bf(Of[nt][1] * linv) << 16);
    unsigned int hi = (unsigned)f2bf(Of[nt][2] * linv) | ((unsigned)f2bf(Of[nt][3] * linv) << 16);
    uint2 pkd; pkd.x = lo; pkd.y = hi;
    *(uint2*)&Po[((size_t)h*N_ + n)*128 + nt*16 + quad*4] = pkd;
  }
  if (quad == 0) {
    Pml[(((size_t)s*8 + h)*N_ + n)*2 + 0] = mi;
    Pml[(((size_t)s*8 + h)*N_ + n)*2 + 1] = Of8[0];
  }
}

// ---------------- merge: combine 4 split-K partials (8 elems/thread) ------------
__global__ __launch_bounds__(256) void k_merge(
    const ushort* __restrict__ Po0, const ushort* __restrict__ Po1,
    const ushort* __restrict__ Po2, const ushort* __restrict__ Po3,
    const float* __restrict__ Pml,
    ushort* __restrict__ out_v_b, ushort* __restrict__ out_g_b)
{
  const int idx = blockIdx.x*256 + threadIdx.x;
  const int c0 = (idx & 15) * 8;
  const int n  = (idx >> 4) & 4095;
  const int h  = idx >> 16;
  float mm[4], ll[4];
  #pragma unroll
  for (int s = 0; s < 4; ++s) {
    mm[s] = Pml[(((size_t)s*8 + h)*N_ + n)*2 + 0];
    ll[s] = Pml[(((size_t)s*8 + h)*N_ + n)*2 + 1];
  }
  const float M = fmaxf(fmaxf(mm[0], mm[1]), fmaxf(mm[2], mm[3]));
  float w[4], tot = 0.f;
  #pragma unroll
  for (int s = 0; s < 4; ++s) { w[s] = exp2f(mm[s] - M) * ll[s]; tot += w[s]; }
  const float inv = 1.0f / tot;
  union { short8 v; ushort u[8]; } a, b, c, d, res;
  a.v = *(const short8*)&Po0[((size_t)h*N_ + n)*128 + c0];
  b.v = *(const short8*)&Po1[((size_t)h*N_ + n)*128 + c0];
  c.v = *(const short8*)&Po2[((size_t)h*N_ + n)*128 + c0];
  d.v = *(const short8*)&Po3[((size_t)h*N_ + n)*128 + c0];
  #pragma unroll
  for (int j = 0; j < 8; ++j)
    res.u[j] = f2bf((w[0]*bf2f(a.u[j]) + w[1]*bf2f(b.u[j]) +
                     w[2]*bf2f(c.u[j]) + w[3]*bf2f(d.u[j])) * inv);
  if (c0 < 32) {
    *(short8*)&out_v_b[(size_t)n*256 + h*32 + c0] = res.v;
  } else {
    const int j = (c0 - 32) >> 5, cc = (c0 - 32) & 31;
    *(short8*)&out_g_b[((size_t)n*3 + j)*256 + h*32 + cc] = res.v;
  }
}

// ---------------- k5a+k5b fused ----------------
__global__ __launch_bounds__(256) void k56ab(
    const ushort* __restrict__ out_v_b, const ushort* __restrict__ Wngt,
    const float* __restrict__ b_ng, const float* __restrict__ h,
    ushort* __restrict__ tmp_b,
    const ushort* __restrict__ out_g_b, const ushort* __restrict__ Wgoutt,
    ushort* __restrict__ gsum_b)
{
  __shared__ __align__(16) ushort As[64*72], Bs[64*72];
  floatx4 acc[4];
  const int lane = threadIdx.x & 63, wave = threadIdx.x >> 6;
  const int quad = lane >> 4, m = lane & 15;
  const int bN = blockIdx.y*64;
  if (blockIdx.x < 64) {
    const int bM = blockIdx.x*64;
    gemm_core<256>(out_v_b, Wngt, bM, bN, acc, As, Bs);
    #pragma unroll
    for (int ct = 0; ct < 4; ++ct) {
      const int c = bN + ct*16 + m;
      #pragma unroll
      for (int r = 0; r < 4; ++r) {
        const int i = bM + wave*16 + quad*4 + r;
        tmp_b[(size_t)i*256 + c] =
            f2bf(acc[ct][r] + b_ng[c] + h[(size_t)i*256 + c] * SQRT_E);
      }
    }
  } else {
    const int bM = (blockIdx.x - 64)*64;
    gemm_core<256>(out_g_b, Wgoutt, bM, bN, acc, As, Bs);
    #pragma unroll
    for (int ct = 0; ct < 4; ++ct) {
      const int c = bN + ct*16 + m;
      #pragma unroll
      for (int r = 0; r < 4; ++r) {
        const int i = bM + wave*16 + quad*4 + r;
        gsum_b[(size_t)i*256 + c] = f2bf(acc[ct][r]);
      }
    }
  }
}

// ---------------- k5c+k5d fused ----------------
__global__ __launch_bounds__(256) void k56cd(
    const ushort* __restrict__ tmp_b, const ushort* __restrict__ Whdect,
    const float* __restrict__ b_hdec,
    const ushort* __restrict__ gsum_b, const ushort* __restrict__ Wgdect,
    const float* __restrict__ pre0,
    float* __restrict__ out)
{
  __shared__ __align__(16) ushort As[64*72], Bs[64*72];
  const int t = threadIdx.x;
  const int lane = t & 63, wave = t >> 6;
  const int quad = lane >> 4, m = lane & 15;
  if (blockIdx.x < 64) {
    floatx4 acc[4];
    const int bM = blockIdx.x*64, bN = blockIdx.y*64;
    gemm_core<256>(tmp_b, Whdect, bM, bN, acc, As, Bs);
    #pragma unroll
    for (int ct = 0; ct < 4; ++ct) {
      const int c = bN + ct*16 + m;
      #pragma unroll
      for (int r = 0; r < 4; ++r) {
        const int i = bM + wave*16 + quad*4 + r;
        out[196608 + (size_t)i*256 + c] = acc[ct][r] + b_hdec[c];
      }
    }
  } else if (blockIdx.y == 0) {
    const int bM = (blockIdx.x - 64)*64;
    floatx4 acc = {0.f, 0.f, 0.f, 0.f};
    const int row = t >> 2, kq = (t & 3) * 8;
    for (int k0 = 0; k0 < 256; k0 += 32) {
      __syncthreads();
      *(short8*)&As[row*40 + kq] = *(const short8*)&gsum_b[(size_t)(bM+row)*256 + k0 + kq];
      if (t < 64)
        *(short8*)&Bs[(t>>2)*40 + kq] = *(const short8*)&Wgdect[(size_t)(t>>2)*256 + k0 + kq];
      __syncthreads();
      const short8 af = *(const short8*)&As[(wave*16 + m)*40 + quad*8];
      const short8 bf = *(const short8*)&Bs[m*40 + quad*8];
      acc = __builtin_amdgcn_mfma_f32_16x16x32_bf16(af, bf, acc, 0, 0, 0);
    }
    #pragma unroll
    for (int r = 0; r < 4; ++r) {
      const int i3 = bM + wave*16 + quad*4 + r;
      out[(size_t)i3*16 + m] = acc[r] + pre0[(size_t)i3*16 + m];
    }
  }
}

extern "C" void kernel_launch(void* const* d_in, const int* in_sizes, int n_in,
                              void* d_out, int out_size, void* d_ws, size_t ws_size,
                              hipStream_t stream) {
  const float* equ    = (const float*)d_in[0];
  const float* h      = (const float*)d_in[1];
  const float* W_equ  = (const float*)d_in[4];
  const float* W_gproj= (const float*)d_in[5];
  const float* W_vg   = (const float*)d_in[6];
  const float* W_g1   = (const float*)d_in[7];
  const float* b_g1   = (const float*)d_in[8];
  const float* W_g2   = (const float*)d_in[9];
  const float* b_g2   = (const float*)d_in[10];
  const float* W_q    = (const float*)d_in[11];
  const float* b_q    = (const float*)d_in[12];
  const float* W_k    = (const float*)d_in[13];
  const float* b_k    = (const float*)d_in[14];
  const float* W_v    = (const float*)d_in[15];
  const float* b_v    = (const float*)d_in[16];
  const float* W_ng   = (const float*)d_in[17];
  const float* b_ng   = (const float*)d_in[18];
  const float* W_gout = (const float*)d_in[19];
  const float* W_gdec = (const float*)d_in[20];
  const float* W_hdec = (const float*)d_in[21];
  const float* b_hdec = (const float*)d_in[22];
  float* out = (float*)d_out;

  // ---- workspace layout (lifetimes annotated), peak 50.4 MiB (52 proven) ----
  // Stages: P=prep G1 G2 G34 A=attn M=merge B=k56ab C=k56cd
  char* wsb = (char*)d_ws;
  constexpr size_t MiB = 1048576;
  float*  q_ws    = (float*) (wsb +  0*MiB);            // 4 MiB   [G34 -> A]
  ushort* kh      = (ushort*)(wsb +  4*MiB);            // 2 MiB   [G34 -> A]
  float*  Pml     = (float*) (wsb +  6*MiB);            // 1 MiB   [A -> M] (4 splits)
  float*  pre0    = (float*) (wsb +  7*MiB);            // 0.75 MiB[P -> C]
  ushort* vt      = (ushort*)(wsb +  8*MiB);            // 8 MiB   [G34 -> A]
  ushort* h2h     = (ushort*)(wsb + 17*MiB);            // 4 MiB   [P/G2 -> G34]
  ushort* h2l     = (ushort*)(wsb + 21*MiB);            // 4 MiB
  ushort* g_src_b = (ushort*)(wsb + 25*MiB);            // 6 MiB   [P -> G34]
  ushort* wbase   = (ushort*)(wsb + 31*MiB);            // 2.875 MiB [P -> G34]
  ushort* Wg1t = wbase;                                 // 512x1024
  ushort* Wg2t = wbase + 524288;                        // 256x512
  ushort* Wth  = wbase + 655360;                        // 768x512 hi
  ushort* Wtl  = wbase + 1048576;                       // 768x512 lo
  ushort* Wvgt = wbase + 1441792;                       // 256x256
  ushort* gram_b  = (ushort*)(wsb + 34*MiB);            // 8 MiB   [P -> G1]
  ushort* hidden  = (ushort*)(wsb + 42*MiB);            // 4 MiB   [G1 -> G2]
  // split-K x4 attention partials (all alias dead regions):
  ushort* Po0     = (ushort*)(wsb + 17*MiB);            // 8 MiB [A -> M] alias h2h/h2l
  ushort* Po1     = (ushort*)(wsb + 25*MiB);            // 8 MiB [A -> M] alias g_src_b+wbase
  ushort* Po2     = (ushort*)(wsb + 34*MiB);            // 8 MiB [A -> M] alias gram_b
  ushort* Po3     = (ushort*)(wsb + 42*MiB);            // 8 MiB [A -> M] alias hidden+
  ushort* wbase2  = (ushort*)(wsb + 50*MiB);            // 0.4 MiB [P -> B/C]
  ushort* Wngt   = wbase2;                              // 256x256
  ushort* Wgoutt = wbase2 + 65536;                      // 256x256
  ushort* Whdect = wbase2 + 131072;                     // 256x256
  ushort* Wgdect = wbase2 + 196608;                     // 16x256
  ushort* out_v_b = (ushort*)(wsb +  4*MiB);            // 2 MiB [M -> B] alias kh
  ushort* out_g_b = (ushort*)(wsb +  8*MiB);            // 6 MiB [M -> B] alias vt
  ushort* tmp_b   = (ushort*)(wsb + 17*MiB);            // 2 MiB [B -> C] alias Po0
  ushort* gsum_b  = (ushort*)(wsb + 25*MiB);            // 6 MiB [B -> C] alias Po1

  // ---- 1 mega-prep launch (10 transposes + hsplit + k1 + pre0) ----
  k_prep<<<9480, 256, 0, stream>>>(
      equ, h, W_equ, W_gproj, W_g1, W_g2, W_q, W_k, W_v,
      W_vg, W_ng, W_gout, W_hdec, W_gdec,
      Wg1t, Wg2t, Wth, Wtl, Wvgt, Wngt, Wgoutt, Whdect, Wgdect,
      h2h, h2l, g_src_b, gram_b, pre0);

  // ---- GEMM chain (BK=64 double-pumped cores) ----
  k_g1<<<dim3(64, 8), 256, 0, stream>>>(gram_b, Wg1t, b_g1, hidden);
  k_g2<<<dim3(64, 4), 256, 0, stream>>>(hidden, Wg2t, b_g2, h2h, h2l);
  k_g34<<<dim3(192, 8), 256, 0, stream>>>(h2h, h2l, Wth, Wtl, b_q, b_k, b_v,
                                          g_src_b, Wvgt, q_ws, kh, vt);

  // ---- attention (8-wave blocks, swapped-operand, in-reg P, split-K x4) ----
  dim3 g3(32, 8, 4);
  k3_attn<<<g3, 512, 0, stream>>>(q_ws, kh, vt, Po0, Po1, Po2, Po3, Pml);
  k_merge<<<2048, 256, 0, stream>>>(Po0, Po1, Po2, Po3, Pml, out_v_b, out_g_b);

  // ---- epilogue GEMMs (fused pairs) ----
  k56ab<<<dim3(256, 4), 256, 0, stream>>>(out_v_b, Wngt, b_ng, h, tmp_b,
                                          out_g_b, Wgoutt, gsum_b);
  k56cd<<<dim3(256, 4), 256, 0, stream>>>(tmp_b, Whdect, b_hdec,
                                          gsum_b, Wgdect, pre0, out);
}

// Round 16
// 260.222 us; speedup vs baseline: 1.0272x; 1.0102x over previous
//
#include <hip/hip_runtime.h>
#include <hip/hip_bf16.h>

typedef __attribute__((ext_vector_type(8))) short short8;
typedef __attribute__((ext_vector_type(4))) short bhalf4;
typedef __attribute__((ext_vector_type(4))) float floatx4;

constexpr int N_ = 4096;
constexpr float SQRT_E = 16.0f;
// q scale folded with log2(e): softmax computed in exp2 domain
constexpr float QSCALE = 0.17677669529663687f * 1.4426950408889634f;

__device__ __forceinline__ ushort f2bf(float x) {
  __hip_bfloat16 h = __float2bfloat16(x);
  return *reinterpret_cast<ushort*>(&h);
}
__device__ __forceinline__ float bf2f(ushort b) {
  unsigned int u = ((unsigned int)b) << 16;
  return __uint_as_float(u);
}

// ---------------- transpose helper (device side of mega-prep) ----------------
__device__ __forceinline__ void do_transpose(
    const float* __restrict__ src, ushort* __restrict__ dsth,
    ushort* __restrict__ dstl, int R, int C, int lb, int cb_shift,
    float* smem, int hasLo)
{
  float (*tile)[33] = (float(*)[33])smem;
  const int r0 = (lb >> cb_shift) * 32;
  const int c0 = (lb & ((1 << cb_shift) - 1)) * 32;
  const int tx = threadIdx.x & 31, ty = threadIdx.x >> 5;
  #pragma unroll
  for (int p = 0; p < 4; ++p) {
    const int lr = p*8 + ty;
    tile[lr][tx] = (r0+lr < R && c0+tx < C) ? src[(size_t)(r0+lr)*C + c0 + tx] : 0.f;
  }
  __syncthreads();
  #pragma unroll
  for (int p = 0; p < 4; ++p) {
    const int dc = p*8 + ty;
    if (c0+dc < C && r0+tx < R) {
      const float v = tile[tx][dc];
      const ushort hi = f2bf(v);
      dsth[(size_t)(c0+dc)*R + r0 + tx] = hi;
      if (hasLo) dstl[(size_t)(c0+dc)*R + r0 + tx] = f2bf(v - bf2f(hi));
    }
  }
}

// ---------------- mega-prep: all transposes + hsplit + k1 in ONE launch --------
__global__ __launch_bounds__(256) void k_prep(
    const float* __restrict__ equ, const float* __restrict__ h,
    const float* __restrict__ W_equ, const float* __restrict__ W_gproj,
    const float* __restrict__ W_g1, const float* __restrict__ W_g2,
    const float* __restrict__ W_q, const float* __restrict__ W_k,
    const float* __restrict__ W_v, const float* __restrict__ W_vg,
    const float* __restrict__ W_ng, const float* __restrict__ W_gout,
    const float* __restrict__ W_hdec, const float* __restrict__ W_gdec,
    ushort* __restrict__ Wg1t, ushort* __restrict__ Wg2t,
    ushort* __restrict__ Wth, ushort* __restrict__ Wtl,
    ushort* __restrict__ Wvgt, ushort* __restrict__ Wngt,
    ushort* __restrict__ Wgoutt, ushort* __restrict__ Whdect,
    ushort* __restrict__ Wgdect,
    ushort* __restrict__ h2h, ushort* __restrict__ h2l,
    ushort* __restrict__ g_src_b, ushort* __restrict__ gram_b,
    float* __restrict__ pre0)
{
  __shared__ __align__(16) float smem[1120];
  const int b = blockIdx.x;
  const int t = threadIdx.x;

  if (b < 512) {            // W_g1 [1024,512] -> Wg1t
    do_transpose(W_g1, Wg1t, nullptr, 1024, 512, b, 4, smem, 0);
  } else if (b < 640) {     // W_g2 [512,256]
    do_transpose(W_g2, Wg2t, nullptr, 512, 256, b-512, 3, smem, 0);
  } else if (b < 768) {     // W_q hi/lo
    do_transpose(W_q, Wth, Wtl, 512, 256, b-640, 3, smem, 1);
  } else if (b < 896) {     // W_k hi/lo
    do_transpose(W_k, Wth + 256*512, Wtl + 256*512, 512, 256, b-768, 3, smem, 1);
  } else if (b < 1024) {    // W_v hi/lo
    do_transpose(W_v, Wth + 512*512, Wtl + 512*512, 512, 256, b-896, 3, smem, 1);
  } else if (b < 1088) {    // W_vg
    do_transpose(W_vg, Wvgt, nullptr, 256, 256, b-1024, 3, smem, 0);
  } else if (b < 1152) {    // W_ng
    do_transpose(W_ng, Wngt, nullptr, 256, 256, b-1088, 3, smem, 0);
  } else if (b < 1216) {    // W_gout
    do_transpose(W_gout, Wgoutt, nullptr, 256, 256, b-1152, 3, smem, 0);
  } else if (b < 1280) {    // W_hdec
    do_transpose(W_hdec, Whdect, nullptr, 256, 256, b-1216, 3, smem, 0);
  } else if (b < 1288) {    // W_gdec [256,16]
    do_transpose(W_gdec, Wgdect, nullptr, 256, 16, b-1280, 0, smem, 0);
  } else if (b < 5384) {    // hsplit: h_src half of h2 (hi/lo)
    const int i = b - 1288;
    const float v = h[(size_t)i*256 + t] * SQRT_E;
    const ushort hi = f2bf(v);
    h2h[(size_t)i*512 + 256 + t] = hi;
    h2l[(size_t)i*512 + 256 + t] = f2bf(v - bf2f(hi));
  } else {                  // k1: g_src_b + gram_b + pre0
    float* eq   = smem;        // 48
    float* gs   = smem + 48;   // 768
    float* g2p  = smem + 816;  // 96
    float* part = smem + 912;  // 192
    const int i = b - 5384;
    if (t < 48) eq[t] = equ[(size_t)i*48 + t];
    __syncthreads();
    #pragma unroll
    for (int j = 0; j < 3; ++j) {
      float s = 0.f;
      #pragma unroll
      for (int m = 0; m < 16; ++m) s += eq[j*16+m] * W_equ[m*256 + t];
      s *= SQRT_E;
      gs[j*256 + t] = s;
      g_src_b[((size_t)i*3 + j)*256 + t] = f2bf(s);
    }
    __syncthreads();
    if (t < 192) {            // 2-way K-split of the gproj GEMV
      const int o = t % 96, half = t / 96;
      const int j = o >> 5, a = o & 31;
      const int e0 = half * 128;
      float s = 0.f;
      for (int e = 0; e < 128; ++e)
        s += gs[j*256 + e0 + e] * W_gproj[(size_t)(e0+e)*32 + a];
      part[t] = s;
    }
    __syncthreads();
    if (t < 96) g2p[t] = part[t] + part[96 + t];
    __syncthreads();
    #pragma unroll
    for (int r = 0; r < 4; ++r) {
      const int idx = r*256 + t;
      const int a = idx >> 5, bb = idx & 31;
      const float s = g2p[a]*g2p[bb] + g2p[32+a]*g2p[32+bb] + g2p[64+a]*g2p[64+bb];
      gram_b[(size_t)i*1024 + idx] = f2bf(s);
    }
    // pre0 = g_src(f32) @ W_gdec, 4-way K-split. t = j*64 + ks*16 + mc
    if (t < 192) {
      const int j = t >> 6, ks = (t >> 4) & 3, mc = t & 15;
      const int e0 = ks * 64;
      float s = 0.f;
      for (int e = 0; e < 64; ++e)
        s += gs[j*256 + e0 + e] * W_gdec[(size_t)(e0 + e)*16 + mc];
      part[t] = s;
    }
    __syncthreads();
    if (t < 48) {
      const int j = t >> 4, mc = t & 15;
      pre0[((size_t)i*3 + j)*16 + mc] =
          part[j*64 + mc] + part[j*64 + 16 + mc] +
          part[j*64 + 32 + mc] + part[j*64 + 48 + mc];
    }
  }
}

// ---------------- GEMM cores: BK=64, double-pumped, register prefetch -----------
template<int KTOT>
__device__ __forceinline__ void gemm_core(
    const ushort* __restrict__ A, const ushort* __restrict__ Bt,
    int bM, int bN, floatx4 acc[4], ushort* As, ushort* Bs)
{
  const int t = threadIdx.x;
  const int wave = t >> 6, lane = t & 63, quad = lane >> 4, m = lane & 15;
  #pragma unroll
  for (int ct = 0; ct < 4; ++ct) acc[ct] = {0.f, 0.f, 0.f, 0.f};
  const int ca = t*2, cb = t*2 + 1;
  const int ra = ca >> 3, pa = ca & 7;
  const int rb = cb >> 3, pb = cb & 7;
  const ushort* pA0 = A  + (size_t)(bM+ra)*KTOT + pa*8;
  const ushort* pA1 = A  + (size_t)(bM+rb)*KTOT + pb*8;
  const ushort* pB0 = Bt + (size_t)(bN+ra)*KTOT + pa*8;
  const ushort* pB1 = Bt + (size_t)(bN+rb)*KTOT + pb*8;
  short8 rA0 = *(const short8*)pA0, rA1 = *(const short8*)pA1;
  short8 rB0 = *(const short8*)pB0, rB1 = *(const short8*)pB1;
  for (int k0 = 0; k0 < KTOT; k0 += 64) {
    __syncthreads();
    *(short8*)&As[ra*72 + pa*8] = rA0;
    *(short8*)&As[rb*72 + pb*8] = rA1;
    *(short8*)&Bs[ra*72 + pa*8] = rB0;
    *(short8*)&Bs[rb*72 + pb*8] = rB1;
    if (k0 + 64 < KTOT) {
      pA0 += 64; pA1 += 64; pB0 += 64; pB1 += 64;
      rA0 = *(const short8*)pA0; rA1 = *(const short8*)pA1;
      rB0 = *(const short8*)pB0; rB1 = *(const short8*)pB1;
    }
    __syncthreads();
    #pragma unroll
    for (int ks = 0; ks < 2; ++ks) {
      const short8 af = *(const short8*)&As[(wave*16 + m)*72 + ks*32 + quad*8];
      #pragma unroll
      for (int ct = 0; ct < 4; ++ct) {
        const short8 bf = *(const short8*)&Bs[(ct*16 + m)*72 + ks*32 + quad*8];
        acc[ct] = __builtin_amdgcn_mfma_f32_16x16x32_bf16(af, bf, acc[ct], 0, 0, 0);
      }
    }
  }
}

template<int KTOT>
__device__ __forceinline__ void gemm_core3(
    const ushort* __restrict__ Ah, const ushort* __restrict__ Al,
    const ushort* __restrict__ Bth, const ushort* __restrict__ Btl,
    int bM, int bN, floatx4 acc[4],
    ushort* Ash, ushort* Asl, ushort* Bsh, ushort* Bsl)
{
  const int t = threadIdx.x;
  const int wave = t >> 6, lane = t & 63, quad = lane >> 4, m = lane & 15;
  #pragma unroll
  for (int ct = 0; ct < 4; ++ct) acc[ct] = {0.f, 0.f, 0.f, 0.f};
  const int ca = t*2, cb = t*2 + 1;
  const int ra = ca >> 3, pa = ca & 7;
  const int rb = cb >> 3, pb = cb & 7;
  const ushort* pAh0 = Ah  + (size_t)(bM+ra)*KTOT + pa*8;
  const ushort* pAh1 = Ah  + (size_t)(bM+rb)*KTOT + pb*8;
  const ushort* pAl0 = Al  + (size_t)(bM+ra)*KTOT + pa*8;
  const ushort* pAl1 = Al  + (size_t)(bM+rb)*KTOT + pb*8;
  const ushort* pBh0 = Bth + (size_t)(bN+ra)*KTOT + pa*8;
  const ushort* pBh1 = Bth + (size_t)(bN+rb)*KTOT + pb*8;
  const ushort* pBl0 = Btl + (size_t)(bN+ra)*KTOT + pa*8;
  const ushort* pBl1 = Btl + (size_t)(bN+rb)*KTOT + pb*8;
  short8 rAh0 = *(const short8*)pAh0, rAh1 = *(const short8*)pAh1;
  short8 rAl0 = *(const short8*)pAl0, rAl1 = *(const short8*)pAl1;
  short8 rBh0 = *(const short8*)pBh0, rBh1 = *(const short8*)pBh1;
  short8 rBl0 = *(const short8*)pBl0, rBl1 = *(const short8*)pBl1;
  for (int k0 = 0; k0 < KTOT; k0 += 64) {
    __syncthreads();
    *(short8*)&Ash[ra*72 + pa*8] = rAh0;
    *(short8*)&Ash[rb*72 + pb*8] = rAh1;
    *(short8*)&Asl[ra*72 + pa*8] = rAl0;
    *(short8*)&Asl[rb*72 + pb*8] = rAl1;
    *(short8*)&Bsh[ra*72 + pa*8] = rBh0;
    *(short8*)&Bsh[rb*72 + pb*8] = rBh1;
    *(short8*)&Bsl[ra*72 + pa*8] = rBl0;
    *(short8*)&Bsl[rb*72 + pb*8] = rBl1;
    if (k0 + 64 < KTOT) {
      pAh0 += 64; pAh1 += 64; pAl0 += 64; pAl1 += 64;
      pBh0 += 64; pBh1 += 64; pBl0 += 64; pBl1 += 64;
      rAh0 = *(const short8*)pAh0; rAh1 = *(const short8*)pAh1;
      rAl0 = *(const short8*)pAl0; rAl1 = *(const short8*)pAl1;
      rBh0 = *(const short8*)pBh0; rBh1 = *(const short8*)pBh1;
      rBl0 = *(const short8*)pBl0; rBl1 = *(const short8*)pBl1;
    }
    __syncthreads();
    #pragma unroll
    for (int ks = 0; ks < 2; ++ks) {
      const short8 ah = *(const short8*)&Ash[(wave*16 + m)*72 + ks*32 + quad*8];
      const short8 al = *(const short8*)&Asl[(wave*16 + m)*72 + ks*32 + quad*8];
      #pragma unroll
      for (int ct = 0; ct < 4; ++ct) {
        const short8 bh = *(const short8*)&Bsh[(ct*16 + m)*72 + ks*32 + quad*8];
        const short8 bl = *(const short8*)&Bsl[(ct*16 + m)*72 + ks*32 + quad*8];
        acc[ct] = __builtin_amdgcn_mfma_f32_16x16x32_bf16(ah, bl, acc[ct], 0, 0, 0);
        acc[ct] = __builtin_amdgcn_mfma_f32_16x16x32_bf16(al, bh, acc[ct], 0, 0, 0);
        acc[ct] = __builtin_amdgcn_mfma_f32_16x16x32_bf16(ah, bh, acc[ct], 0, 0, 0);
      }
    }
  }
}

// G1: hidden = relu(gram @ W_g1 + b_g1)
__global__ __launch_bounds__(256) void k_g1(
    const ushort* __restrict__ gram_b, const ushort* __restrict__ Wg1t,
    const float* __restrict__ b_g1, ushort* __restrict__ hidden)
{
  __shared__ __align__(16) ushort As[64*72], Bs[64*72];
  floatx4 acc[4];
  const int bM = blockIdx.x*64, bN = blockIdx.y*64;
  gemm_core<1024>(gram_b, Wg1t, bM, bN, acc, As, Bs);
  const int lane = threadIdx.x & 63, wave = threadIdx.x >> 6;
  const int quad = lane >> 4, m = lane & 15;
  #pragma unroll
  for (int ct = 0; ct < 4; ++ct) {
    const int c = bN + ct*16 + m;
    #pragma unroll
    for (int r = 0; r < 4; ++r) {
      const int i = bM + wave*16 + quad*4 + r;
      hidden[(size_t)i*512 + c] = f2bf(fmaxf(acc[ct][r] + b_g1[c], 0.f));
    }
  }
}

// G2: g2 = hidden @ W_g2 + b_g2 -> hi/lo into h2 cols 0..255
__global__ __launch_bounds__(256) void k_g2(
    const ushort* __restrict__ hidden, const ushort* __restrict__ Wg2t,
    const float* __restrict__ b_g2, ushort* __restrict__ h2h, ushort* __restrict__ h2l)
{
  __shared__ __align__(16) ushort As[64*72], Bs[64*72];
  floatx4 acc[4];
  const int bM = blockIdx.x*64, bN = blockIdx.y*64;
  gemm_core<512>(hidden, Wg2t, bM, bN, acc, As, Bs);
  const int lane = threadIdx.x & 63, wave = threadIdx.x >> 6;
  const int quad = lane >> 4, m = lane & 15;
  #pragma unroll
  for (int ct = 0; ct < 4; ++ct) {
    const int c = bN + ct*16 + m;
    #pragma unroll
    for (int r = 0; r < 4; ++r) {
      const int i = bM + wave*16 + quad*4 + r;
      const float s = acc[ct][r] + b_g2[c];
      const ushort hi = f2bf(s);
      h2h[(size_t)i*512 + c] = hi;
      h2l[(size_t)i*512 + c] = f2bf(s - bf2f(hi));
    }
  }
}

// G3+G4 fused: q/k hi/lo 3-term; v 1-term; vg 1-term. vt = [head][d 0..127][n].
// NOTE (r14): splitting this into separate g3/g4 kernels REGRESSED +6 us —
// the mixed heavy/light 1536-block grid load-balances better than two
// dispatches with separate tails. Keep monolithic.
__global__ __launch_bounds__(256) void k_g34(
    const ushort* __restrict__ h2h, const ushort* __restrict__ h2l,
    const ushort* __restrict__ Wth, const ushort* __restrict__ Wtl,
    const float* __restrict__ b_q, const float* __restrict__ b_k,
    const float* __restrict__ b_v,
    const ushort* __restrict__ g_src_b, const ushort* __restrict__ Wvgt,
    float* __restrict__ q_ws, ushort* __restrict__ kh,
    ushort* __restrict__ vt)
{
  __shared__ __align__(16) ushort S0[64*72], S1[64*72], S2[64*72], S3[64*72];
  const int lb = blockIdx.y*192 + blockIdx.x;     // grid (192,8) = 1536
  const int lane = threadIdx.x & 63, wave = threadIdx.x >> 6;
  const int quad = lane >> 4, m = lane & 15;
  floatx4 acc[4];
  if (lb < 768) {
    const int bM = (lb & 63)*64, bN = (lb >> 6)*64;
    if (bN < 512) {
      gemm_core3<512>(h2h, h2l, Wth, Wtl, bM, bN, acc, S0, S1, S2, S3);
      #pragma unroll
      for (int ct = 0; ct < 4; ++ct) {
        const int c = bN + ct*16 + m;
        #pragma unroll
        for (int r = 0; r < 4; ++r) {
          const int i = bM + wave*16 + quad*4 + r;
          if (c < 256) {
            const float s = acc[ct][r] + b_q[c];
            q_ws[((size_t)(c >> 5)*N_ + i)*32 + (c & 31)] = s * QSCALE;
          } else {
            const int cc = c - 256;
            const float s = acc[ct][r] + b_k[cc];
            kh[((size_t)(cc >> 5)*N_ + i)*32 + (cc & 31)] = f2bf(s);
          }
        }
      }
    } else {
      gemm_core<512>(h2h, Wth, bM, bN, acc, S0, S1);
      #pragma unroll
      for (int ct = 0; ct < 4; ++ct) {
        const int cc = bN + ct*16 + m - 512;
        #pragma unroll
        for (int r = 0; r < 4; ++r) {
          const int i = bM + wave*16 + quad*4 + r;
          const float s = acc[ct][r] + b_v[cc];
          vt[((size_t)(cc >> 5)*128 + (cc & 31))*N_ + i] = f2bf(s);
        }
      }
    }
  } else {
    const int lb2 = lb - 768;
    const int bM = (lb2 >> 2)*64, bN = (lb2 & 3)*64;
    gemm_core<256>(g_src_b, Wvgt, bM, bN, acc, S0, S1);
    #pragma unroll
    for (int ct = 0; ct < 4; ++ct) {
      const int c = bN + ct*16 + m;
      const int hh = c >> 5, d = c & 31;
      #pragma unroll
      for (int r = 0; r < 4; ++r) {
        const int i3 = bM + wave*16 + quad*4 + r;
        const int i = i3 / 3, j = i3 - 3*i;
        vt[((size_t)hh*128 + 32 + j*32 + d)*N_ + i] = f2bf(acc[ct][r]);
      }
    }
  }
}

// ---------------- K3: swapped-operand flash attention, P fully in-register -----
// mfma(K,Q) gives S^T with q = lane&15 -> softmax is lane-local. V columns are
// stored bit-permuted in LDS (slot{5..0} = {k5,k3,k2,k4,k1,k0}) so each lane's
// own 16 P values form its PV B-fragment directly: no P LDS buffer, no cross-
// lane exchange. PV swapped too (O^T = V^T P^T). Denominator = ones-row MFMA.
// ROUND 16: SINGLE-BF16 Q — absmax was 0.125 vs threshold 0.5125 (4x margin);
// K was already single bf16, so dropping Q's lo-term (~2x the QK rounding
// error, absmax -> ~0.25) buys 4 fewer MFMAs/kt (26 -> 22) + 16 VALU prologue.
// 8-wave blocks (512 thr, 128 q-rows). Grid (32,8,4)=1024 = 4 blk/CU resident.
// LESSONS: (r10) doubling accumulator state spills (~64 live VGPR budget);
// (r12) fixed-base exp2 softmax NaNs — the online max is load-bearing;
// (r14) splitting k_g34 regressed (mixed-grid load balance beats LDS-union).
__global__ __launch_bounds__(512, 4) void k3_attn(
    const float* __restrict__ q_ws, const ushort* __restrict__ kh,
    const ushort* __restrict__ vt,
    ushort* __restrict__ Po0, ushort* __restrict__ Po1,
    ushort* __restrict__ Po2, ushort* __restrict__ Po3,
    float* __restrict__ Pml)
{
  __shared__ __align__(16) ushort Khs[64*40];              // 5 KiB
  __shared__ __align__(16) ushort Vs[128*64];              // 16 KiB, permuted+swizzled
  __shared__ float li_s[128];

  const int t    = threadIdx.x;          // 0..511
  const int wave = t >> 6;               // 0..7
  const int lane = t & 63;
  const int quad = lane >> 4;
  const int m    = lane & 15;
  const int h    = blockIdx.y;
  const int s    = blockIdx.z;
  const int n0q  = blockIdx.x * 128;

  const int ktb = s * 16;
  const int kte = ktb + 16;

  // Q fragment (B-operand; rows n0q + wave*16 + m): SINGLE bf16 (r16)
  union { short8 v; ushort u[8]; } Aqh;
  {
    const float* qp = q_ws + ((size_t)h*N_ + n0q + wave*16 + m)*32 + quad*8;
    #pragma unroll
    for (int jj = 0; jj < 8; ++jj) Aqh.u[jj] = f2bf(qp[jj]);
  }

  // ones A-fragment: A row 0 = ones -> denominator row of O^T
  union { short8 v; ushort u[8]; } onesf;
  {
    const ushort ov = (m == 0) ? (ushort)0x3F80 : (ushort)0;
    #pragma unroll
    for (int jj = 0; jj < 8; ++jj) onesf.u[jj] = ov;
  }

  // Of[nt][r] = O^T[d = nt*16 + quad*4 + r][q = wave*16 + m]; Of8 row0 = denom
  floatx4 Of[8];
  #pragma unroll
  for (int nt = 0; nt < 8; ++nt) Of[nt] = {0.f, 0.f, 0.f, 0.f};
  floatx4 Of8 = {0.f, 0.f, 0.f, 0.f};
  float mi = -3.0e38f;

  // K staging: 256 chunks handled by threads t < 256
  const int krow = t >> 2, kch = (t & 3) * 8;
  const ushort* pKh = kh + ((size_t)h*N_ + ktb*64 + (krow & 63))*32 + kch;

  // V staging: 1024 (row,g) chunks over 512 threads (2 each); each 8-k run
  // splits into two permuted b64s.
  // slot = 32*(g>>2) + 16*(g&1) + 8*(e>>2) + 4*((g>>1)&1) + (e&3)
  const ushort* pV[2];
  int wv0[2], wv1[2];
  #pragma unroll
  for (int p = 0; p < 2; ++p) {
    const int idx = p*512 + t, row = idx >> 3, g = idx & 7;
    pV[p] = vt + ((size_t)h*128 + row)*N_ + ktb*64 + g*8;
    const int sb0  = 32*(g>>2) + 16*(g&1) + 4*((g>>1)&1);
    const int blk0 = sb0 >> 3, off = sb0 & 4, r7 = row & 7;
    wv0[p] = row*64 + ((blk0       ^ r7) * 8) + off;
    wv1[p] = row*64 + (((blk0 + 1) ^ r7) * 8) + off;
  }

  short8 rK0 = {0,0,0,0,0,0,0,0};
  if (t < 256) rK0 = *(const short8*)pKh;
  short8 rV[2];
  #pragma unroll
  for (int p = 0; p < 2; ++p) rV[p] = *(const short8*)pV[p];

  const int x7 = m & 7;   // read-side swizzle key (row = nt*16 + m)

  for (int kt = ktb; kt < kte; ++kt) {
    __syncthreads();
    if (t < 256) *(short8*)&Khs[krow*40 + kch] = rK0;
    #pragma unroll
    for (int p = 0; p < 2; ++p) {
      union { short8 v; bhalf4 h2[2]; } tmp;
      tmp.v = rV[p];
      *(bhalf4*)&Vs[wv0[p]] = tmp.h2[0];
      *(bhalf4*)&Vs[wv1[p]] = tmp.h2[1];
    }
    if (kt + 1 < kte) {
      if (t < 256) { pKh += 2048; rK0 = *(const short8*)pKh; }
      #pragma unroll
      for (int p = 0; p < 2; ++p) { pV[p] += 64; rV[p] = *(const short8*)pV[p]; }
    }
    __syncthreads();

    // S^T = K Q^T (swapped operands): sf[kb][r] = S[k=kb*16+quad*4+r][q=m-col]
    floatx4 sf[4];
    #pragma unroll
    for (int kb = 0; kb < 4; ++kb) {
      const short8 bkh = *(const short8*)&Khs[(kb*16 + m)*40 + quad*8];
      floatx4 sv = {0.f, 0.f, 0.f, 0.f};
      sv = __builtin_amdgcn_mfma_f32_16x16x32_bf16(bkh, Aqh.v, sv, 0, 0, 0);
      sf[kb] = sv;
    }

    // row max: 15 fmax local + 2 shuffle across quads (lanes m, m^16, m^32, m^48)
    float nm = fmaxf(fmaxf(sf[0][0], sf[0][1]), fmaxf(sf[0][2], sf[0][3]));
    nm = fmaxf(nm, fmaxf(fmaxf(sf[1][0], sf[1][1]), fmaxf(sf[1][2], sf[1][3])));
    nm = fmaxf(nm, fmaxf(fmaxf(sf[2][0], sf[2][1]), fmaxf(sf[2][2], sf[2][3])));
    nm = fmaxf(nm, fmaxf(fmaxf(sf[3][0], sf[3][1]), fmaxf(sf[3][2], sf[3][3])));
    nm = fmaxf(nm, __shfl_xor(nm, 16));
    nm = fmaxf(nm, __shfl_xor(nm, 32));

    if (__any(nm > mi + 20.f)) {
      const float mn = fmaxf(mi, nm);
      const float al = exp2f(mi - mn);
      mi = mn;
      #pragma unroll
      for (int nt = 0; nt < 8; ++nt) {
        Of[nt][0] *= al; Of[nt][1] *= al; Of[nt][2] *= al; Of[nt][3] *= al;
      }
      Of8[0] *= al; Of8[1] *= al; Of8[2] *= al; Of8[3] *= al;
    }

    // P = exp2(S - mi), Schraudolph bits, packed in-register into B-fragments:
    // pk[ks].u[p] = {P(kb=2ks+(p>>1), r=2(p&1)) lo16, r=2(p&1)+1 hi16}
    const float base = 1064866805.0f - mi*8388608.0f;
    union { short8 v; unsigned int u[4]; } pk[2];
    #pragma unroll
    for (int kb = 0; kb < 4; ++kb) {
      int p0 = (int)(sf[kb][0]*8388608.0f + base); p0 = p0 < 0 ? 0 : p0;
      int p1 = (int)(sf[kb][1]*8388608.0f + base); p1 = p1 < 0 ? 0 : p1;
      int p2 = (int)(sf[kb][2]*8388608.0f + base); p2 = p2 < 0 ? 0 : p2;
      int p3 = (int)(sf[kb][3]*8388608.0f + base); p3 = p3 < 0 ? 0 : p3;
      pk[kb >> 1].u[(kb & 1)*2 + 0] = ((unsigned)p0 >> 16) | ((unsigned)p1 & 0xffff0000u);
      pk[kb >> 1].u[(kb & 1)*2 + 1] = ((unsigned)p2 >> 16) | ((unsigned)p3 & 0xffff0000u);
    }

    // O^T += V^T P^T : A = V^T fragment from permuted LDS, B = pk (in-register)
    #pragma unroll
    for (int ks = 0; ks < 2; ++ks) {
      #pragma unroll
      for (int nt = 0; nt < 8; ++nt) {
        const short8 av = *(const short8*)&Vs[(nt*16 + m)*64 + (((ks*4 + quad) ^ x7) * 8)];
        Of[nt] = __builtin_amdgcn_mfma_f32_16x16x32_bf16(av, pk[ks].v, Of[nt], 0, 0, 0);
      }
      Of8 = __builtin_amdgcn_mfma_f32_16x16x32_bf16(onesf.v, pk[ks].v, Of8, 0, 0, 0);
    }
  }

  // denom lives at quad==0 lanes (C row 0), broadcast via LDS
  if (quad == 0) li_s[wave*16 + m] = Of8[0];
  __syncthreads();
  const float linv = 1.0f / li_s[wave*16 + m];

  ushort* Po = (s == 0) ? Po0 : ((s == 1) ? Po1 : ((s == 2) ? Po2 : Po3));
  const int n = n0q + wave*16 + m;
  #pragma unroll
  for (int nt = 0; nt < 8; ++nt) {
    unsigned int lo = (unsigned)f2bf(Of[nt][0] * linv) | ((unsigned)f2bf(Of[nt][1] * linv) << 16);
    unsigned int hi = (unsigned)f2bf(Of[nt][2] * linv) | ((unsigned)f2bf(Of[nt][3] * linv) << 16);
    uint2 pkd; pkd.x = lo; pkd.y = hi;
    *(uint2*)&Po[((size_t)h*N_ + n)*128 + nt*16 + quad*4] = pkd;
  }
  if (quad == 0) {
    Pml[(((size_t)s*8 + h)*N_ + n)*2 + 0] = mi;
    Pml[(((size_t)s*8 + h)*N_ + n)*2 + 1] = Of8[0];
  }
}

// ---------------- merge: combine 4 split-K partials (8 elems/thread) ------------
__global__ __launch_bounds__(256) void k_merge(
    const ushort* __restrict__ Po0, const ushort* __restrict__ Po1,
    const ushort* __restrict__ Po2, const ushort* __restrict__ Po3,
    const float* __restrict__ Pml,
    ushort* __restrict__ out_v_b, ushort* __restrict__ out_g_b)
{
  const int idx = blockIdx.x*256 + threadIdx.x;
  const int c0 = (idx & 15) * 8;
  const int n  = (idx >> 4) & 4095;
  const int h  = idx >> 16;
  float mm[4], ll[4];
  #pragma unroll
  for (int s = 0; s < 4; ++s) {
    mm[s] = Pml[(((size_t)s*8 + h)*N_ + n)*2 + 0];
    ll[s] = Pml[(((size_t)s*8 + h)*N_ + n)*2 + 1];
  }
  const float M = fmaxf(fmaxf(mm[0], mm[1]), fmaxf(mm[2], mm[3]));
  float w[4], tot = 0.f;
  #pragma unroll
  for (int s = 0; s < 4; ++s) { w[s] = exp2f(mm[s] - M) * ll[s]; tot += w[s]; }
  const float inv = 1.0f / tot;
  union { short8 v; ushort u[8]; } a, b, c, d, res;
  a.v = *(const short8*)&Po0[((size_t)h*N_ + n)*128 + c0];
  b.v = *(const short8*)&Po1[((size_t)h*N_ + n)*128 + c0];
  c.v = *(const short8*)&Po2[((size_t)h*N_ + n)*128 + c0];
  d.v = *(const short8*)&Po3[((size_t)h*N_ + n)*128 + c0];
  #pragma unroll
  for (int j = 0; j < 8; ++j)
    res.u[j] = f2bf((w[0]*bf2f(a.u[j]) + w[1]*bf2f(b.u[j]) +
                     w[2]*bf2f(c.u[j]) + w[3]*bf2f(d.u[j])) * inv);
  if (c0 < 32) {
    *(short8*)&out_v_b[(size_t)n*256 + h*32 + c0] = res.v;
  } else {
    const int j = (c0 - 32) >> 5, cc = (c0 - 32) & 31;
    *(short8*)&out_g_b[((size_t)n*3 + j)*256 + h*32 + cc] = res.v;
  }
}

// ---------------- k5a+k5b fused ----------------
__global__ __launch_bounds__(256) void k56ab(
    const ushort* __restrict__ out_v_b, const ushort* __restrict__ Wngt,
    const float* __restrict__ b_ng, const float* __restrict__ h,
    ushort* __restrict__ tmp_b,
    const ushort* __restrict__ out_g_b, const ushort* __restrict__ Wgoutt,
    ushort* __restrict__ gsum_b)
{
  __shared__ __align__(16) ushort As[64*72], Bs[64*72];
  floatx4 acc[4];
  const int lane = threadIdx.x & 63, wave = threadIdx.x >> 6;
  const int quad = lane >> 4, m = lane & 15;
  const int bN = blockIdx.y*64;
  if (blockIdx.x < 64) {
    const int bM = blockIdx.x*64;
    gemm_core<256>(out_v_b, Wngt, bM, bN, acc, As, Bs);
    #pragma unroll
    for (int ct = 0; ct < 4; ++ct) {
      const int c = bN + ct*16 + m;
      #pragma unroll
      for (int r = 0; r < 4; ++r) {
        const int i = bM + wave*16 + quad*4 + r;
        tmp_b[(size_t)i*256 + c] =
            f2bf(acc[ct][r] + b_ng[c] + h[(size_t)i*256 + c] * SQRT_E);
      }
    }
  } else {
    const int bM = (blockIdx.x - 64)*64;
    gemm_core<256>(out_g_b, Wgoutt, bM, bN, acc, As, Bs);
    #pragma unroll
    for (int ct = 0; ct < 4; ++ct) {
      const int c = bN + ct*16 + m;
      #pragma unroll
      for (int r = 0; r < 4; ++r) {
        const int i = bM + wave*16 + quad*4 + r;
        gsum_b[(size_t)i*256 + c] = f2bf(acc[ct][r]);
      }
    }
  }
}

// ---------------- k5c+k5d fused ----------------
__global__ __launch_bounds__(256) void k56cd(
    const ushort* __restrict__ tmp_b, const ushort* __restrict__ Whdect,
    const float* __restrict__ b_hdec,
    const ushort* __restrict__ gsum_b, const ushort* __restrict__ Wgdect,
    const float* __restrict__ pre0,
    float* __restrict__ out)
{
  __shared__ __align__(16) ushort As[64*72], Bs[64*72];
  const int t = threadIdx.x;
  const int lane = t & 63, wave = t >> 6;
  const int quad = lane >> 4, m = lane & 15;
  if (blockIdx.x < 64) {
    floatx4 acc[4];
    const int bM = blockIdx.x*64, bN = blockIdx.y*64;
    gemm_core<256>(tmp_b, Whdect, bM, bN, acc, As, Bs);
    #pragma unroll
    for (int ct = 0; ct < 4; ++ct) {
      const int c = bN + ct*16 + m;
      #pragma unroll
      for (int r = 0; r < 4; ++r) {
        const int i = bM + wave*16 + quad*4 + r;
        out[196608 + (size_t)i*256 + c] = acc[ct][r] + b_hdec[c];
      }
    }
  } else if (blockIdx.y == 0) {
    const int bM = (blockIdx.x - 64)*64;
    floatx4 acc = {0.f, 0.f, 0.f, 0.f};
    const int row = t >> 2, kq = (t & 3) * 8;
    for (int k0 = 0; k0 < 256; k0 += 32) {
      __syncthreads();
      *(short8*)&As[row*40 + kq] = *(const short8*)&gsum_b[(size_t)(bM+row)*256 + k0 + kq];
      if (t < 64)
        *(short8*)&Bs[(t>>2)*40 + kq] = *(const short8*)&Wgdect[(size_t)(t>>2)*256 + k0 + kq];
      __syncthreads();
      const short8 af = *(const short8*)&As[(wave*16 + m)*40 + quad*8];
      const short8 bf = *(const short8*)&Bs[m*40 + quad*8];
      acc = __builtin_amdgcn_mfma_f32_16x16x32_bf16(af, bf, acc, 0, 0, 0);
    }
    #pragma unroll
    for (int r = 0; r < 4; ++r) {
      const int i3 = bM + wave*16 + quad*4 + r;
      out[(size_t)i3*16 + m] = acc[r] + pre0[(size_t)i3*16 + m];
    }
  }
}

extern "C" void kernel_launch(void* const* d_in, const int* in_sizes, int n_in,
                              void* d_out, int out_size, void* d_ws, size_t ws_size,
                              hipStream_t stream) {
  const float* equ    = (const float*)d_in[0];
  const float* h      = (const float*)d_in[1];
  const float* W_equ  = (const float*)d_in[4];
  const float* W_gproj= (const float*)d_in[5];
  const float* W_vg   = (const float*)d_in[6];
  const float* W_g1   = (const float*)d_in[7];
  const float* b_g1   = (const float*)d_in[8];
  const float* W_g2   = (const float*)d_in[9];
  const float* b_g2   = (const float*)d_in[10];
  const float* W_q    = (const float*)d_in[11];
  const float* b_q    = (const float*)d_in[12];
  const float* W_k    = (const float*)d_in[13];
  const float* b_k    = (const float*)d_in[14];
  const float* W_v    = (const float*)d_in[15];
  const float* b_v    = (const float*)d_in[16];
  const float* W_ng   = (const float*)d_in[17];
  const float* b_ng   = (const float*)d_in[18];
  const float* W_gout = (const float*)d_in[19];
  const float* W_gdec = (const float*)d_in[20];
  const float* W_hdec = (const float*)d_in[21];
  const float* b_hdec = (const float*)d_in[22];
  float* out = (float*)d_out;

  // ---- workspace layout (lifetimes annotated), peak 50.4 MiB (52 proven) ----
  // Stages: P=prep G1 G2 G34 A=attn M=merge B=k56ab C=k56cd
  char* wsb = (char*)d_ws;
  constexpr size_t MiB = 1048576;
  float*  q_ws    = (float*) (wsb +  0*MiB);            // 4 MiB   [G34 -> A]
  ushort* kh      = (ushort*)(wsb +  4*MiB);            // 2 MiB   [G34 -> A]
  float*  Pml     = (float*) (wsb +  6*MiB);            // 1 MiB   [A -> M] (4 splits)
  float*  pre0    = (float*) (wsb +  7*MiB);            // 0.75 MiB[P -> C]
  ushort* vt      = (ushort*)(wsb +  8*MiB);            // 8 MiB   [G34 -> A]
  ushort* h2h     = (ushort*)(wsb + 17*MiB);            // 4 MiB   [P/G2 -> G34]
  ushort* h2l     = (ushort*)(wsb + 21*MiB);            // 4 MiB
  ushort* g_src_b = (ushort*)(wsb + 25*MiB);            // 6 MiB   [P -> G34]
  ushort* wbase   = (ushort*)(wsb + 31*MiB);            // 2.875 MiB [P -> G34]
  ushort* Wg1t = wbase;                                 // 512x1024
  ushort* Wg2t = wbase + 524288;                        // 256x512
  ushort* Wth  = wbase + 655360;                        // 768x512 hi
  ushort* Wtl  = wbase + 1048576;                       // 768x512 lo
  ushort* Wvgt = wbase + 1441792;                       // 256x256
  ushort* gram_b  = (ushort*)(wsb + 34*MiB);            // 8 MiB   [P -> G1]
  ushort* hidden  = (ushort*)(wsb + 42*MiB);            // 4 MiB   [G1 -> G2]
  // split-K x4 attention partials (all alias dead regions):
  ushort* Po0     = (ushort*)(wsb + 17*MiB);            // 8 MiB [A -> M] alias h2h/h2l
  ushort* Po1     = (ushort*)(wsb + 25*MiB);            // 8 MiB [A -> M] alias g_src_b+wbase
  ushort* Po2     = (ushort*)(wsb + 34*MiB);            // 8 MiB [A -> M] alias gram_b
  ushort* Po3     = (ushort*)(wsb + 42*MiB);            // 8 MiB [A -> M] alias hidden+
  ushort* wbase2  = (ushort*)(wsb + 50*MiB);            // 0.4 MiB [P -> B/C]
  ushort* Wngt   = wbase2;                              // 256x256
  ushort* Wgoutt = wbase2 + 65536;                      // 256x256
  ushort* Whdect = wbase2 + 131072;                     // 256x256
  ushort* Wgdect = wbase2 + 196608;                     // 16x256
  ushort* out_v_b = (ushort*)(wsb +  4*MiB);            // 2 MiB [M -> B] alias kh
  ushort* out_g_b = (ushort*)(wsb +  8*MiB);            // 6 MiB [M -> B] alias vt
  ushort* tmp_b   = (ushort*)(wsb + 17*MiB);            // 2 MiB [B -> C] alias Po0
  ushort* gsum_b  = (ushort*)(wsb + 25*MiB);            // 6 MiB [B -> C] alias Po1

  // ---- 1 mega-prep launch (10 transposes + hsplit + k1 + pre0) ----
  k_prep<<<9480, 256, 0, stream>>>(
      equ, h, W_equ, W_gproj, W_g1, W_g2, W_q, W_k, W_v,
      W_vg, W_ng, W_gout, W_hdec, W_gdec,
      Wg1t, Wg2t, Wth, Wtl, Wvgt, Wngt, Wgoutt, Whdect, Wgdect,
      h2h, h2l, g_src_b, gram_b, pre0);

  // ---- GEMM chain (BK=64 double-pumped cores) ----
  k_g1<<<dim3(64, 8), 256, 0, stream>>>(gram_b, Wg1t, b_g1, hidden);
  k_g2<<<dim3(64, 4), 256, 0, stream>>>(hidden, Wg2t, b_g2, h2h, h2l);
  k_g34<<<dim3(192, 8), 256, 0, stream>>>(h2h, h2l, Wth, Wtl, b_q, b_k, b_v,
                                          g_src_b, Wvgt, q_ws, kh, vt);

  // ---- attention (8-wave, single-bf16 Q, in-reg P, split-K x4) + merge ----
  dim3 g3(32, 8, 4);
  k3_attn<<<g3, 512, 0, stream>>>(q_ws, kh, vt, Po0, Po1, Po2, Po3, Pml);
  k_merge<<<2048, 256, 0, stream>>>(Po0, Po1, Po2, Po3, Pml, out_v_b, out_g_b);

  // ---- epilogue GEMMs (fused pairs) ----
  k56ab<<<dim3(256, 4), 256, 0, stream>>>(out_v_b, Wngt, b_ng, h, tmp_b,
                                          out_g_b, Wgoutt, gsum_b);
  k56cd<<<dim3(256, 4), 256, 0, stream>>>(tmp_b, Whdect, b_hdec,
                                          gsum_b, Wgdect, pre0, out);
}

// Round 17
// 257.828 us; speedup vs baseline: 1.0367x; 1.0093x over previous
//
#include <hip/hip_runtime.h>
#include <hip/hip_bf16.h>

typedef __attribute__((ext_vector_type(8))) short short8;
typedef __attribute__((ext_vector_type(4))) short bhalf4;
typedef __attribute__((ext_vector_type(4))) float floatx4;

constexpr int N_ = 4096;
constexpr float SQRT_E = 16.0f;
// q scale folded with log2(e): softmax computed in exp2 domain
constexpr float QSCALE = 0.17677669529663687f * 1.4426950408889634f;

__device__ __forceinline__ ushort f2bf(float x) {
  __hip_bfloat16 h = __float2bfloat16(x);
  return *reinterpret_cast<ushort*>(&h);
}
__device__ __forceinline__ float bf2f(ushort b) {
  unsigned int u = ((unsigned int)b) << 16;
  return __uint_as_float(u);
}

// ---------------- transpose helper (device side of mega-prep) ----------------
__device__ __forceinline__ void do_transpose(
    const float* __restrict__ src, ushort* __restrict__ dsth,
    ushort* __restrict__ dstl, int R, int C, int lb, int cb_shift,
    float* smem, int hasLo)
{
  float (*tile)[33] = (float(*)[33])smem;
  const int r0 = (lb >> cb_shift) * 32;
  const int c0 = (lb & ((1 << cb_shift) - 1)) * 32;
  const int tx = threadIdx.x & 31, ty = threadIdx.x >> 5;
  #pragma unroll
  for (int p = 0; p < 4; ++p) {
    const int lr = p*8 + ty;
    tile[lr][tx] = (r0+lr < R && c0+tx < C) ? src[(size_t)(r0+lr)*C + c0 + tx] : 0.f;
  }
  __syncthreads();
  #pragma unroll
  for (int p = 0; p < 4; ++p) {
    const int dc = p*8 + ty;
    if (c0+dc < C && r0+tx < R) {
      const float v = tile[tx][dc];
      const ushort hi = f2bf(v);
      dsth[(size_t)(c0+dc)*R + r0 + tx] = hi;
      if (hasLo) dstl[(size_t)(c0+dc)*R + r0 + tx] = f2bf(v - bf2f(hi));
    }
  }
}

// ---------------- mega-prep: all transposes + hsplit + k1 in ONE launch --------
__global__ __launch_bounds__(256) void k_prep(
    const float* __restrict__ equ, const float* __restrict__ h,
    const float* __restrict__ W_equ, const float* __restrict__ W_gproj,
    const float* __restrict__ W_g1, const float* __restrict__ W_g2,
    const float* __restrict__ W_q, const float* __restrict__ W_k,
    const float* __restrict__ W_v, const float* __restrict__ W_vg,
    const float* __restrict__ W_ng, const float* __restrict__ W_gout,
    const float* __restrict__ W_hdec, const float* __restrict__ W_gdec,
    ushort* __restrict__ Wg1t, ushort* __restrict__ Wg2t,
    ushort* __restrict__ Wth, ushort* __restrict__ Wtl,
    ushort* __restrict__ Wvgt, ushort* __restrict__ Wngt,
    ushort* __restrict__ Wgoutt, ushort* __restrict__ Whdect,
    ushort* __restrict__ Wgdect,
    ushort* __restrict__ h2h, ushort* __restrict__ h2l,
    ushort* __restrict__ g_src_b, ushort* __restrict__ gram_b,
    float* __restrict__ pre0)
{
  __shared__ __align__(16) float smem[1120];
  const int b = blockIdx.x;
  const int t = threadIdx.x;

  if (b < 512) {            // W_g1 [1024,512] -> Wg1t
    do_transpose(W_g1, Wg1t, nullptr, 1024, 512, b, 4, smem, 0);
  } else if (b < 640) {     // W_g2 [512,256]
    do_transpose(W_g2, Wg2t, nullptr, 512, 256, b-512, 3, smem, 0);
  } else if (b < 768) {     // W_q hi/lo
    do_transpose(W_q, Wth, Wtl, 512, 256, b-640, 3, smem, 1);
  } else if (b < 896) {     // W_k hi/lo
    do_transpose(W_k, Wth + 256*512, Wtl + 256*512, 512, 256, b-768, 3, smem, 1);
  } else if (b < 1024) {    // W_v hi/lo
    do_transpose(W_v, Wth + 512*512, Wtl + 512*512, 512, 256, b-896, 3, smem, 1);
  } else if (b < 1088) {    // W_vg
    do_transpose(W_vg, Wvgt, nullptr, 256, 256, b-1024, 3, smem, 0);
  } else if (b < 1152) {    // W_ng
    do_transpose(W_ng, Wngt, nullptr, 256, 256, b-1088, 3, smem, 0);
  } else if (b < 1216) {    // W_gout
    do_transpose(W_gout, Wgoutt, nullptr, 256, 256, b-1152, 3, smem, 0);
  } else if (b < 1280) {    // W_hdec
    do_transpose(W_hdec, Whdect, nullptr, 256, 256, b-1216, 3, smem, 0);
  } else if (b < 1288) {    // W_gdec [256,16]
    do_transpose(W_gdec, Wgdect, nullptr, 256, 16, b-1280, 0, smem, 0);
  } else if (b < 5384) {    // hsplit: h_src half of h2 (hi/lo)
    const int i = b - 1288;
    const float v = h[(size_t)i*256 + t] * SQRT_E;
    const ushort hi = f2bf(v);
    h2h[(size_t)i*512 + 256 + t] = hi;
    h2l[(size_t)i*512 + 256 + t] = f2bf(v - bf2f(hi));
  } else {                  // k1: g_src_b + gram_b + pre0
    float* eq   = smem;        // 48
    float* gs   = smem + 48;   // 768
    float* g2p  = smem + 816;  // 96
    float* part = smem + 912;  // 192
    const int i = b - 5384;
    if (t < 48) eq[t] = equ[(size_t)i*48 + t];
    __syncthreads();
    #pragma unroll
    for (int j = 0; j < 3; ++j) {
      float s = 0.f;
      #pragma unroll
      for (int m = 0; m < 16; ++m) s += eq[j*16+m] * W_equ[m*256 + t];
      s *= SQRT_E;
      gs[j*256 + t] = s;
      g_src_b[((size_t)i*3 + j)*256 + t] = f2bf(s);
    }
    __syncthreads();
    if (t < 192) {            // 2-way K-split of the gproj GEMV
      const int o = t % 96, half = t / 96;
      const int j = o >> 5, a = o & 31;
      const int e0 = half * 128;
      float s = 0.f;
      for (int e = 0; e < 128; ++e)
        s += gs[j*256 + e0 + e] * W_gproj[(size_t)(e0+e)*32 + a];
      part[t] = s;
    }
    __syncthreads();
    if (t < 96) g2p[t] = part[t] + part[96 + t];
    __syncthreads();
    #pragma unroll
    for (int r = 0; r < 4; ++r) {
      const int idx = r*256 + t;
      const int a = idx >> 5, bb = idx & 31;
      const float s = g2p[a]*g2p[bb] + g2p[32+a]*g2p[32+bb] + g2p[64+a]*g2p[64+bb];
      gram_b[(size_t)i*1024 + idx] = f2bf(s);
    }
    // pre0 = g_src(f32) @ W_gdec, 4-way K-split. t = j*64 + ks*16 + mc
    if (t < 192) {
      const int j = t >> 6, ks = (t >> 4) & 3, mc = t & 15;
      const int e0 = ks * 64;
      float s = 0.f;
      for (int e = 0; e < 64; ++e)
        s += gs[j*256 + e0 + e] * W_gdec[(size_t)(e0 + e)*16 + mc];
      part[t] = s;
    }
    __syncthreads();
    if (t < 48) {
      const int j = t >> 4, mc = t & 15;
      pre0[((size_t)i*3 + j)*16 + mc] =
          part[j*64 + mc] + part[j*64 + 16 + mc] +
          part[j*64 + 32 + mc] + part[j*64 + 48 + mc];
    }
  }
}

// ---------------- GEMM cores: BK=64, double-pumped, register prefetch -----------
template<int KTOT>
__device__ __forceinline__ void gemm_core(
    const ushort* __restrict__ A, const ushort* __restrict__ Bt,
    int bM, int bN, floatx4 acc[4], ushort* As, ushort* Bs)
{
  const int t = threadIdx.x;
  const int wave = t >> 6, lane = t & 63, quad = lane >> 4, m = lane & 15;
  #pragma unroll
  for (int ct = 0; ct < 4; ++ct) acc[ct] = {0.f, 0.f, 0.f, 0.f};
  const int ca = t*2, cb = t*2 + 1;
  const int ra = ca >> 3, pa = ca & 7;
  const int rb = cb >> 3, pb = cb & 7;
  const ushort* pA0 = A  + (size_t)(bM+ra)*KTOT + pa*8;
  const ushort* pA1 = A  + (size_t)(bM+rb)*KTOT + pb*8;
  const ushort* pB0 = Bt + (size_t)(bN+ra)*KTOT + pa*8;
  const ushort* pB1 = Bt + (size_t)(bN+rb)*KTOT + pb*8;
  short8 rA0 = *(const short8*)pA0, rA1 = *(const short8*)pA1;
  short8 rB0 = *(const short8*)pB0, rB1 = *(const short8*)pB1;
  for (int k0 = 0; k0 < KTOT; k0 += 64) {
    __syncthreads();
    *(short8*)&As[ra*72 + pa*8] = rA0;
    *(short8*)&As[rb*72 + pb*8] = rA1;
    *(short8*)&Bs[ra*72 + pa*8] = rB0;
    *(short8*)&Bs[rb*72 + pb*8] = rB1;
    if (k0 + 64 < KTOT) {
      pA0 += 64; pA1 += 64; pB0 += 64; pB1 += 64;
      rA0 = *(const short8*)pA0; rA1 = *(const short8*)pA1;
      rB0 = *(const short8*)pB0; rB1 = *(const short8*)pB1;
    }
    __syncthreads();
    #pragma unroll
    for (int ks = 0; ks < 2; ++ks) {
      const short8 af = *(const short8*)&As[(wave*16 + m)*72 + ks*32 + quad*8];
      #pragma unroll
      for (int ct = 0; ct < 4; ++ct) {
        const short8 bf = *(const short8*)&Bs[(ct*16 + m)*72 + ks*32 + quad*8];
        acc[ct] = __builtin_amdgcn_mfma_f32_16x16x32_bf16(af, bf, acc[ct], 0, 0, 0);
      }
    }
  }
}

// G1: hidden = relu(gram @ W_g1 + b_g1)
__global__ __launch_bounds__(256) void k_g1(
    const ushort* __restrict__ gram_b, const ushort* __restrict__ Wg1t,
    const float* __restrict__ b_g1, ushort* __restrict__ hidden)
{
  __shared__ __align__(16) ushort As[64*72], Bs[64*72];
  floatx4 acc[4];
  const int bM = blockIdx.x*64, bN = blockIdx.y*64;
  gemm_core<1024>(gram_b, Wg1t, bM, bN, acc, As, Bs);
  const int lane = threadIdx.x & 63, wave = threadIdx.x >> 6;
  const int quad = lane >> 4, m = lane & 15;
  #pragma unroll
  for (int ct = 0; ct < 4; ++ct) {
    const int c = bN + ct*16 + m;
    #pragma unroll
    for (int r = 0; r < 4; ++r) {
      const int i = bM + wave*16 + quad*4 + r;
      hidden[(size_t)i*512 + c] = f2bf(fmaxf(acc[ct][r] + b_g1[c], 0.f));
    }
  }
}

// G2: g2 = hidden @ W_g2 + b_g2 -> hi/lo into h2 cols 0..255
__global__ __launch_bounds__(256) void k_g2(
    const ushort* __restrict__ hidden, const ushort* __restrict__ Wg2t,
    const float* __restrict__ b_g2, ushort* __restrict__ h2h, ushort* __restrict__ h2l)
{
  __shared__ __align__(16) ushort As[64*72], Bs[64*72];
  floatx4 acc[4];
  const int bM = blockIdx.x*64, bN = blockIdx.y*64;
  gemm_core<512>(hidden, Wg2t, bM, bN, acc, As, Bs);
  const int lane = threadIdx.x & 63, wave = threadIdx.x >> 6;
  const int quad = lane >> 4, m = lane & 15;
  #pragma unroll
  for (int ct = 0; ct < 4; ++ct) {
    const int c = bN + ct*16 + m;
    #pragma unroll
    for (int r = 0; r < 4; ++r) {
      const int i = bM + wave*16 + quad*4 + r;
      const float s = acc[ct][r] + b_g2[c];
      const ushort hi = f2bf(s);
      h2h[(size_t)i*512 + c] = hi;
      h2l[(size_t)i*512 + c] = f2bf(s - bf2f(hi));
    }
  }
}

// G3+G4 fused: q/k/v all 1-TERM bf16 GEMM (r17: q is rounded to bf16 in k3
// and k at output anyway — the 3-term hi/lo precision was computed and then
// discarded at the bf16 boundary; absmax sits at the output-quantization
// floor 0.125 with threshold 0.5125). LDS union drops 4 -> 2 buffers
// (18.4 KB) -> 8 blocks/CU, grid 1536 fits ONE occupancy round (the r14
// split attempted this via separate kernels and lost to dispatch tails;
// this gets the occupancy inside the monolithic grid). h2l/Wtl now unused.
// NOTE (r14): keep monolithic — mixed-grid load balance beats LDS-union split.
__global__ __launch_bounds__(256) void k_g34(
    const ushort* __restrict__ h2h, const ushort* __restrict__ h2l,
    const ushort* __restrict__ Wth, const ushort* __restrict__ Wtl,
    const float* __restrict__ b_q, const float* __restrict__ b_k,
    const float* __restrict__ b_v,
    const ushort* __restrict__ g_src_b, const ushort* __restrict__ Wvgt,
    float* __restrict__ q_ws, ushort* __restrict__ kh,
    ushort* __restrict__ vt)
{
  __shared__ __align__(16) ushort S0[64*72], S1[64*72];
  const int lb = blockIdx.y*192 + blockIdx.x;     // grid (192,8) = 1536
  const int lane = threadIdx.x & 63, wave = threadIdx.x >> 6;
  const int quad = lane >> 4, m = lane & 15;
  floatx4 acc[4];
  if (lb < 768) {
    const int bM = (lb & 63)*64, bN = (lb >> 6)*64;
    gemm_core<512>(h2h, Wth, bM, bN, acc, S0, S1);
    if (bN < 512) {
      #pragma unroll
      for (int ct = 0; ct < 4; ++ct) {
        const int c = bN + ct*16 + m;
        #pragma unroll
        for (int r = 0; r < 4; ++r) {
          const int i = bM + wave*16 + quad*4 + r;
          if (c < 256) {
            const float s = acc[ct][r] + b_q[c];
            q_ws[((size_t)(c >> 5)*N_ + i)*32 + (c & 31)] = s * QSCALE;
          } else {
            const int cc = c - 256;
            const float s = acc[ct][r] + b_k[cc];
            kh[((size_t)(cc >> 5)*N_ + i)*32 + (cc & 31)] = f2bf(s);
          }
        }
      }
    } else {
      #pragma unroll
      for (int ct = 0; ct < 4; ++ct) {
        const int cc = bN + ct*16 + m - 512;
        #pragma unroll
        for (int r = 0; r < 4; ++r) {
          const int i = bM + wave*16 + quad*4 + r;
          const float s = acc[ct][r] + b_v[cc];
          vt[((size_t)(cc >> 5)*128 + (cc & 31))*N_ + i] = f2bf(s);
        }
      }
    }
  } else {
    const int lb2 = lb - 768;
    const int bM = (lb2 >> 2)*64, bN = (lb2 & 3)*64;
    gemm_core<256>(g_src_b, Wvgt, bM, bN, acc, S0, S1);
    #pragma unroll
    for (int ct = 0; ct < 4; ++ct) {
      const int c = bN + ct*16 + m;
      const int hh = c >> 5, d = c & 31;
      #pragma unroll
      for (int r = 0; r < 4; ++r) {
        const int i3 = bM + wave*16 + quad*4 + r;
        const int i = i3 / 3, j = i3 - 3*i;
        vt[((size_t)hh*128 + 32 + j*32 + d)*N_ + i] = f2bf(acc[ct][r]);
      }
    }
  }
}

// ---------------- K3: swapped-operand flash attention, P fully in-register -----
// mfma(K,Q) gives S^T with q = lane&15 -> softmax is lane-local. V columns are
// stored bit-permuted in LDS (slot{5..0} = {k5,k3,k2,k4,k1,k0}) so each lane's
// own 16 P values form its PV B-fragment directly: no P LDS buffer, no cross-
// lane exchange. PV swapped too (O^T = V^T P^T). Denominator = ones-row MFMA.
// r16: SINGLE-BF16 Q (absmax stayed 0.125 = output quantization floor).
// 8-wave blocks (512 thr, 128 q-rows). Grid (32,8,4)=1024 = 4 blk/CU resident.
// LESSONS: (r10) doubling accumulator state spills (~64 live VGPR budget);
// (r12) fixed-base exp2 softmax NaNs — the online max is load-bearing;
// (r14) splitting k_g34 regressed (mixed-grid load balance beats LDS-union).
__global__ __launch_bounds__(512, 4) void k3_attn(
    const float* __restrict__ q_ws, const ushort* __restrict__ kh,
    const ushort* __restrict__ vt,
    ushort* __restrict__ Po0, ushort* __restrict__ Po1,
    ushort* __restrict__ Po2, ushort* __restrict__ Po3,
    float* __restrict__ Pml)
{
  __shared__ __align__(16) ushort Khs[64*40];              // 5 KiB
  __shared__ __align__(16) ushort Vs[128*64];              // 16 KiB, permuted+swizzled
  __shared__ float li_s[128];

  const int t    = threadIdx.x;          // 0..511
  const int wave = t >> 6;               // 0..7
  const int lane = t & 63;
  const int quad = lane >> 4;
  const int m    = lane & 15;
  const int h    = blockIdx.y;
  const int s    = blockIdx.z;
  const int n0q  = blockIdx.x * 128;

  const int ktb = s * 16;
  const int kte = ktb + 16;

  // Q fragment (B-operand; rows n0q + wave*16 + m): SINGLE bf16 (r16)
  union { short8 v; ushort u[8]; } Aqh;
  {
    const float* qp = q_ws + ((size_t)h*N_ + n0q + wave*16 + m)*32 + quad*8;
    #pragma unroll
    for (int jj = 0; jj < 8; ++jj) Aqh.u[jj] = f2bf(qp[jj]);
  }

  // ones A-fragment: A row 0 = ones -> denominator row of O^T
  union { short8 v; ushort u[8]; } onesf;
  {
    const ushort ov = (m == 0) ? (ushort)0x3F80 : (ushort)0;
    #pragma unroll
    for (int jj = 0; jj < 8; ++jj) onesf.u[jj] = ov;
  }

  // Of[nt][r] = O^T[d = nt*16 + quad*4 + r][q = wave*16 + m]; Of8 row0 = denom
  floatx4 Of[8];
  #pragma unroll
  for (int nt = 0; nt < 8; ++nt) Of[nt] = {0.f, 0.f, 0.f, 0.f};
  floatx4 Of8 = {0.f, 0.f, 0.f, 0.f};
  float mi = -3.0e38f;

  // K staging: 256 chunks handled by threads t < 256
  const int krow = t >> 2, kch = (t & 3) * 8;
  const ushort* pKh = kh + ((size_t)h*N_ + ktb*64 + (krow & 63))*32 + kch;

  // V staging: 1024 (row,g) chunks over 512 threads (2 each); each 8-k run
  // splits into two permuted b64s.
  // slot = 32*(g>>2) + 16*(g&1) + 8*(e>>2) + 4*((g>>1)&1) + (e&3)
  const ushort* pV[2];
  int wv0[2], wv1[2];
  #pragma unroll
  for (int p = 0; p < 2; ++p) {
    const int idx = p*512 + t, row = idx >> 3, g = idx & 7;
    pV[p] = vt + ((size_t)h*128 + row)*N_ + ktb*64 + g*8;
    const int sb0  = 32*(g>>2) + 16*(g&1) + 4*((g>>1)&1);
    const int blk0 = sb0 >> 3, off = sb0 & 4, r7 = row & 7;
    wv0[p] = row*64 + ((blk0       ^ r7) * 8) + off;
    wv1[p] = row*64 + (((blk0 + 1) ^ r7) * 8) + off;
  }

  short8 rK0 = {0,0,0,0,0,0,0,0};
  if (t < 256) rK0 = *(const short8*)pKh;
  short8 rV[2];
  #pragma unroll
  for (int p = 0; p < 2; ++p) rV[p] = *(const short8*)pV[p];

  const int x7 = m & 7;   // read-side swizzle key (row = nt*16 + m)

  for (int kt = ktb; kt < kte; ++kt) {
    __syncthreads();
    if (t < 256) *(short8*)&Khs[krow*40 + kch] = rK0;
    #pragma unroll
    for (int p = 0; p < 2; ++p) {
      union { short8 v; bhalf4 h2[2]; } tmp;
      tmp.v = rV[p];
      *(bhalf4*)&Vs[wv0[p]] = tmp.h2[0];
      *(bhalf4*)&Vs[wv1[p]] = tmp.h2[1];
    }
    if (kt + 1 < kte) {
      if (t < 256) { pKh += 2048; rK0 = *(const short8*)pKh; }
      #pragma unroll
      for (int p = 0; p < 2; ++p) { pV[p] += 64; rV[p] = *(const short8*)pV[p]; }
    }
    __syncthreads();

    // S^T = K Q^T (swapped operands): sf[kb][r] = S[k=kb*16+quad*4+r][q=m-col]
    floatx4 sf[4];
    #pragma unroll
    for (int kb = 0; kb < 4; ++kb) {
      const short8 bkh = *(const short8*)&Khs[(kb*16 + m)*40 + quad*8];
      floatx4 sv = {0.f, 0.f, 0.f, 0.f};
      sv = __builtin_amdgcn_mfma_f32_16x16x32_bf16(bkh, Aqh.v, sv, 0, 0, 0);
      sf[kb] = sv;
    }

    // row max: 15 fmax local + 2 shuffle across quads (lanes m, m^16, m^32, m^48)
    float nm = fmaxf(fmaxf(sf[0][0], sf[0][1]), fmaxf(sf[0][2], sf[0][3]));
    nm = fmaxf(nm, fmaxf(fmaxf(sf[1][0], sf[1][1]), fmaxf(sf[1][2], sf[1][3])));
    nm = fmaxf(nm, fmaxf(fmaxf(sf[2][0], sf[2][1]), fmaxf(sf[2][2], sf[2][3])));
    nm = fmaxf(nm, fmaxf(fmaxf(sf[3][0], sf[3][1]), fmaxf(sf[3][2], sf[3][3])));
    nm = fmaxf(nm, __shfl_xor(nm, 16));
    nm = fmaxf(nm, __shfl_xor(nm, 32));

    if (__any(nm > mi + 20.f)) {
      const float mn = fmaxf(mi, nm);
      const float al = exp2f(mi - mn);
      mi = mn;
      #pragma unroll
      for (int nt = 0; nt < 8; ++nt) {
        Of[nt][0] *= al; Of[nt][1] *= al; Of[nt][2] *= al; Of[nt][3] *= al;
      }
      Of8[0] *= al; Of8[1] *= al; Of8[2] *= al; Of8[3] *= al;
    }

    // P = exp2(S - mi), Schraudolph bits, packed in-register into B-fragments:
    // pk[ks].u[p] = {P(kb=2ks+(p>>1), r=2(p&1)) lo16, r=2(p&1)+1 hi16}
    const float base = 1064866805.0f - mi*8388608.0f;
    union { short8 v; unsigned int u[4]; } pk[2];
    #pragma unroll
    for (int kb = 0; kb < 4; ++kb) {
      int p0 = (int)(sf[kb][0]*8388608.0f + base); p0 = p0 < 0 ? 0 : p0;
      int p1 = (int)(sf[kb][1]*8388608.0f + base); p1 = p1 < 0 ? 0 : p1;
      int p2 = (int)(sf[kb][2]*8388608.0f + base); p2 = p2 < 0 ? 0 : p2;
      int p3 = (int)(sf[kb][3]*8388608.0f + base); p3 = p3 < 0 ? 0 : p3;
      pk[kb >> 1].u[(kb & 1)*2 + 0] = ((unsigned)p0 >> 16) | ((unsigned)p1 & 0xffff0000u);
      pk[kb >> 1].u[(kb & 1)*2 + 1] = ((unsigned)p2 >> 16) | ((unsigned)p3 & 0xffff0000u);
    }

    // O^T += V^T P^T : A = V^T fragment from permuted LDS, B = pk (in-register)
    #pragma unroll
    for (int ks = 0; ks < 2; ++ks) {
      #pragma unroll
      for (int nt = 0; nt < 8; ++nt) {
        const short8 av = *(const short8*)&Vs[(nt*16 + m)*64 + (((ks*4 + quad) ^ x7) * 8)];
        Of[nt] = __builtin_amdgcn_mfma_f32_16x16x32_bf16(av, pk[ks].v, Of[nt], 0, 0, 0);
      }
      Of8 = __builtin_amdgcn_mfma_f32_16x16x32_bf16(onesf.v, pk[ks].v, Of8, 0, 0, 0);
    }
  }

  // denom lives at quad==0 lanes (C row 0), broadcast via LDS
  if (quad == 0) li_s[wave*16 + m] = Of8[0];
  __syncthreads();
  const float linv = 1.0f / li_s[wave*16 + m];

  ushort* Po = (s == 0) ? Po0 : ((s == 1) ? Po1 : ((s == 2) ? Po2 : Po3));
  const int n = n0q + wave*16 + m;
  #pragma unroll
  for (int nt = 0; nt < 8; ++nt) {
    unsigned int lo = (unsigned)f2bf(Of[nt][0] * linv) | ((unsigned)f2bf(Of[nt][1] * linv) << 16);
    unsigned int hi = (unsigned)f2bf(Of[nt][2] * linv) | ((unsigned)f2bf(Of[nt][3] * linv) << 16);
    uint2 pkd; pkd.x = lo; pkd.y = hi;
    *(uint2*)&Po[((size_t)h*N_ + n)*128 + nt*16 + quad*4] = pkd;
  }
  if (quad == 0) {
    Pml[(((size_t)s*8 + h)*N_ + n)*2 + 0] = mi;
    Pml[(((size_t)s*8 + h)*N_ + n)*2 + 1] = Of8[0];
  }
}

// ---------------- merge: combine 4 split-K partials (8 elems/thread) ------------
__global__ __launch_bounds__(256) void k_merge(
    const ushort* __restrict__ Po0, const ushort* __restrict__ Po1,
    const ushort* __restrict__ Po2, const ushort* __restrict__ Po3,
    const float* __restrict__ Pml,
    ushort* __restrict__ out_v_b, ushort* __restrict__ out_g_b)
{
  const int idx = blockIdx.x*256 + threadIdx.x;
  const int c0 = (idx & 15) * 8;
  const int n  = (idx >> 4) & 4095;
  const int h  = idx >> 16;
  float mm[4], ll[4];
  #pragma unroll
  for (int s = 0; s < 4; ++s) {
    mm[s] = Pml[(((size_t)s*8 + h)*N_ + n)*2 + 0];
    ll[s] = Pml[(((size_t)s*8 + h)*N_ + n)*2 + 1];
  }
  const float M = fmaxf(fmaxf(mm[0], mm[1]), fmaxf(mm[2], mm[3]));
  float w[4], tot = 0.f;
  #pragma unroll
  for (int s = 0; s < 4; ++s) { w[s] = exp2f(mm[s] - M) * ll[s]; tot += w[s]; }
  const float inv = 1.0f / tot;
  union { short8 v; ushort u[8]; } a, b, c, d, res;
  a.v = *(const short8*)&Po0[((size_t)h*N_ + n)*128 + c0];
  b.v = *(const short8*)&Po1[((size_t)h*N_ + n)*128 + c0];
  c.v = *(const short8*)&Po2[((size_t)h*N_ + n)*128 + c0];
  d.v = *(const short8*)&Po3[((size_t)h*N_ + n)*128 + c0];
  #pragma unroll
  for (int j = 0; j < 8; ++j)
    res.u[j] = f2bf((w[0]*bf2f(a.u[j]) + w[1]*bf2f(b.u[j]) +
                     w[2]*bf2f(c.u[j]) + w[3]*bf2f(d.u[j])) * inv);
  if (c0 < 32) {
    *(short8*)&out_v_b[(size_t)n*256 + h*32 + c0] = res.v;
  } else {
    const int j = (c0 - 32) >> 5, cc = (c0 - 32) & 31;
    *(short8*)&out_g_b[((size_t)n*3 + j)*256 + h*32 + cc] = res.v;
  }
}

// ---------------- k5a+k5b fused ----------------
__global__ __launch_bounds__(256) void k56ab(
    const ushort* __restrict__ out_v_b, const ushort* __restrict__ Wngt,
    const float* __restrict__ b_ng, const float* __restrict__ h,
    ushort* __restrict__ tmp_b,
    const ushort* __restrict__ out_g_b, const ushort* __restrict__ Wgoutt,
    ushort* __restrict__ gsum_b)
{
  __shared__ __align__(16) ushort As[64*72], Bs[64*72];
  floatx4 acc[4];
  const int lane = threadIdx.x & 63, wave = threadIdx.x >> 6;
  const int quad = lane >> 4, m = lane & 15;
  const int bN = blockIdx.y*64;
  if (blockIdx.x < 64) {
    const int bM = blockIdx.x*64;
    gemm_core<256>(out_v_b, Wngt, bM, bN, acc, As, Bs);
    #pragma unroll
    for (int ct = 0; ct < 4; ++ct) {
      const int c = bN + ct*16 + m;
      #pragma unroll
      for (int r = 0; r < 4; ++r) {
        const int i = bM + wave*16 + quad*4 + r;
        tmp_b[(size_t)i*256 + c] =
            f2bf(acc[ct][r] + b_ng[c] + h[(size_t)i*256 + c] * SQRT_E);
      }
    }
  } else {
    const int bM = (blockIdx.x - 64)*64;
    gemm_core<256>(out_g_b, Wgoutt, bM, bN, acc, As, Bs);
    #pragma unroll
    for (int ct = 0; ct < 4; ++ct) {
      const int c = bN + ct*16 + m;
      #pragma unroll
      for (int r = 0; r < 4; ++r) {
        const int i = bM + wave*16 + quad*4 + r;
        gsum_b[(size_t)i*256 + c] = f2bf(acc[ct][r]);
      }
    }
  }
}

// ---------------- k5c+k5d fused ----------------
__global__ __launch_bounds__(256) void k56cd(
    const ushort* __restrict__ tmp_b, const ushort* __restrict__ Whdect,
    const float* __restrict__ b_hdec,
    const ushort* __restrict__ gsum_b, const ushort* __restrict__ Wgdect,
    const float* __restrict__ pre0,
    float* __restrict__ out)
{
  __shared__ __align__(16) ushort As[64*72], Bs[64*72];
  const int t = threadIdx.x;
  const int lane = t & 63, wave = t >> 6;
  const int quad = lane >> 4, m = lane & 15;
  if (blockIdx.x < 64) {
    floatx4 acc[4];
    const int bM = blockIdx.x*64, bN = blockIdx.y*64;
    gemm_core<256>(tmp_b, Whdect, bM, bN, acc, As, Bs);
    #pragma unroll
    for (int ct = 0; ct < 4; ++ct) {
      const int c = bN + ct*16 + m;
      #pragma unroll
      for (int r = 0; r < 4; ++r) {
        const int i = bM + wave*16 + quad*4 + r;
        out[196608 + (size_t)i*256 + c] = acc[ct][r] + b_hdec[c];
      }
    }
  } else if (blockIdx.y == 0) {
    const int bM = (blockIdx.x - 64)*64;
    floatx4 acc = {0.f, 0.f, 0.f, 0.f};
    const int row = t >> 2, kq = (t & 3) * 8;
    for (int k0 = 0; k0 < 256; k0 += 32) {
      __syncthreads();
      *(short8*)&As[row*40 + kq] = *(const short8*)&gsum_b[(size_t)(bM+row)*256 + k0 + kq];
      if (t < 64)
        *(short8*)&Bs[(t>>2)*40 + kq] = *(const short8*)&Wgdect[(size_t)(t>>2)*256 + k0 + kq];
      __syncthreads();
      const short8 af = *(const short8*)&As[(wave*16 + m)*40 + quad*8];
      const short8 bf = *(const short8*)&Bs[m*40 + quad*8];
      acc = __builtin_amdgcn_mfma_f32_16x16x32_bf16(af, bf, acc, 0, 0, 0);
    }
    #pragma unroll
    for (int r = 0; r < 4; ++r) {
      const int i3 = bM + wave*16 + quad*4 + r;
      out[(size_t)i3*16 + m] = acc[r] + pre0[(size_t)i3*16 + m];
    }
  }
}

extern "C" void kernel_launch(void* const* d_in, const int* in_sizes, int n_in,
                              void* d_out, int out_size, void* d_ws, size_t ws_size,
                              hipStream_t stream) {
  const float* equ    = (const float*)d_in[0];
  const float* h      = (const float*)d_in[1];
  const float* W_equ  = (const float*)d_in[4];
  const float* W_gproj= (const float*)d_in[5];
  const float* W_vg   = (const float*)d_in[6];
  const float* W_g1   = (const float*)d_in[7];
  const float* b_g1   = (const float*)d_in[8];
  const float* W_g2   = (const float*)d_in[9];
  const float* b_g2   = (const float*)d_in[10];
  const float* W_q    = (const float*)d_in[11];
  const float* b_q    = (const float*)d_in[12];
  const float* W_k    = (const float*)d_in[13];
  const float* b_k    = (const float*)d_in[14];
  const float* W_v    = (const float*)d_in[15];
  const float* b_v    = (const float*)d_in[16];
  const float* W_ng   = (const float*)d_in[17];
  const float* b_ng   = (const float*)d_in[18];
  const float* W_gout = (const float*)d_in[19];
  const float* W_gdec = (const float*)d_in[20];
  const float* W_hdec = (const float*)d_in[21];
  const float* b_hdec = (const float*)d_in[22];
  float* out = (float*)d_out;

  // ---- workspace layout (lifetimes annotated), peak 50.4 MiB (52 proven) ----
  // Stages: P=prep G1 G2 G34 A=attn M=merge B=k56ab C=k56cd
  char* wsb = (char*)d_ws;
  constexpr size_t MiB = 1048576;
  float*  q_ws    = (float*) (wsb +  0*MiB);            // 4 MiB   [G34 -> A]
  ushort* kh      = (ushort*)(wsb +  4*MiB);            // 2 MiB   [G34 -> A]
  float*  Pml     = (float*) (wsb +  6*MiB);            // 1 MiB   [A -> M] (4 splits)
  float*  pre0    = (float*) (wsb +  7*MiB);            // 0.75 MiB[P -> C]
  ushort* vt      = (ushort*)(wsb +  8*MiB);            // 8 MiB   [G34 -> A]
  ushort* h2h     = (ushort*)(wsb + 17*MiB);            // 4 MiB   [P/G2 -> G34]
  ushort* h2l     = (ushort*)(wsb + 21*MiB);            // 4 MiB   (dead after r17)
  ushort* g_src_b = (ushort*)(wsb + 25*MiB);            // 6 MiB   [P -> G34]
  ushort* wbase   = (ushort*)(wsb + 31*MiB);            // 2.875 MiB [P -> G34]
  ushort* Wg1t = wbase;                                 // 512x1024
  ushort* Wg2t = wbase + 524288;                        // 256x512
  ushort* Wth  = wbase + 655360;                        // 768x512 hi
  ushort* Wtl  = wbase + 1048576;                       // 768x512 lo (dead after r17)
  ushort* Wvgt = wbase + 1441792;                       // 256x256
  ushort* gram_b  = (ushort*)(wsb + 34*MiB);            // 8 MiB   [P -> G1]
  ushort* hidden  = (ushort*)(wsb + 42*MiB);            // 4 MiB   [G1 -> G2]
  // split-K x4 attention partials (all alias dead regions):
  ushort* Po0     = (ushort*)(wsb + 17*MiB);            // 8 MiB [A -> M] alias h2h/h2l
  ushort* Po1     = (ushort*)(wsb + 25*MiB);            // 8 MiB [A -> M] alias g_src_b+wbase
  ushort* Po2     = (ushort*)(wsb + 34*MiB);            // 8 MiB [A -> M] alias gram_b
  ushort* Po3     = (ushort*)(wsb + 42*MiB);            // 8 MiB [A -> M] alias hidden+
  ushort* wbase2  = (ushort*)(wsb + 50*MiB);            // 0.4 MiB [P -> B/C]
  ushort* Wngt   = wbase2;                              // 256x256
  ushort* Wgoutt = wbase2 + 65536;                      // 256x256
  ushort* Whdect = wbase2 + 131072;                     // 256x256
  ushort* Wgdect = wbase2 + 196608;                     // 16x256
  ushort* out_v_b = (ushort*)(wsb +  4*MiB);            // 2 MiB [M -> B] alias kh
  ushort* out_g_b = (ushort*)(wsb +  8*MiB);            // 6 MiB [M -> B] alias vt
  ushort* tmp_b   = (ushort*)(wsb + 17*MiB);            // 2 MiB [B -> C] alias Po0
  ushort* gsum_b  = (ushort*)(wsb + 25*MiB);            // 6 MiB [B -> C] alias Po1

  // ---- 1 mega-prep launch (10 transposes + hsplit + k1 + pre0) ----
  k_prep<<<9480, 256, 0, stream>>>(
      equ, h, W_equ, W_gproj, W_g1, W_g2, W_q, W_k, W_v,
      W_vg, W_ng, W_gout, W_hdec, W_gdec,
      Wg1t, Wg2t, Wth, Wtl, Wvgt, Wngt, Wgoutt, Whdect, Wgdect,
      h2h, h2l, g_src_b, gram_b, pre0);

  // ---- GEMM chain (BK=64 double-pumped cores) ----
  k_g1<<<dim3(64, 8), 256, 0, stream>>>(gram_b, Wg1t, b_g1, hidden);
  k_g2<<<dim3(64, 4), 256, 0, stream>>>(hidden, Wg2t, b_g2, h2h, h2l);
  k_g34<<<dim3(192, 8), 256, 0, stream>>>(h2h, h2l, Wth, Wtl, b_q, b_k, b_v,
                                          g_src_b, Wvgt, q_ws, kh, vt);

  // ---- attention (8-wave, single-bf16 Q, in-reg P, split-K x4) + merge ----
  dim3 g3(32, 8, 4);
  k3_attn<<<g3, 512, 0, stream>>>(q_ws, kh, vt, Po0, Po1, Po2, Po3, Pml);
  k_merge<<<2048, 256, 0, stream>>>(Po0, Po1, Po2, Po3, Pml, out_v_b, out_g_b);

  // ---- epilogue GEMMs (fused pairs) ----
  k56ab<<<dim3(256, 4), 256, 0, stream>>>(out_v_b, Wngt, b_ng, h, tmp_b,
                                          out_g_b, Wgoutt, gsum_b);
  k56cd<<<dim3(256, 4), 256, 0, stream>>>(tmp_b, Whdect, b_hdec,
                                          gsum_b, Wgdect, pre0, out);
}

// Round 18
// 256.298 us; speedup vs baseline: 1.0429x; 1.0060x over previous
//
#include <hip/hip_runtime.h>
#include <hip/hip_bf16.h>

typedef __attribute__((ext_vector_type(8))) short short8;
typedef __attribute__((ext_vector_type(4))) short bhalf4;
typedef __attribute__((ext_vector_type(4))) float floatx4;

constexpr int N_ = 4096;
constexpr float SQRT_E = 16.0f;
// q scale folded with log2(e): softmax computed in exp2 domain
constexpr float QSCALE = 0.17677669529663687f * 1.4426950408889634f;

__device__ __forceinline__ ushort f2bf(float x) {
  __hip_bfloat16 h = __float2bfloat16(x);
  return *reinterpret_cast<ushort*>(&h);
}
__device__ __forceinline__ float bf2f(ushort b) {
  unsigned int u = ((unsigned int)b) << 16;
  return __uint_as_float(u);
}

// ---------------- transpose helper (device side of mega-prep) ----------------
// r18: lo-part (dstl) writes removed — h2l/Wtl were dead after r16/r17's
// single-bf16 q/k/v (bit-exact change: removed stores were never read).
__device__ __forceinline__ void do_transpose(
    const float* __restrict__ src, ushort* __restrict__ dsth,
    int R, int C, int lb, int cb_shift, float* smem)
{
  float (*tile)[33] = (float(*)[33])smem;
  const int r0 = (lb >> cb_shift) * 32;
  const int c0 = (lb & ((1 << cb_shift) - 1)) * 32;
  const int tx = threadIdx.x & 31, ty = threadIdx.x >> 5;
  #pragma unroll
  for (int p = 0; p < 4; ++p) {
    const int lr = p*8 + ty;
    tile[lr][tx] = (r0+lr < R && c0+tx < C) ? src[(size_t)(r0+lr)*C + c0 + tx] : 0.f;
  }
  __syncthreads();
  #pragma unroll
  for (int p = 0; p < 4; ++p) {
    const int dc = p*8 + ty;
    if (c0+dc < C && r0+tx < R)
      dsth[(size_t)(c0+dc)*R + r0 + tx] = f2bf(tile[tx][dc]);
  }
}

// ---------------- mega-prep: all transposes + hsplit + k1 in ONE launch --------
__global__ __launch_bounds__(256) void k_prep(
    const float* __restrict__ equ, const float* __restrict__ h,
    const float* __restrict__ W_equ, const float* __restrict__ W_gproj,
    const float* __restrict__ W_g1, const float* __restrict__ W_g2,
    const float* __restrict__ W_q, const float* __restrict__ W_k,
    const float* __restrict__ W_v, const float* __restrict__ W_vg,
    const float* __restrict__ W_ng, const float* __restrict__ W_gout,
    const float* __restrict__ W_hdec, const float* __restrict__ W_gdec,
    ushort* __restrict__ Wg1t, ushort* __restrict__ Wg2t,
    ushort* __restrict__ Wth,
    ushort* __restrict__ Wvgt, ushort* __restrict__ Wngt,
    ushort* __restrict__ Wgoutt, ushort* __restrict__ Whdect,
    ushort* __restrict__ Wgdect,
    ushort* __restrict__ h2h,
    ushort* __restrict__ g_src_b, ushort* __restrict__ gram_b,
    float* __restrict__ pre0)
{
  __shared__ __align__(16) float smem[1120];
  const int b = blockIdx.x;
  const int t = threadIdx.x;

  if (b < 512) {            // W_g1 [1024,512] -> Wg1t
    do_transpose(W_g1, Wg1t, 1024, 512, b, 4, smem);
  } else if (b < 640) {     // W_g2 [512,256]
    do_transpose(W_g2, Wg2t, 512, 256, b-512, 3, smem);
  } else if (b < 768) {     // W_q (single bf16, r18)
    do_transpose(W_q, Wth, 512, 256, b-640, 3, smem);
  } else if (b < 896) {     // W_k
    do_transpose(W_k, Wth + 256*512, 512, 256, b-768, 3, smem);
  } else if (b < 1024) {    // W_v
    do_transpose(W_v, Wth + 512*512, 512, 256, b-896, 3, smem);
  } else if (b < 1088) {    // W_vg
    do_transpose(W_vg, Wvgt, 256, 256, b-1024, 3, smem);
  } else if (b < 1152) {    // W_ng
    do_transpose(W_ng, Wngt, 256, 256, b-1088, 3, smem);
  } else if (b < 1216) {    // W_gout
    do_transpose(W_gout, Wgoutt, 256, 256, b-1152, 3, smem);
  } else if (b < 1280) {    // W_hdec
    do_transpose(W_hdec, Whdect, 256, 256, b-1216, 3, smem);
  } else if (b < 1288) {    // W_gdec [256,16]
    do_transpose(W_gdec, Wgdect, 256, 16, b-1280, 0, smem);
  } else if (b < 5384) {    // hsplit: h_src half of h2 (hi only, r18)
    const int i = b - 1288;
    h2h[(size_t)i*512 + 256 + t] = f2bf(h[(size_t)i*256 + t] * SQRT_E);
  } else {                  // k1: g_src_b + gram_b + pre0
    float* eq   = smem;        // 48
    float* gs   = smem + 48;   // 768
    float* g2p  = smem + 816;  // 96
    float* part = smem + 912;  // 192
    const int i = b - 5384;
    if (t < 48) eq[t] = equ[(size_t)i*48 + t];
    __syncthreads();
    #pragma unroll
    for (int j = 0; j < 3; ++j) {
      float s = 0.f;
      #pragma unroll
      for (int m = 0; m < 16; ++m) s += eq[j*16+m] * W_equ[m*256 + t];
      s *= SQRT_E;
      gs[j*256 + t] = s;
      g_src_b[((size_t)i*3 + j)*256 + t] = f2bf(s);
    }
    __syncthreads();
    if (t < 192) {            // 2-way K-split of the gproj GEMV
      const int o = t % 96, half = t / 96;
      const int j = o >> 5, a = o & 31;
      const int e0 = half * 128;
      float s = 0.f;
      for (int e = 0; e < 128; ++e)
        s += gs[j*256 + e0 + e] * W_gproj[(size_t)(e0+e)*32 + a];
      part[t] = s;
    }
    __syncthreads();
    if (t < 96) g2p[t] = part[t] + part[96 + t];
    __syncthreads();
    #pragma unroll
    for (int r = 0; r < 4; ++r) {
      const int idx = r*256 + t;
      const int a = idx >> 5, bb = idx & 31;
      const float s = g2p[a]*g2p[bb] + g2p[32+a]*g2p[32+bb] + g2p[64+a]*g2p[64+bb];
      gram_b[(size_t)i*1024 + idx] = f2bf(s);
    }
    // pre0 = g_src(f32) @ W_gdec, 4-way K-split. t = j*64 + ks*16 + mc
    if (t < 192) {
      const int j = t >> 6, ks = (t >> 4) & 3, mc = t & 15;
      const int e0 = ks * 64;
      float s = 0.f;
      for (int e = 0; e < 64; ++e)
        s += gs[j*256 + e0 + e] * W_gdec[(size_t)(e0 + e)*16 + mc];
      part[t] = s;
    }
    __syncthreads();
    if (t < 48) {
      const int j = t >> 4, mc = t & 15;
      pre0[((size_t)i*3 + j)*16 + mc] =
          part[j*64 + mc] + part[j*64 + 16 + mc] +
          part[j*64 + 32 + mc] + part[j*64 + 48 + mc];
    }
  }
}

// ---------------- GEMM core: BK=64, double-pumped, register prefetch -----------
template<int KTOT>
__device__ __forceinline__ void gemm_core(
    const ushort* __restrict__ A, const ushort* __restrict__ Bt,
    int bM, int bN, floatx4 acc[4], ushort* As, ushort* Bs)
{
  const int t = threadIdx.x;
  const int wave = t >> 6, lane = t & 63, quad = lane >> 4, m = lane & 15;
  #pragma unroll
  for (int ct = 0; ct < 4; ++ct) acc[ct] = {0.f, 0.f, 0.f, 0.f};
  const int ca = t*2, cb = t*2 + 1;
  const int ra = ca >> 3, pa = ca & 7;
  const int rb = cb >> 3, pb = cb & 7;
  const ushort* pA0 = A  + (size_t)(bM+ra)*KTOT + pa*8;
  const ushort* pA1 = A  + (size_t)(bM+rb)*KTOT + pb*8;
  const ushort* pB0 = Bt + (size_t)(bN+ra)*KTOT + pa*8;
  const ushort* pB1 = Bt + (size_t)(bN+rb)*KTOT + pb*8;
  short8 rA0 = *(const short8*)pA0, rA1 = *(const short8*)pA1;
  short8 rB0 = *(const short8*)pB0, rB1 = *(const short8*)pB1;
  for (int k0 = 0; k0 < KTOT; k0 += 64) {
    __syncthreads();
    *(short8*)&As[ra*72 + pa*8] = rA0;
    *(short8*)&As[rb*72 + pb*8] = rA1;
    *(short8*)&Bs[ra*72 + pa*8] = rB0;
    *(short8*)&Bs[rb*72 + pb*8] = rB1;
    if (k0 + 64 < KTOT) {
      pA0 += 64; pA1 += 64; pB0 += 64; pB1 += 64;
      rA0 = *(const short8*)pA0; rA1 = *(const short8*)pA1;
      rB0 = *(const short8*)pB0; rB1 = *(const short8*)pB1;
    }
    __syncthreads();
    #pragma unroll
    for (int ks = 0; ks < 2; ++ks) {
      const short8 af = *(const short8*)&As[(wave*16 + m)*72 + ks*32 + quad*8];
      #pragma unroll
      for (int ct = 0; ct < 4; ++ct) {
        const short8 bf = *(const short8*)&Bs[(ct*16 + m)*72 + ks*32 + quad*8];
        acc[ct] = __builtin_amdgcn_mfma_f32_16x16x32_bf16(af, bf, acc[ct], 0, 0, 0);
      }
    }
  }
}

// G1: hidden = relu(gram @ W_g1 + b_g1)
__global__ __launch_bounds__(256) void k_g1(
    const ushort* __restrict__ gram_b, const ushort* __restrict__ Wg1t,
    const float* __restrict__ b_g1, ushort* __restrict__ hidden)
{
  __shared__ __align__(16) ushort As[64*72], Bs[64*72];
  floatx4 acc[4];
  const int bM = blockIdx.x*64, bN = blockIdx.y*64;
  gemm_core<1024>(gram_b, Wg1t, bM, bN, acc, As, Bs);
  const int lane = threadIdx.x & 63, wave = threadIdx.x >> 6;
  const int quad = lane >> 4, m = lane & 15;
  #pragma unroll
  for (int ct = 0; ct < 4; ++ct) {
    const int c = bN + ct*16 + m;
    #pragma unroll
    for (int r = 0; r < 4; ++r) {
      const int i = bM + wave*16 + quad*4 + r;
      hidden[(size_t)i*512 + c] = f2bf(fmaxf(acc[ct][r] + b_g1[c], 0.f));
    }
  }
}

// G2: g2 = hidden @ W_g2 + b_g2 -> h2 cols 0..255 (hi only, r18)
__global__ __launch_bounds__(256) void k_g2(
    const ushort* __restrict__ hidden, const ushort* __restrict__ Wg2t,
    const float* __restrict__ b_g2, ushort* __restrict__ h2h)
{
  __shared__ __align__(16) ushort As[64*72], Bs[64*72];
  floatx4 acc[4];
  const int bM = blockIdx.x*64, bN = blockIdx.y*64;
  gemm_core<512>(hidden, Wg2t, bM, bN, acc, As, Bs);
  const int lane = threadIdx.x & 63, wave = threadIdx.x >> 6;
  const int quad = lane >> 4, m = lane & 15;
  #pragma unroll
  for (int ct = 0; ct < 4; ++ct) {
    const int c = bN + ct*16 + m;
    #pragma unroll
    for (int r = 0; r < 4; ++r) {
      const int i = bM + wave*16 + quad*4 + r;
      h2h[(size_t)i*512 + c] = f2bf(acc[ct][r] + b_g2[c]);
    }
  }
}

// G3+G4 fused: q/k/v all 1-TERM bf16 GEMM (r17; absmax 0.1875 vs thr 0.5125).
// LDS 2 buffers (18.4 KB) -> 8 blocks/CU, grid 1536 fits ONE occupancy round.
// NOTE (r14): keep monolithic — mixed-grid load balance beats LDS-union split.
__global__ __launch_bounds__(256) void k_g34(
    const ushort* __restrict__ h2h,
    const ushort* __restrict__ Wth,
    const float* __restrict__ b_q, const float* __restrict__ b_k,
    const float* __restrict__ b_v,
    const ushort* __restrict__ g_src_b, const ushort* __restrict__ Wvgt,
    float* __restrict__ q_ws, ushort* __restrict__ kh,
    ushort* __restrict__ vt)
{
  __shared__ __align__(16) ushort S0[64*72], S1[64*72];
  const int lb = blockIdx.y*192 + blockIdx.x;     // grid (192,8) = 1536
  const int lane = threadIdx.x & 63, wave = threadIdx.x >> 6;
  const int quad = lane >> 4, m = lane & 15;
  floatx4 acc[4];
  if (lb < 768) {
    const int bM = (lb & 63)*64, bN = (lb >> 6)*64;
    gemm_core<512>(h2h, Wth, bM, bN, acc, S0, S1);
    if (bN < 512) {
      #pragma unroll
      for (int ct = 0; ct < 4; ++ct) {
        const int c = bN + ct*16 + m;
        #pragma unroll
        for (int r = 0; r < 4; ++r) {
          const int i = bM + wave*16 + quad*4 + r;
          if (c < 256) {
            const float s = acc[ct][r] + b_q[c];
            q_ws[((size_t)(c >> 5)*N_ + i)*32 + (c & 31)] = s * QSCALE;
          } else {
            const int cc = c - 256;
            const float s = acc[ct][r] + b_k[cc];
            kh[((size_t)(cc >> 5)*N_ + i)*32 + (cc & 31)] = f2bf(s);
          }
        }
      }
    } else {
      #pragma unroll
      for (int ct = 0; ct < 4; ++ct) {
        const int cc = bN + ct*16 + m - 512;
        #pragma unroll
        for (int r = 0; r < 4; ++r) {
          const int i = bM + wave*16 + quad*4 + r;
          const float s = acc[ct][r] + b_v[cc];
          vt[((size_t)(cc >> 5)*128 + (cc & 31))*N_ + i] = f2bf(s);
        }
      }
    }
  } else {
    const int lb2 = lb - 768;
    const int bM = (lb2 >> 2)*64, bN = (lb2 & 3)*64;
    gemm_core<256>(g_src_b, Wvgt, bM, bN, acc, S0, S1);
    #pragma unroll
    for (int ct = 0; ct < 4; ++ct) {
      const int c = bN + ct*16 + m;
      const int hh = c >> 5, d = c & 31;
      #pragma unroll
      for (int r = 0; r < 4; ++r) {
        const int i3 = bM + wave*16 + quad*4 + r;
        const int i = i3 / 3, j = i3 - 3*i;
        vt[((size_t)hh*128 + 32 + j*32 + d)*N_ + i] = f2bf(acc[ct][r]);
      }
    }
  }
}

// ---------------- K3: swapped-operand flash attention, P fully in-register -----
// mfma(K,Q) gives S^T with q = lane&15 -> softmax is lane-local. V columns are
// stored bit-permuted in LDS (slot{5..0} = {k5,k3,k2,k4,k1,k0}) so each lane's
// own 16 P values form its PV B-fragment directly: no P LDS buffer, no cross-
// lane exchange. PV swapped too (O^T = V^T P^T). Denominator = ones-row MFMA.
// r16: SINGLE-BF16 Q. 8-wave blocks (512 thr, 128 q-rows). Grid (32,8,4)=1024.
// LESSONS: (r10) doubling accumulator state spills (~64 live VGPR budget);
// (r12) fixed-base exp2 softmax NaNs — the online max is load-bearing;
// (r14) splitting k_g34 regressed (mixed-grid load balance beats LDS-union).
__global__ __launch_bounds__(512, 4) void k3_attn(
    const float* __restrict__ q_ws, const ushort* __restrict__ kh,
    const ushort* __restrict__ vt,
    ushort* __restrict__ Po0, ushort* __restrict__ Po1,
    ushort* __restrict__ Po2, ushort* __restrict__ Po3,
    float* __restrict__ Pml)
{
  __shared__ __align__(16) ushort Khs[64*40];              // 5 KiB
  __shared__ __align__(16) ushort Vs[128*64];              // 16 KiB, permuted+swizzled
  __shared__ float li_s[128];

  const int t    = threadIdx.x;          // 0..511
  const int wave = t >> 6;               // 0..7
  const int lane = t & 63;
  const int quad = lane >> 4;
  const int m    = lane & 15;
  const int h    = blockIdx.y;
  const int s    = blockIdx.z;
  const int n0q  = blockIdx.x * 128;

  const int ktb = s * 16;
  const int kte = ktb + 16;

  // Q fragment (B-operand; rows n0q + wave*16 + m): SINGLE bf16 (r16)
  union { short8 v; ushort u[8]; } Aqh;
  {
    const float* qp = q_ws + ((size_t)h*N_ + n0q + wave*16 + m)*32 + quad*8;
    #pragma unroll
    for (int jj = 0; jj < 8; ++jj) Aqh.u[jj] = f2bf(qp[jj]);
  }

  // ones A-fragment: A row 0 = ones -> denominator row of O^T
  union { short8 v; ushort u[8]; } onesf;
  {
    const ushort ov = (m == 0) ? (ushort)0x3F80 : (ushort)0;
    #pragma unroll
    for (int jj = 0; jj < 8; ++jj) onesf.u[jj] = ov;
  }

  // Of[nt][r] = O^T[d = nt*16 + quad*4 + r][q = wave*16 + m]; Of8 row0 = denom
  floatx4 Of[8];
  #pragma unroll
  for (int nt = 0; nt < 8; ++nt) Of[nt] = {0.f, 0.f, 0.f, 0.f};
  floatx4 Of8 = {0.f, 0.f, 0.f, 0.f};
  float mi = -3.0e38f;

  // K staging: 256 chunks handled by threads t < 256
  const int krow = t >> 2, kch = (t & 3) * 8;
  const ushort* pKh = kh + ((size_t)h*N_ + ktb*64 + (krow & 63))*32 + kch;

  // V staging: 1024 (row,g) chunks over 512 threads (2 each); each 8-k run
  // splits into two permuted b64s.
  // slot = 32*(g>>2) + 16*(g&1) + 8*(e>>2) + 4*((g>>1)&1) + (e&3)
  const ushort* pV[2];
  int wv0[2], wv1[2];
  #pragma unroll
  for (int p = 0; p < 2; ++p) {
    const int idx = p*512 + t, row = idx >> 3, g = idx & 7;
    pV[p] = vt + ((size_t)h*128 + row)*N_ + ktb*64 + g*8;
    const int sb0  = 32*(g>>2) + 16*(g&1) + 4*((g>>1)&1);
    const int blk0 = sb0 >> 3, off = sb0 & 4, r7 = row & 7;
    wv0[p] = row*64 + ((blk0       ^ r7) * 8) + off;
    wv1[p] = row*64 + (((blk0 + 1) ^ r7) * 8) + off;
  }

  short8 rK0 = {0,0,0,0,0,0,0,0};
  if (t < 256) rK0 = *(const short8*)pKh;
  short8 rV[2];
  #pragma unroll
  for (int p = 0; p < 2; ++p) rV[p] = *(const short8*)pV[p];

  const int x7 = m & 7;   // read-side swizzle key (row = nt*16 + m)

  for (int kt = ktb; kt < kte; ++kt) {
    __syncthreads();
    if (t < 256) *(short8*)&Khs[krow*40 + kch] = rK0;
    #pragma unroll
    for (int p = 0; p < 2; ++p) {
      union { short8 v; bhalf4 h2[2]; } tmp;
      tmp.v = rV[p];
      *(bhalf4*)&Vs[wv0[p]] = tmp.h2[0];
      *(bhalf4*)&Vs[wv1[p]] = tmp.h2[1];
    }
    if (kt + 1 < kte) {
      if (t < 256) { pKh += 2048; rK0 = *(const short8*)pKh; }
      #pragma unroll
      for (int p = 0; p < 2; ++p) { pV[p] += 64; rV[p] = *(const short8*)pV[p]; }
    }
    __syncthreads();

    // S^T = K Q^T (swapped operands): sf[kb][r] = S[k=kb*16+quad*4+r][q=m-col]
    floatx4 sf[4];
    #pragma unroll
    for (int kb = 0; kb < 4; ++kb) {
      const short8 bkh = *(const short8*)&Khs[(kb*16 + m)*40 + quad*8];
      floatx4 sv = {0.f, 0.f, 0.f, 0.f};
      sv = __builtin_amdgcn_mfma_f32_16x16x32_bf16(bkh, Aqh.v, sv, 0, 0, 0);
      sf[kb] = sv;
    }

    // row max: 15 fmax local + 2 shuffle across quads (lanes m, m^16, m^32, m^48)
    float nm = fmaxf(fmaxf(sf[0][0], sf[0][1]), fmaxf(sf[0][2], sf[0][3]));
    nm = fmaxf(nm, fmaxf(fmaxf(sf[1][0], sf[1][1]), fmaxf(sf[1][2], sf[1][3])));
    nm = fmaxf(nm, fmaxf(fmaxf(sf[2][0], sf[2][1]), fmaxf(sf[2][2], sf[2][3])));
    nm = fmaxf(nm, fmaxf(fmaxf(sf[3][0], sf[3][1]), fmaxf(sf[3][2], sf[3][3])));
    nm = fmaxf(nm, __shfl_xor(nm, 16));
    nm = fmaxf(nm, __shfl_xor(nm, 32));

    if (__any(nm > mi + 20.f)) {
      const float mn = fmaxf(mi, nm);
      const float al = exp2f(mi - mn);
      mi = mn;
      #pragma unroll
      for (int nt = 0; nt < 8; ++nt) {
        Of[nt][0] *= al; Of[nt][1] *= al; Of[nt][2] *= al; Of[nt][3] *= al;
      }
      Of8[0] *= al; Of8[1] *= al; Of8[2] *= al; Of8[3] *= al;
    }

    // P = exp2(S - mi), Schraudolph bits, packed in-register into B-fragments:
    // pk[ks].u[p] = {P(kb=2ks+(p>>1), r=2(p&1)) lo16, r=2(p&1)+1 hi16}
    const float base = 1064866805.0f - mi*8388608.0f;
    union { short8 v; unsigned int u[4]; } pk[2];
    #pragma unroll
    for (int kb = 0; kb < 4; ++kb) {
      int p0 = (int)(sf[kb][0]*8388608.0f + base); p0 = p0 < 0 ? 0 : p0;
      int p1 = (int)(sf[kb][1]*8388608.0f + base); p1 = p1 < 0 ? 0 : p1;
      int p2 = (int)(sf[kb][2]*8388608.0f + base); p2 = p2 < 0 ? 0 : p2;
      int p3 = (int)(sf[kb][3]*8388608.0f + base); p3 = p3 < 0 ? 0 : p3;
      pk[kb >> 1].u[(kb & 1)*2 + 0] = ((unsigned)p0 >> 16) | ((unsigned)p1 & 0xffff0000u);
      pk[kb >> 1].u[(kb & 1)*2 + 1] = ((unsigned)p2 >> 16) | ((unsigned)p3 & 0xffff0000u);
    }

    // O^T += V^T P^T : A = V^T fragment from permuted LDS, B = pk (in-register)
    #pragma unroll
    for (int ks = 0; ks < 2; ++ks) {
      #pragma unroll
      for (int nt = 0; nt < 8; ++nt) {
        const short8 av = *(const short8*)&Vs[(nt*16 + m)*64 + (((ks*4 + quad) ^ x7) * 8)];
        Of[nt] = __builtin_amdgcn_mfma_f32_16x16x32_bf16(av, pk[ks].v, Of[nt], 0, 0, 0);
      }
      Of8 = __builtin_amdgcn_mfma_f32_16x16x32_bf16(onesf.v, pk[ks].v, Of8, 0, 0, 0);
    }
  }

  // denom lives at quad==0 lanes (C row 0), broadcast via LDS
  if (quad == 0) li_s[wave*16 + m] = Of8[0];
  __syncthreads();
  const float linv = 1.0f / li_s[wave*16 + m];

  ushort* Po = (s == 0) ? Po0 : ((s == 1) ? Po1 : ((s == 2) ? Po2 : Po3));
  const int n = n0q + wave*16 + m;
  #pragma unroll
  for (int nt = 0; nt < 8; ++nt) {
    unsigned int lo = (unsigned)f2bf(Of[nt][0] * linv) | ((unsigned)f2bf(Of[nt][1] * linv) << 16);
    unsigned int hi = (unsigned)f2bf(Of[nt][2] * linv) | ((unsigned)f2bf(Of[nt][3] * linv) << 16);
    uint2 pkd; pkd.x = lo; pkd.y = hi;
    *(uint2*)&Po[((size_t)h*N_ + n)*128 + nt*16 + quad*4] = pkd;
  }
  if (quad == 0) {
    Pml[(((size_t)s*8 + h)*N_ + n)*2 + 0] = mi;
    Pml[(((size_t)s*8 + h)*N_ + n)*2 + 1] = Of8[0];
  }
}

// ---------------- merge: combine 4 split-K partials (8 elems/thread) ------------
__global__ __launch_bounds__(256) void k_merge(
    const ushort* __restrict__ Po0, const ushort* __restrict__ Po1,
    const ushort* __restrict__ Po2, const ushort* __restrict__ Po3,
    const float* __restrict__ Pml,
    ushort* __restrict__ out_v_b, ushort* __restrict__ out_g_b)
{
  const int idx = blockIdx.x*256 + threadIdx.x;
  const int c0 = (idx & 15) * 8;
  const int n  = (idx >> 4) & 4095;
  const int h  = idx >> 16;
  float mm[4], ll[4];
  #pragma unroll
  for (int s = 0; s < 4; ++s) {
    mm[s] = Pml[(((size_t)s*8 + h)*N_ + n)*2 + 0];
    ll[s] = Pml[(((size_t)s*8 + h)*N_ + n)*2 + 1];
  }
  const float M = fmaxf(fmaxf(mm[0], mm[1]), fmaxf(mm[2], mm[3]));
  float w[4], tot = 0.f;
  #pragma unroll
  for (int s = 0; s < 4; ++s) { w[s] = exp2f(mm[s] - M) * ll[s]; tot += w[s]; }
  const float inv = 1.0f / tot;
  union { short8 v; ushort u[8]; } a, b, c, d, res;
  a.v = *(const short8*)&Po0[((size_t)h*N_ + n)*128 + c0];
  b.v = *(const short8*)&Po1[((size_t)h*N_ + n)*128 + c0];
  c.v = *(const short8*)&Po2[((size_t)h*N_ + n)*128 + c0];
  d.v = *(const short8*)&Po3[((size_t)h*N_ + n)*128 + c0];
  #pragma unroll
  for (int j = 0; j < 8; ++j)
    res.u[j] = f2bf((w[0]*bf2f(a.u[j]) + w[1]*bf2f(b.u[j]) +
                     w[2]*bf2f(c.u[j]) + w[3]*bf2f(d.u[j])) * inv);
  if (c0 < 32) {
    *(short8*)&out_v_b[(size_t)n*256 + h*32 + c0] = res.v;
  } else {
    const int j = (c0 - 32) >> 5, cc = (c0 - 32) & 31;
    *(short8*)&out_g_b[((size_t)n*3 + j)*256 + h*32 + cc] = res.v;
  }
}

// ---------------- k5a+k5b fused ----------------
__global__ __launch_bounds__(256) void k56ab(
    const ushort* __restrict__ out_v_b, const ushort* __restrict__ Wngt,
    const float* __restrict__ b_ng, const float* __restrict__ h,
    ushort* __restrict__ tmp_b,
    const ushort* __restrict__ out_g_b, const ushort* __restrict__ Wgoutt,
    ushort* __restrict__ gsum_b)
{
  __shared__ __align__(16) ushort As[64*72], Bs[64*72];
  floatx4 acc[4];
  const int lane = threadIdx.x & 63, wave = threadIdx.x >> 6;
  const int quad = lane >> 4, m = lane & 15;
  const int bN = blockIdx.y*64;
  if (blockIdx.x < 64) {
    const int bM = blockIdx.x*64;
    gemm_core<256>(out_v_b, Wngt, bM, bN, acc, As, Bs);
    #pragma unroll
    for (int ct = 0; ct < 4; ++ct) {
      const int c = bN + ct*16 + m;
      #pragma unroll
      for (int r = 0; r < 4; ++r) {
        const int i = bM + wave*16 + quad*4 + r;
        tmp_b[(size_t)i*256 + c] =
            f2bf(acc[ct][r] + b_ng[c] + h[(size_t)i*256 + c] * SQRT_E);
      }
    }
  } else {
    const int bM = (blockIdx.x - 64)*64;
    gemm_core<256>(out_g_b, Wgoutt, bM, bN, acc, As, Bs);
    #pragma unroll
    for (int ct = 0; ct < 4; ++ct) {
      const int c = bN + ct*16 + m;
      #pragma unroll
      for (int r = 0; r < 4; ++r) {
        const int i = bM + wave*16 + quad*4 + r;
        gsum_b[(size_t)i*256 + c] = f2bf(acc[ct][r]);
      }
    }
  }
}

// ---------------- k5c+k5d fused ----------------
__global__ __launch_bounds__(256) void k56cd(
    const ushort* __restrict__ tmp_b, const ushort* __restrict__ Whdect,
    const float* __restrict__ b_hdec,
    const ushort* __restrict__ gsum_b, const ushort* __restrict__ Wgdect,
    const float* __restrict__ pre0,
    float* __restrict__ out)
{
  __shared__ __align__(16) ushort As[64*72], Bs[64*72];
  const int t = threadIdx.x;
  const int lane = t & 63, wave = t >> 6;
  const int quad = lane >> 4, m = lane & 15;
  if (blockIdx.x < 64) {
    floatx4 acc[4];
    const int bM = blockIdx.x*64, bN = blockIdx.y*64;
    gemm_core<256>(tmp_b, Whdect, bM, bN, acc, As, Bs);
    #pragma unroll
    for (int ct = 0; ct < 4; ++ct) {
      const int c = bN + ct*16 + m;
      #pragma unroll
      for (int r = 0; r < 4; ++r) {
        const int i = bM + wave*16 + quad*4 + r;
        out[196608 + (size_t)i*256 + c] = acc[ct][r] + b_hdec[c];
      }
    }
  } else if (blockIdx.y == 0) {
    const int bM = (blockIdx.x - 64)*64;
    floatx4 acc = {0.f, 0.f, 0.f, 0.f};
    const int row = t >> 2, kq = (t & 3) * 8;
    for (int k0 = 0; k0 < 256; k0 += 32) {
      __syncthreads();
      *(short8*)&As[row*40 + kq] = *(const short8*)&gsum_b[(size_t)(bM+row)*256 + k0 + kq];
      if (t < 64)
        *(short8*)&Bs[(t>>2)*40 + kq] = *(const short8*)&Wgdect[(size_t)(t>>2)*256 + k0 + kq];
      __syncthreads();
      const short8 af = *(const short8*)&As[(wave*16 + m)*40 + quad*8];
      const short8 bf = *(const short8*)&Bs[m*40 + quad*8];
      acc = __builtin_amdgcn_mfma_f32_16x16x32_bf16(af, bf, acc, 0, 0, 0);
    }
    #pragma unroll
    for (int r = 0; r < 4; ++r) {
      const int i3 = bM + wave*16 + quad*4 + r;
      out[(size_t)i3*16 + m] = acc[r] + pre0[(size_t)i3*16 + m];
    }
  }
}

extern "C" void kernel_launch(void* const* d_in, const int* in_sizes, int n_in,
                              void* d_out, int out_size, void* d_ws, size_t ws_size,
                              hipStream_t stream) {
  const float* equ    = (const float*)d_in[0];
  const float* h      = (const float*)d_in[1];
  const float* W_equ  = (const float*)d_in[4];
  const float* W_gproj= (const float*)d_in[5];
  const float* W_vg   = (const float*)d_in[6];
  const float* W_g1   = (const float*)d_in[7];
  const float* b_g1   = (const float*)d_in[8];
  const float* W_g2   = (const float*)d_in[9];
  const float* b_g2   = (const float*)d_in[10];
  const float* W_q    = (const float*)d_in[11];
  const float* b_q    = (const float*)d_in[12];
  const float* W_k    = (const float*)d_in[13];
  const float* b_k    = (const float*)d_in[14];
  const float* W_v    = (const float*)d_in[15];
  const float* b_v    = (const float*)d_in[16];
  const float* W_ng   = (const float*)d_in[17];
  const float* b_ng   = (const float*)d_in[18];
  const float* W_gout = (const float*)d_in[19];
  const float* W_gdec = (const float*)d_in[20];
  const float* W_hdec = (const float*)d_in[21];
  const float* b_hdec = (const float*)d_in[22];
  float* out = (float*)d_out;

  // ---- workspace layout (lifetimes annotated), peak 50.4 MiB (52 proven) ----
  // Stages: P=prep G1 G2 G34 A=attn M=merge B=k56ab C=k56cd
  char* wsb = (char*)d_ws;
  constexpr size_t MiB = 1048576;
  float*  q_ws    = (float*) (wsb +  0*MiB);            // 4 MiB   [G34 -> A]
  ushort* kh      = (ushort*)(wsb +  4*MiB);            // 2 MiB   [G34 -> A]
  float*  Pml     = (float*) (wsb +  6*MiB);            // 1 MiB   [A -> M] (4 splits)
  float*  pre0    = (float*) (wsb +  7*MiB);            // 0.75 MiB[P -> C]
  ushort* vt      = (ushort*)(wsb +  8*MiB);            // 8 MiB   [G34 -> A]
  ushort* h2h     = (ushort*)(wsb + 17*MiB);            // 4 MiB   [P/G2 -> G34]
  ushort* g_src_b = (ushort*)(wsb + 25*MiB);            // 6 MiB   [P -> G34]
  ushort* wbase   = (ushort*)(wsb + 31*MiB);            // ~1.9 MiB [P -> G34]
  ushort* Wg1t = wbase;                                 // 512x1024
  ushort* Wg2t = wbase + 524288;                        // 256x512
  ushort* Wth  = wbase + 655360;                        // 768x512 (single bf16)
  ushort* Wvgt = wbase + 1048576;                       // 256x256
  ushort* gram_b  = (ushort*)(wsb + 34*MiB);            // 8 MiB   [P -> G1]
  ushort* hidden  = (ushort*)(wsb + 42*MiB);            // 4 MiB   [G1 -> G2]
  // split-K x4 attention partials (all alias dead regions):
  ushort* Po0     = (ushort*)(wsb + 17*MiB);            // 8 MiB [A -> M] alias h2h
  ushort* Po1     = (ushort*)(wsb + 25*MiB);            // 8 MiB [A -> M] alias g_src_b+wbase
  ushort* Po2     = (ushort*)(wsb + 34*MiB);            // 8 MiB [A -> M] alias gram_b
  ushort* Po3     = (ushort*)(wsb + 42*MiB);            // 8 MiB [A -> M] alias hidden+
  ushort* wbase2  = (ushort*)(wsb + 50*MiB);            // 0.4 MiB [P -> B/C]
  ushort* Wngt   = wbase2;                              // 256x256
  ushort* Wgoutt = wbase2 + 65536;                      // 256x256
  ushort* Whdect = wbase2 + 131072;                     // 256x256
  ushort* Wgdect = wbase2 + 196608;                     // 16x256
  ushort* out_v_b = (ushort*)(wsb +  4*MiB);            // 2 MiB [M -> B] alias kh
  ushort* out_g_b = (ushort*)(wsb +  8*MiB);            // 6 MiB [M -> B] alias vt
  ushort* tmp_b   = (ushort*)(wsb + 17*MiB);            // 2 MiB [B -> C] alias Po0
  ushort* gsum_b  = (ushort*)(wsb + 25*MiB);            // 6 MiB [B -> C] alias Po1

  // ---- 1 mega-prep launch (10 transposes + hsplit + k1 + pre0) ----
  k_prep<<<9480, 256, 0, stream>>>(
      equ, h, W_equ, W_gproj, W_g1, W_g2, W_q, W_k, W_v,
      W_vg, W_ng, W_gout, W_hdec, W_gdec,
      Wg1t, Wg2t, Wth, Wvgt, Wngt, Wgoutt, Whdect, Wgdect,
      h2h, g_src_b, gram_b, pre0);

  // ---- GEMM chain (BK=64 double-pumped cores) ----
  k_g1<<<dim3(64, 8), 256, 0, stream>>>(gram_b, Wg1t, b_g1, hidden);
  k_g2<<<dim3(64, 4), 256, 0, stream>>>(hidden, Wg2t, b_g2, h2h);
  k_g34<<<dim3(192, 8), 256, 0, stream>>>(h2h, Wth, b_q, b_k, b_v,
                                          g_src_b, Wvgt, q_ws, kh, vt);

  // ---- attention (8-wave, single-bf16 Q, in-reg P, split-K x4) + merge ----
  dim3 g3(32, 8, 4);
  k3_attn<<<g3, 512, 0, stream>>>(q_ws, kh, vt, Po0, Po1, Po2, Po3, Pml);
  k_merge<<<2048, 256, 0, stream>>>(Po0, Po1, Po2, Po3, Pml, out_v_b, out_g_b);

  // ---- epilogue GEMMs (fused pairs) ----
  k56ab<<<dim3(256, 4), 256, 0, stream>>>(out_v_b, Wngt, b_ng, h, tmp_b,
                                          out_g_b, Wgoutt, gsum_b);
  k56cd<<<dim3(256, 4), 256, 0, stream>>>(tmp_b, Whdect, b_hdec,
                                          gsum_b, Wgdect, pre0, out);
}